// Round 12
// baseline (316.121 us; speedup 1.0000x reference)
//
#include <hip/hip_runtime.h>
#include <hip/hip_bf16.h>
#include <math.h>

#define NRES 512
#define CS 384
#define CZ 128
#define NH 12
#define PQ 4
#define PV 8
#define OUT_DIM 2112   // H*(C + 3*PV + PV + CZ)
#define PRJ 1152       // packed projection width: q192|k192|v192|qp144|kp144|vp288

typedef __attribute__((ext_vector_type(8))) short short8;
typedef __attribute__((ext_vector_type(4))) float f32x4;

__device__ __forceinline__ float softplusf(float x) { return log1pf(expf(x)); }

__device__ __forceinline__ unsigned short f2bf(float f) {
    union { float f; unsigned u; } v; v.f = f;
    unsigned r = v.u + 0x7FFF + ((v.u >> 16) & 1);
    return (unsigned short)(r >> 16);
}

__device__ __forceinline__ unsigned cvt_pk_bf16(float lo, float hi) {
    unsigned r;
    asm volatile("v_cvt_pk_bf16_f32 %0, %1, %2" : "=v"(r) : "v"(lo), "v"(hi));
    return r;
}

// ---------------------------------------------------------------------------
// Pack 6 projection weights into Bp[384][1152] + Wb MFMA B-fragments
// + zero proj (avoids runtime fillBuffer in-graph).
// ---------------------------------------------------------------------------
__global__ void pack_proj_kernel(const float* __restrict__ Wq, const float* __restrict__ Wk,
                                 const float* __restrict__ Wv, const float* __restrict__ Wqp,
                                 const float* __restrict__ Wkp, const float* __restrict__ Wvp,
                                 const float* __restrict__ Wb,
                                 float* __restrict__ Bp, unsigned short* __restrict__ wbfrag,
                                 float* __restrict__ proj)
{
    int x = blockIdx.x * blockDim.x + threadIdx.x;
    if (x < CS * PRJ) {
        int k = x / PRJ, c = x % PRJ;
        float v;
        if      (c < 192)  v = Wq [k * 192 + c];
        else if (c < 384)  v = Wk [k * 192 + (c - 192)];
        else if (c < 576)  v = Wv [k * 192 + (c - 384)];
        else if (c < 720)  v = Wqp[k * 144 + (c - 576)];
        else if (c < 864)  v = Wkp[k * 144 + (c - 720)];
        else               v = Wvp[k * 288 + (c - 864)];
        Bp[x] = v;
    } else if (x < CS * PRJ + 2048) {
        int idx = x - CS * PRJ;               // ks*512 + lane*8 + e
        int ks = idx >> 9, r = idx & 511;
        int lane = r >> 3, e = r & 7;
        int col = lane & 15, kb = (lane >> 4) * 8;
        int row = ks * 32 + kb + e;
        float v = (col < NH) ? Wb[row * NH + col] : 0.f;
        wbfrag[idx] = f2bf(v);
    } else {
        int idx = x - (CS * PRJ + 2048);
        if (idx < NRES * PRJ) proj[idx] = 0.f;
    }
}

// ---------------------------------------------------------------------------
// Tiled f32 GEMM: BM=64, BN=64, BK=16, 256 threads, 4x4 micro-tile.
// ---------------------------------------------------------------------------
__global__ void gemm_tiled(const float* __restrict__ A, const float* __restrict__ B,
                           const float* __restrict__ bias, const float* __restrict__ res,
                           float* __restrict__ C, int M, int K, int Nc, int relu, int KS,
                           int reluA)
{
    __shared__ float As[16][68];
    __shared__ float Bs[16][64];
    int m0 = blockIdx.x * 64, n0 = blockIdx.y * 64;
    int kbeg = blockIdx.z * KS;
    int t = threadIdx.x;
    int tm = t >> 4, tn = t & 15;
    int lr = t >> 2, lc4 = t & 3;
    int br = t >> 4, bc4 = t & 15;
    float acc[4][4] = {{0.f}};

    for (int kt = kbeg; kt < kbeg + KS; kt += 16) {
        float4 a4 = *(const float4*)&A[(size_t)(m0 + lr) * K + kt + lc4 * 4];
        float4 b4 = *(const float4*)&B[(size_t)(kt + br) * Nc + n0 + bc4 * 4];
        if (reluA) {
            a4.x = fmaxf(a4.x, 0.f); a4.y = fmaxf(a4.y, 0.f);
            a4.z = fmaxf(a4.z, 0.f); a4.w = fmaxf(a4.w, 0.f);
        }
        As[lc4 * 4 + 0][lr] = a4.x;
        As[lc4 * 4 + 1][lr] = a4.y;
        As[lc4 * 4 + 2][lr] = a4.z;
        As[lc4 * 4 + 3][lr] = a4.w;
        *(float4*)&Bs[br][bc4 * 4] = b4;
        __syncthreads();
#pragma unroll
        for (int k = 0; k < 16; ++k) {
            float4 av = *(const float4*)&As[k][tm * 4];
            float4 bv = *(const float4*)&Bs[k][tn * 4];
            acc[0][0] = fmaf(av.x, bv.x, acc[0][0]); acc[0][1] = fmaf(av.x, bv.y, acc[0][1]);
            acc[0][2] = fmaf(av.x, bv.z, acc[0][2]); acc[0][3] = fmaf(av.x, bv.w, acc[0][3]);
            acc[1][0] = fmaf(av.y, bv.x, acc[1][0]); acc[1][1] = fmaf(av.y, bv.y, acc[1][1]);
            acc[1][2] = fmaf(av.y, bv.z, acc[1][2]); acc[1][3] = fmaf(av.y, bv.w, acc[1][3]);
            acc[2][0] = fmaf(av.z, bv.x, acc[2][0]); acc[2][1] = fmaf(av.z, bv.y, acc[2][1]);
            acc[2][2] = fmaf(av.z, bv.z, acc[2][2]); acc[2][3] = fmaf(av.z, bv.w, acc[2][3]);
            acc[3][0] = fmaf(av.w, bv.x, acc[3][0]); acc[3][1] = fmaf(av.w, bv.y, acc[3][1]);
            acc[3][2] = fmaf(av.w, bv.z, acc[3][2]); acc[3][3] = fmaf(av.w, bv.w, acc[3][3]);
        }
        __syncthreads();
    }

    if (gridDim.z > 1) {
#pragma unroll
        for (int r = 0; r < 4; ++r)
#pragma unroll
            for (int c = 0; c < 4; ++c)
                atomicAdd(&C[(size_t)(m0 + tm * 4 + r) * Nc + n0 + tn * 4 + c], acc[r][c]);
    } else {
#pragma unroll
        for (int r = 0; r < 4; ++r) {
            int row = m0 + tm * 4 + r;
            float4 v;
            float* vp = (float*)&v;
#pragma unroll
            for (int c = 0; c < 4; ++c) {
                int col = n0 + tn * 4 + c;
                float x = acc[r][c];
                if (bias) x += bias[col];
                if (res)  x += res[(size_t)row * Nc + col];
                if (relu) x = fmaxf(x, 0.f);
                vp[c] = x;
            }
            *(float4*)&C[(size_t)row * Nc + n0 + tn * 4] = v;
        }
    }
}

// ---------------------------------------------------------------------------
// Fused init: out1 = bo + single ; h1 = b1 ; h2 = b2
// ---------------------------------------------------------------------------
__global__ void init3_kernel(const float* __restrict__ bo, const float* __restrict__ single,
                             const float* __restrict__ b1, const float* __restrict__ b2,
                             float* __restrict__ out1, float* __restrict__ h1,
                             float* __restrict__ h2)
{
    int x = blockIdx.x * blockDim.x + threadIdx.x;
    if (x >= NRES * CS) return;
    int c = x % CS;
    out1[x] = bo[c] + single[x];
    h1[x] = b1[c];
    h2[x] = b2[c];
}

// ---------------------------------------------------------------------------
// Frames: one thread per (n, h).
// ---------------------------------------------------------------------------
__global__ void frames_kernel(const float* __restrict__ proj, const float* __restrict__ rot,
                              const float* __restrict__ trans,
                              float* __restrict__ gq, float* __restrict__ gv,
                              float* __restrict__ sqq,
                              float* __restrict__ kT, float* __restrict__ gkT,
                              float* __restrict__ sqkT)
{
    int x = blockIdx.x * blockDim.x + threadIdx.x;
    if (x >= NRES * NH) return;
    int n = x / NH, h = x % NH;
    float R[9], t3[3];
#pragma unroll
    for (int r = 0; r < 9; ++r) R[r] = rot[n * 9 + r];
#pragma unroll
    for (int r = 0; r < 3; ++r) t3[r] = trans[n * 3 + r];
    const float* qp = proj + (size_t)n * PRJ + 576 + h * (PQ * 3);
    const float* kp = proj + (size_t)n * PRJ + 720 + h * (PQ * 3);
    const float* vp = proj + (size_t)n * PRJ + 864 + h * (PV * 3);
    const float* kk = proj + (size_t)n * PRJ + 192 + h * 16;

#pragma unroll
    for (int c = 0; c < 16; ++c) kT[(h * 16 + c) * NRES + n] = kk[c];

    float sq = 0.f, sk = 0.f;
#pragma unroll
    for (int p = 0; p < PQ; ++p) {
        const float* in = qp + p * 3;
        float* og = gq + (size_t)n * 144 + h * (PQ * 3) + p * 3;
#pragma unroll
        for (int a = 0; a < 3; ++a) {
            float g = R[a*3+0]*in[0] + R[a*3+1]*in[1] + R[a*3+2]*in[2] + t3[a];
            og[a] = g; sq += g * g;
        }
        const float* in2 = kp + p * 3;
#pragma unroll
        for (int a = 0; a < 3; ++a) {
            float g = R[a*3+0]*in2[0] + R[a*3+1]*in2[1] + R[a*3+2]*in2[2] + t3[a];
            gkT[(h * 12 + p * 3 + a) * NRES + n] = g;
            sk += g * g;
        }
    }
    sqq[n * NH + h] = sq;
    sqkT[h * NRES + n] = sk;
#pragma unroll
    for (int p = 0; p < PV; ++p) {
        const float* in = vp + p * 3;
        float* og = gv + (size_t)n * 288 + h * (PV * 3) + p * 3;
#pragma unroll
        for (int a = 0; a < 3; ++a)
            og[a] = R[a*3+0]*in[0] + R[a*3+1]*in[1] + R[a*3+2]*in[2] + t3[a];
    }
}

// ---------------------------------------------------------------------------
// Logits v7: grid (i=512, jt=16), block 128 (2 waves), 32-j tile per block.
// Load order fixed for in-order vmcnt: bfrag+f32 part (L2) FIRST, HBM pair
// loads issued AFTER, so the f32 compute doesn't drain the HBM queue.
// ---------------------------------------------------------------------------
__global__ __launch_bounds__(128) void logits_mfma_kernel(
        const float* __restrict__ pair, const float* __restrict__ proj,
        const float* __restrict__ gq, const float* __restrict__ kT,
        const float* __restrict__ gkT, const float* __restrict__ sqq,
        const float* __restrict__ sqkT, const unsigned short* __restrict__ wbfrag,
        const float* __restrict__ gamma_raw, float* __restrict__ L)
{
    __shared__ unsigned short pl[32 * 128];   // bf16 swizzled (8 KB)
    __shared__ float bias_s[32 * 17];         // 2.2 KB

    int i = blockIdx.x, jt = blockIdx.y, t = threadIdx.x;
    int lane = t & 63, w = t >> 6;

    // (a) prepacked Wb B-fragments (L2-hot)
    short8 bfrag[4];
#pragma unroll
    for (int ks = 0; ks < 4; ++ks)
        bfrag[ks] = *(const short8*)&wbfrag[ks * 512 + lane * 8];

    // (b) f32 part: L2-resident loads + compute (no HBM in queue yet)
    const float WLc = 0.57735026918962576f;   // sqrt(1/3)
    const float WCc = 0.23570226039551584f;   // sqrt(2/(9*4))
    int jl = t & 31, hg = t >> 5;
    int j = jt * 32 + jl;
    float lp[3];
#pragma unroll
    for (int hh = 0; hh < 3; ++hh) {
        int h = hg * 3 + hh;
        float qk = 0.f;
#pragma unroll
        for (int c = 0; c < 16; ++c)
            qk = fmaf(proj[(size_t)i * PRJ + h * 16 + c], kT[(h * 16 + c) * NRES + j], qk);
        float cross = 0.f;
#pragma unroll
        for (int x = 0; x < 12; ++x)
            cross = fmaf(gq[(size_t)i * 144 + h * 12 + x], gkT[(h * 12 + x) * NRES + j], cross);
        float gamh = softplusf(gamma_raw[h]);
        float d2 = sqq[i * NH + h] + sqkT[h * NRES + j] - 2.f * cross;
        lp[hh] = WLc * (qk * 0.25f - 0.5f * WCc * gamh * d2);
    }

    // (c) pair tile: HBM loads issued after the L2 phase, convert, LDS write
    const float* prow = pair + ((size_t)i * NRES + jt * 32) * CZ;
#pragma unroll
    for (int m = 0; m < 8; ++m) {
        float4 v = *(const float4*)&prow[m * 512 + t * 4];
        int idx = m * 512 + t * 4;
        int row = idx >> 7, kk = idx & 127;
        unsigned b01 = cvt_pk_bf16(v.x, v.y);
        unsigned b23 = cvt_pk_bf16(v.z, v.w);
        int byte = row * 256 + ((kk * 2) ^ ((row & 7) << 4));
        *(uint2*)((char*)pl + byte) = make_uint2(b01, b23);
    }
    __syncthreads();

    // MFMA bias: wave w covers rows [w*16, w*16+16)
    {
        f32x4 acc = {0.f, 0.f, 0.f, 0.f};
        int arow = w * 16 + (lane & 15);
        int kb2 = (lane >> 4) * 16;
#pragma unroll
        for (int ks = 0; ks < 4; ++ks) {
            int byte = arow * 256 + (((ks * 64) + kb2) ^ ((arow & 7) << 4));
            short8 afrag = *(const short8*)((const char*)pl + byte);
            acc = __builtin_amdgcn_mfma_f32_16x16x32_bf16(afrag, bfrag[ks], acc, 0, 0, 0);
        }
        int crow = w * 16 + (lane >> 4) * 4;
        int ccol = lane & 15;
#pragma unroll
        for (int r = 0; r < 4; ++r) bias_s[(crow + r) * 17 + ccol] = acc[r];
    }
    __syncthreads();

    // combine + store
#pragma unroll
    for (int hh = 0; hh < 3; ++hh) {
        int h = hg * 3 + hh;
        L[((size_t)i * NH + h) * NRES + j] = lp[hh] + WLc * bias_s[jl * 17 + h];
    }
}

// ---------------------------------------------------------------------------
// Softmax per (i,h) row in place + vectorized zero of concat/optS.
// ---------------------------------------------------------------------------
__global__ void softmax_kernel(float* __restrict__ L, float* __restrict__ concat,
                               float* __restrict__ optS)
{
    int row = blockIdx.x;
    float* p = L + (size_t)row * NRES;
    int t = threadIdx.x;
    __shared__ float red[256];
    float v0 = p[t], v1 = p[t + 256];
    red[t] = fmaxf(v0, v1);
    __syncthreads();
    for (int s = 128; s > 0; s >>= 1) { if (t < s) red[t] = fmaxf(red[t], red[t + s]); __syncthreads(); }
    float m = red[0];
    __syncthreads();
    float e0 = expf(v0 - m), e1 = expf(v1 - m);
    red[t] = e0 + e1;
    __syncthreads();
    for (int s = 128; s > 0; s >>= 1) { if (t < s) red[t] += red[t + s]; __syncthreads(); }
    float inv = 1.f / red[0];
    p[t] = e0 * inv;
    p[t + 256] = e1 * inv;

    // zero downstream atomic-accumulation regions (float4)
    float4 z = {0.f, 0.f, 0.f, 0.f};
    unsigned gx = blockIdx.x * 256 + t, gs = gridDim.x * 256;
    for (unsigned x = gx; x < (unsigned)(NRES * OUT_DIM / 4); x += gs)
        ((float4*)concat)[x] = z;
    for (unsigned x = gx; x < (unsigned)(NRES * 288 / 4); x += gs)
        ((float4*)optS)[x] = z;
}

// ---------------------------------------------------------------------------
// o_pair: grid (512 i, 4 jh), 384 threads = (32 z-quads x 12 heads), 128 j.
// ---------------------------------------------------------------------------
__global__ __launch_bounds__(384) void opair_kernel(const float* __restrict__ pair,
                                                    const float* __restrict__ A,
                                                    float* __restrict__ concat)
{
    __shared__ float al[NH * 128];      // 6 KB
    int i = blockIdx.x, jh = blockIdx.y, t = threadIdx.x;
    if (t < 384) {
        int h = t / 32, j4 = t % 32;
        *(float4*)&al[(h * 32 + j4) * 4] =
            *(const float4*)&A[(size_t)i * NH * NRES + h * NRES + jh * 128 + j4 * 4];
    }
    __syncthreads();
    int zq = t & 31, h = t >> 5;
    float4 acc = {0.f, 0.f, 0.f, 0.f};
    const float* pr = pair + ((size_t)i * NRES + jh * 128) * CZ;
    const float* ah = al + h * 128;
    for (int j = 0; j < 128; ++j) {
        float4 p4 = *(const float4*)&pr[(size_t)j * CZ + zq * 4];
        float a = ah[j];
        acc.x = fmaf(a, p4.x, acc.x);
        acc.y = fmaf(a, p4.y, acc.y);
        acc.z = fmaf(a, p4.z, acc.z);
        acc.w = fmaf(a, p4.w, acc.w);
    }
    float* c = &concat[(size_t)i * OUT_DIM + 576 + h * 128 + zq * 4];
    atomicAdd(c + 0, acc.x);
    atomicAdd(c + 1, acc.y);
    atomicAdd(c + 2, acc.z);
    atomicAdd(c + 3, acc.w);
}

// ---------------------------------------------------------------------------
// o_v / o_pt partials: grid (512 i, 8 jq), 512 threads (480 active), 64 j.
// ---------------------------------------------------------------------------
__global__ __launch_bounds__(512) void ov_opt_kernel(const float* __restrict__ A,
                                                     const float* __restrict__ proj,
                                                     const float* __restrict__ gv,
                                                     float* __restrict__ concat,
                                                     float* __restrict__ optS)
{
    __shared__ float al[NH * 64];       // 3 KB
    int i = blockIdx.x, jq = blockIdx.y, t = threadIdx.x;
    if (t < 192) {
        int h = t / 16, j4 = t % 16;
        *(float4*)&al[(h * 16 + j4) * 4] =
            *(const float4*)&A[(size_t)i * NH * NRES + h * NRES + jq * 64 + j4 * 4];
    }
    __syncthreads();

    if (t < 480) {
        float acc = 0.f;
        if (t < 192) {
            int h = t >> 4;
            const float* ah = al + h * 64;
            const float* pv = proj + (size_t)(jq * 64) * PRJ + 384 + t;
            for (int j = 0; j < 64; ++j) { acc = fmaf(ah[j], *pv, acc); pv += PRJ; }
            atomicAdd(&concat[(size_t)i * OUT_DIM + t], acc);
        } else {
            int e = t - 192;
            int h = e / 24;
            const float* ah = al + h * 64;
            const float* pv = gv + (size_t)(jq * 64) * 288 + e;
            for (int j = 0; j < 64; ++j) { acc = fmaf(ah[j], *pv, acc); pv += 288; }
            atomicAdd(&optS[(size_t)i * 288 + e], acc);
        }
    }
}

// ---------------------------------------------------------------------------
// finalize: local = rot^T (o_pt - trans), norms -> concat
// ---------------------------------------------------------------------------
__global__ void finalize_pt_kernel(const float* __restrict__ optS, const float* __restrict__ rot,
                                   const float* __restrict__ trans, float* __restrict__ concat)
{
    int i = blockIdx.x, t = threadIdx.x;
    if (t >= 96) return;
    int h = t >> 3, p = t & 7;
    const float* o = optS + (size_t)i * 288 + h * 24 + p * 3;
    float b0 = o[0] - trans[i * 3 + 0];
    float b1 = o[1] - trans[i * 3 + 1];
    float b2 = o[2] - trans[i * 3 + 2];
    const float* Ri = rot + i * 9;
    float l0 = Ri[0] * b0 + Ri[3] * b1 + Ri[6] * b2;
    float l1 = Ri[1] * b0 + Ri[4] * b1 + Ri[7] * b2;
    float l2 = Ri[2] * b0 + Ri[5] * b1 + Ri[8] * b2;
    float* c = concat + (size_t)i * OUT_DIM;
    c[192 + h * 24 + p * 3 + 0] = l0;
    c[192 + h * 24 + p * 3 + 1] = l1;
    c[192 + h * 24 + p * 3 + 2] = l2;
    c[480 + h * 8 + p] = sqrtf(l0 * l0 + l1 * l1 + l2 * l2 + 1e-8f);
}

// ---------------------------------------------------------------------------
// LayerNorm over 384 (+ optional extra output: extraOut = extraB + y)
// ---------------------------------------------------------------------------
__global__ void ln_kernel(const float* __restrict__ x, const float* __restrict__ g,
                          const float* __restrict__ b, float* __restrict__ y,
                          const float* __restrict__ extraB, float* __restrict__ extraOut)
{
    int i = blockIdx.x, t = threadIdx.x;
    const float* xr = x + (size_t)i * CS;
    float a0 = xr[t], a1 = xr[t + 128], a2 = xr[t + 256];
    __shared__ float red[128];
    red[t] = a0 + a1 + a2;
    __syncthreads();
    for (int s = 64; s > 0; s >>= 1) { if (t < s) red[t] += red[t + s]; __syncthreads(); }
    float mean = red[0] * (1.f / CS);
    __syncthreads();
    float d0 = a0 - mean, d1 = a1 - mean, d2 = a2 - mean;
    red[t] = d0 * d0 + d1 * d1 + d2 * d2;
    __syncthreads();
    for (int s = 64; s > 0; s >>= 1) { if (t < s) red[t] += red[t + s]; __syncthreads(); }
    float rstd = rsqrtf(red[0] * (1.f / CS) + 1e-5f);
    float* yr = y + (size_t)i * CS;
    float y0 = d0 * rstd * g[t]       + b[t];
    float y1 = d1 * rstd * g[t + 128] + b[t + 128];
    float y2 = d2 * rstd * g[t + 256] + b[t + 256];
    yr[t] = y0; yr[t + 128] = y1; yr[t + 256] = y2;
    if (extraOut) {
        float* er = extraOut + (size_t)i * CS;
        er[t]       = extraB[t]       + y0;
        er[t + 128] = extraB[t + 128] + y1;
        er[t + 256] = extraB[t + 256] + y2;
    }
}

// ---------------------------------------------------------------------------
// Backbone (+ zero loss for the following loss kernel)
// ---------------------------------------------------------------------------
__global__ void backbone_kernel(const float* __restrict__ sfin, const float* __restrict__ Wbu,
                                const float* __restrict__ bbu, const float* __restrict__ rot,
                                const float* __restrict__ trans, float* __restrict__ rot_out,
                                float* __restrict__ trans_out, float* __restrict__ loss)
{
    int i = blockIdx.x, t = threadIdx.x;
    if (i == 0 && t == 0) *loss = 0.f;
    float part[6] = {0.f, 0.f, 0.f, 0.f, 0.f, 0.f};
    for (int k = t; k < CS; k += 128) {
        float s = sfin[(size_t)i * CS + k];
        const float* wr = Wbu + k * 6;
#pragma unroll
        for (int c = 0; c < 6; ++c) part[c] = fmaf(s, wr[c], part[c]);
    }
    __shared__ float red[6][128];
#pragma unroll
    for (int c = 0; c < 6; ++c) red[c][t] = part[c];
    __syncthreads();
    for (int s = 64; s > 0; s >>= 1) {
        if (t < s) {
#pragma unroll
            for (int c = 0; c < 6; ++c) red[c][t] += red[c][t + s];
        }
        __syncthreads();
    }
    if (t == 0) {
        float u[6];
#pragma unroll
        for (int c = 0; c < 6; ++c) u[c] = red[c][0] + bbu[c];
        float a = 1.f, b = u[0], c2 = u[1], d = u[2];
        float inv = rsqrtf(a * a + b * b + c2 * c2 + d * d);
        a *= inv; b *= inv; c2 *= inv; d *= inv;
        float R[9] = { a*a + b*b - c2*c2 - d*d, 2.f*(b*c2 - a*d),        2.f*(b*d + a*c2),
                       2.f*(b*c2 + a*d),        a*a - b*b + c2*c2 - d*d, 2.f*(c2*d - a*b),
                       2.f*(b*d - a*c2),        2.f*(c2*d + a*b),        a*a - b*b - c2*c2 + d*d };
        const float* Ri = rot + i * 9;
        float Rn[9];
#pragma unroll
        for (int r = 0; r < 3; ++r)
#pragma unroll
            for (int cc = 0; cc < 3; ++cc) {
                float s2 = 0.f;
#pragma unroll
                for (int kk = 0; kk < 3; ++kk) s2 += Ri[r * 3 + kk] * R[kk * 3 + cc];
                Rn[r * 3 + cc] = s2;
            }
#pragma unroll
        for (int r = 0; r < 9; ++r) rot_out[i * 9 + r] = Rn[r];
        float t0 = u[3], t1 = u[4], t2 = u[5];
#pragma unroll
        for (int r = 0; r < 3; ++r)
            trans_out[i * 3 + r] = Ri[r * 3 + 0] * t0 + Ri[r * 3 + 1] * t1 + Ri[r * 3 + 2] * t2 + trans[i * 3 + r];
    }
}

// ---------------------------------------------------------------------------
// Loss
// ---------------------------------------------------------------------------
__global__ void loss_kernel(const float* __restrict__ rot_new, const float* __restrict__ trans_new,
                            const float* __restrict__ rot_truth, const float* __restrict__ trans_truth,
                            float* __restrict__ loss)
{
    int i = blockIdx.x;
    int t = threadIdx.x;
    __shared__ float red[256];
    float Rn[9], Rt[9];
#pragma unroll
    for (int r = 0; r < 9; ++r) { Rn[r] = rot_new[i * 9 + r]; Rt[r] = rot_truth[i * 9 + r]; }
    float ti0 = trans_new[i * 3 + 0], ti1 = trans_new[i * 3 + 1], ti2 = trans_new[i * 3 + 2];
    float tt0 = trans_truth[i * 3 + 0], tt1 = trans_truth[i * 3 + 1], tt2 = trans_truth[i * 3 + 2];
    float s = 0.f;
    for (int j = t; j < NRES; j += 256) {
        float db0 = trans_new[j * 3 + 0] - ti0;
        float db1 = trans_new[j * 3 + 1] - ti1;
        float db2 = trans_new[j * 3 + 2] - ti2;
        float dp0 = Rn[0] * db0 + Rn[3] * db1 + Rn[6] * db2;
        float dp1 = Rn[1] * db0 + Rn[4] * db1 + Rn[7] * db2;
        float dp2 = Rn[2] * db0 + Rn[5] * db1 + Rn[8] * db2;
        float eb0 = trans_truth[j * 3 + 0] - tt0;
        float eb1 = trans_truth[j * 3 + 1] - tt1;
        float eb2 = trans_truth[j * 3 + 2] - tt2;
        float dt0 = Rt[0] * eb0 + Rt[3] * eb1 + Rt[6] * eb2;
        float dt1 = Rt[1] * eb0 + Rt[4] * eb1 + Rt[7] * eb2;
        float dt2 = Rt[2] * eb0 + Rt[5] * eb1 + Rt[8] * eb2;
        float dx = dp0 - dt0, dy = dp1 - dt1, dz = dp2 - dt2;
        float dd = sqrtf(dx * dx + dy * dy + dz * dz + 1e-12f);
        s += fminf(dd, 10.f);
    }
    red[t] = s;
    __syncthreads();
    for (int k = 128; k > 0; k >>= 1) { if (t < k) red[t] += red[t + k]; __syncthreads(); }
    if (t == 0) atomicAdd(loss, red[0] * (1.f / (512.f * 512.f * 10.f)));
}

// ---------------------------------------------------------------------------
extern "C" void kernel_launch(void* const* d_in, const int* in_sizes, int n_in,
                              void* d_out, int out_size, void* d_ws, size_t ws_size,
                              hipStream_t stream)
{
    const float* single      = (const float*)d_in[0];
    const float* pair        = (const float*)d_in[1];
    const float* rot         = (const float*)d_in[2];
    const float* trans       = (const float*)d_in[3];
    const float* rot_truth   = (const float*)d_in[4];
    const float* trans_truth = (const float*)d_in[5];
    const float* Wq  = (const float*)d_in[6];
    const float* Wk  = (const float*)d_in[7];
    const float* Wv  = (const float*)d_in[8];
    const float* Wqp = (const float*)d_in[9];
    const float* Wkp = (const float*)d_in[10];
    const float* Wvp = (const float*)d_in[11];
    const float* Wb  = (const float*)d_in[12];
    const float* Wo  = (const float*)d_in[13];
    const float* bo  = (const float*)d_in[14];
    const float* gamma_raw = (const float*)d_in[15];
    const float* ln1_g = (const float*)d_in[16];
    const float* ln1_b = (const float*)d_in[17];
    const float* ln2_g = (const float*)d_in[18];
    const float* ln2_b = (const float*)d_in[19];
    const float* W1 = (const float*)d_in[20];
    const float* b1 = (const float*)d_in[21];
    const float* W2 = (const float*)d_in[22];
    const float* b2 = (const float*)d_in[23];
    const float* W3 = (const float*)d_in[24];
    const float* b3 = (const float*)d_in[25];
    const float* Wbu = (const float*)d_in[26];
    const float* bbu = (const float*)d_in[27];

    float* out = (float*)d_out;
    float* single_out = out;                   // 512*384
    float* rot_out    = out + 196608;          // 512*9
    float* trans_out  = out + 201216;          // 512*3
    float* loss_out   = out + 202752;          // 1

    float* ws = (float*)d_ws;
    float* proj   = ws;                         // 589824
    float* gq     = proj   + 589824;            // 73728
    float* gv     = gq     + 73728;             // 147456
    float* sqq    = gv     + 147456;            // 6144
    float* kT     = sqq    + 6144;              // 98304
    float* gkT    = kT     + 98304;             // 73728
    float* sqkT   = gkT    + 73728;             // 6144
    float* wbfragf= sqkT   + 6144;              // 1024 (2048 ushorts)
    float* Amat   = wbfragf+ 1024;              // 3145728
    float* Bp     = Amat;                       // alias: dead after proj GEMM
    float* out2   = Amat;                       // alias: Amat dead after ov_opt
    float* optS   = kT;                         // alias: kT/gkT dead after logits
    float* concat = Amat   + 3145728;           // 1081344
    float* out1   = concat + 1081344;           // 196608
    float* sln    = out1   + 196608;            // 196608
    float* h1     = sln    + 196608;            // 196608
    float* h2     = h1     + 196608;            // 196608
    unsigned short* wbfrag = (unsigned short*)wbfragf;

    dim3 b256(256);

    // 1. pack weights (+ Wb frags + zero proj); projection GEMM (k-split 3)
    int pack_total = CS * PRJ + 2048 + NRES * PRJ;
    pack_proj_kernel<<<dim3((pack_total + 255) / 256), b256, 0, stream>>>(
        Wq, Wk, Wv, Wqp, Wkp, Wvp, Wb, Bp, wbfrag, proj);
    gemm_tiled<<<dim3(8, PRJ / 64, 3), b256, 0, stream>>>(single, Bp, nullptr, nullptr, proj,
                                                          NRES, CS, PRJ, 0, 128, 0);

    // 2. frames
    frames_kernel<<<dim3((NRES * NH + 255) / 256), b256, 0, stream>>>(proj, rot, trans,
                                                                      gq, gv, sqq, kT, gkT, sqkT);

    // 3. logits (reordered loads) + softmax
    logits_mfma_kernel<<<dim3(NRES, 16), dim3(128), 0, stream>>>(pair, proj, gq, kT, gkT,
                                                                 sqq, sqkT, wbfrag, gamma_raw,
                                                                 Amat);
    softmax_kernel<<<dim3(NRES * NH), b256, 0, stream>>>(Amat, concat, optS);

    // 4. attention outputs (deeper j-splits, atomic combine) + finalize
    opair_kernel<<<dim3(NRES, 4), dim3(384), 0, stream>>>(pair, Amat, concat);
    ov_opt_kernel<<<dim3(NRES, 8), dim3(512), 0, stream>>>(Amat, proj, gv, concat, optS);
    finalize_pt_kernel<<<dim3(NRES), dim3(96), 0, stream>>>(optS, rot, trans, concat);

    // 5. inits + Wo GEMM (k-split 6, atomic)
    init3_kernel<<<dim3((NRES * CS + 255) / 256), b256, 0, stream>>>(bo, single, b1, b2,
                                                                     out1, h1, h2);
    gemm_tiled<<<dim3(8, CS / 64, 6), b256, 0, stream>>>(concat, Wo, nullptr, nullptr, out1,
                                                         NRES, OUT_DIM, CS, 0, 352, 0);

    // 6. LN1 (also writes out2 = b3 + sln) + FF (k-split 6) + LN2
    ln_kernel<<<dim3(NRES), dim3(128), 0, stream>>>(out1, ln1_g, ln1_b, sln, b3, out2);
    gemm_tiled<<<dim3(8, CS / 64, 6), b256, 0, stream>>>(sln, W1, nullptr, nullptr, h1,
                                                         NRES, CS, CS, 0, 64, 0);
    gemm_tiled<<<dim3(8, CS / 64, 6), b256, 0, stream>>>(h1, W2, nullptr, nullptr, h2,
                                                         NRES, CS, CS, 0, 64, 1);
    gemm_tiled<<<dim3(8, CS / 64, 6), b256, 0, stream>>>(h2, W3, nullptr, nullptr, out2,
                                                         NRES, CS, CS, 0, 64, 1);
    ln_kernel<<<dim3(NRES), dim3(128), 0, stream>>>(out2, ln2_g, ln2_b, single_out,
                                                    nullptr, nullptr);

    // 7. backbone (zeroes loss) + loss
    backbone_kernel<<<dim3(NRES), dim3(128), 0, stream>>>(single_out, Wbu, bbu, rot, trans,
                                                          rot_out, trans_out, loss_out);
    loss_kernel<<<dim3(NRES), b256, 0, stream>>>(rot_out, trans_out, rot_truth, trans_truth,
                                                 loss_out);
}

// Round 13
// 278.032 us; speedup vs baseline: 1.1370x; 1.1370x over previous
//
#include <hip/hip_runtime.h>
#include <hip/hip_bf16.h>
#include <math.h>

#define NRES 512
#define CS 384
#define CZ 128
#define NH 12
#define PQ 4
#define PV 8
#define OUT_DIM 2112   // H*(C + 3*PV + PV + CZ)
#define PRJ 1152       // packed projection width: q192|k192|v192|qp144|kp144|vp288

typedef __attribute__((ext_vector_type(8))) short short8;
typedef __attribute__((ext_vector_type(4))) float f32x4;

__device__ __forceinline__ float softplusf(float x) { return log1pf(expf(x)); }

__device__ __forceinline__ unsigned short f2bf(float f) {
    union { float f; unsigned u; } v; v.f = f;
    unsigned r = v.u + 0x7FFF + ((v.u >> 16) & 1);
    return (unsigned short)(r >> 16);
}

__device__ __forceinline__ unsigned cvt_pk_bf16(float lo, float hi) {
    unsigned r;
    asm volatile("v_cvt_pk_bf16_f32 %0, %1, %2" : "=v"(r) : "v"(lo), "v"(hi));
    return r;
}

// ---------------------------------------------------------------------------
// Pack 6 projection weights into Bp[384][1152] + Wb MFMA B-fragments
// + zero proj (avoids slow runtime fillBuffer in-graph).
// ---------------------------------------------------------------------------
__global__ void pack_proj_kernel(const float* __restrict__ Wq, const float* __restrict__ Wk,
                                 const float* __restrict__ Wv, const float* __restrict__ Wqp,
                                 const float* __restrict__ Wkp, const float* __restrict__ Wvp,
                                 const float* __restrict__ Wb,
                                 float* __restrict__ Bp, unsigned short* __restrict__ wbfrag,
                                 float* __restrict__ proj)
{
    int x = blockIdx.x * blockDim.x + threadIdx.x;
    if (x < CS * PRJ) {
        int k = x / PRJ, c = x % PRJ;
        float v;
        if      (c < 192)  v = Wq [k * 192 + c];
        else if (c < 384)  v = Wk [k * 192 + (c - 192)];
        else if (c < 576)  v = Wv [k * 192 + (c - 384)];
        else if (c < 720)  v = Wqp[k * 144 + (c - 576)];
        else if (c < 864)  v = Wkp[k * 144 + (c - 720)];
        else               v = Wvp[k * 288 + (c - 864)];
        Bp[x] = v;
    } else if (x < CS * PRJ + 2048) {
        int idx = x - CS * PRJ;               // ks*512 + lane*8 + e
        int ks = idx >> 9, r = idx & 511;
        int lane = r >> 3, e = r & 7;
        int col = lane & 15, kb = (lane >> 4) * 8;
        int row = ks * 32 + kb + e;
        float v = (col < NH) ? Wb[row * NH + col] : 0.f;
        wbfrag[idx] = f2bf(v);
    } else {
        int idx = x - (CS * PRJ + 2048);
        if (idx < NRES * PRJ) proj[idx] = 0.f;
    }
}

// ---------------------------------------------------------------------------
// Tiled f32 GEMM: BM=64, BN=64, BK=16, 256 threads, 4x4 micro-tile.
// reluA: relu A on load. gridDim.z>1: k-split partial, atomicAdd into pre-init C.
// ---------------------------------------------------------------------------
__global__ void gemm_tiled(const float* __restrict__ A, const float* __restrict__ B,
                           const float* __restrict__ bias, const float* __restrict__ res,
                           float* __restrict__ C, int M, int K, int Nc, int relu, int KS,
                           int reluA)
{
    __shared__ float As[16][68];
    __shared__ float Bs[16][64];
    int m0 = blockIdx.x * 64, n0 = blockIdx.y * 64;
    int kbeg = blockIdx.z * KS;
    int t = threadIdx.x;
    int tm = t >> 4, tn = t & 15;
    int lr = t >> 2, lc4 = t & 3;
    int br = t >> 4, bc4 = t & 15;
    float acc[4][4] = {{0.f}};

    for (int kt = kbeg; kt < kbeg + KS; kt += 16) {
        float4 a4 = *(const float4*)&A[(size_t)(m0 + lr) * K + kt + lc4 * 4];
        float4 b4 = *(const float4*)&B[(size_t)(kt + br) * Nc + n0 + bc4 * 4];
        if (reluA) {
            a4.x = fmaxf(a4.x, 0.f); a4.y = fmaxf(a4.y, 0.f);
            a4.z = fmaxf(a4.z, 0.f); a4.w = fmaxf(a4.w, 0.f);
        }
        As[lc4 * 4 + 0][lr] = a4.x;
        As[lc4 * 4 + 1][lr] = a4.y;
        As[lc4 * 4 + 2][lr] = a4.z;
        As[lc4 * 4 + 3][lr] = a4.w;
        *(float4*)&Bs[br][bc4 * 4] = b4;
        __syncthreads();
#pragma unroll
        for (int k = 0; k < 16; ++k) {
            float4 av = *(const float4*)&As[k][tm * 4];
            float4 bv = *(const float4*)&Bs[k][tn * 4];
            acc[0][0] = fmaf(av.x, bv.x, acc[0][0]); acc[0][1] = fmaf(av.x, bv.y, acc[0][1]);
            acc[0][2] = fmaf(av.x, bv.z, acc[0][2]); acc[0][3] = fmaf(av.x, bv.w, acc[0][3]);
            acc[1][0] = fmaf(av.y, bv.x, acc[1][0]); acc[1][1] = fmaf(av.y, bv.y, acc[1][1]);
            acc[1][2] = fmaf(av.y, bv.z, acc[1][2]); acc[1][3] = fmaf(av.y, bv.w, acc[1][3]);
            acc[2][0] = fmaf(av.z, bv.x, acc[2][0]); acc[2][1] = fmaf(av.z, bv.y, acc[2][1]);
            acc[2][2] = fmaf(av.z, bv.z, acc[2][2]); acc[2][3] = fmaf(av.z, bv.w, acc[2][3]);
            acc[3][0] = fmaf(av.w, bv.x, acc[3][0]); acc[3][1] = fmaf(av.w, bv.y, acc[3][1]);
            acc[3][2] = fmaf(av.w, bv.z, acc[3][2]); acc[3][3] = fmaf(av.w, bv.w, acc[3][3]);
        }
        __syncthreads();
    }

    if (gridDim.z > 1) {
#pragma unroll
        for (int r = 0; r < 4; ++r)
#pragma unroll
            for (int c = 0; c < 4; ++c)
                atomicAdd(&C[(size_t)(m0 + tm * 4 + r) * Nc + n0 + tn * 4 + c], acc[r][c]);
    } else {
#pragma unroll
        for (int r = 0; r < 4; ++r) {
            int row = m0 + tm * 4 + r;
            float4 v;
            float* vp = (float*)&v;
#pragma unroll
            for (int c = 0; c < 4; ++c) {
                int col = n0 + tn * 4 + c;
                float x = acc[r][c];
                if (bias) x += bias[col];
                if (res)  x += res[(size_t)row * Nc + col];
                if (relu) x = fmaxf(x, 0.f);
                vp[c] = x;
            }
            *(float4*)&C[(size_t)row * Nc + n0 + tn * 4] = v;
        }
    }
}

// ---------------------------------------------------------------------------
// init: out[x] = bias[x % Nc] (+ res[x])
// ---------------------------------------------------------------------------
__global__ void init_bias_kernel(const float* __restrict__ bias, const float* __restrict__ res,
                                 float* __restrict__ out, int total, int Nc)
{
    int x = blockIdx.x * blockDim.x + threadIdx.x;
    if (x >= total) return;
    float v = bias[x % Nc];
    if (res) v += res[x];
    out[x] = v;
}

// ---------------------------------------------------------------------------
// Frames: one thread per (n, h).
// ---------------------------------------------------------------------------
__global__ void frames_kernel(const float* __restrict__ proj, const float* __restrict__ rot,
                              const float* __restrict__ trans,
                              float* __restrict__ gq, float* __restrict__ gv,
                              float* __restrict__ sqq,
                              float* __restrict__ kT, float* __restrict__ gkT,
                              float* __restrict__ sqkT)
{
    int x = blockIdx.x * blockDim.x + threadIdx.x;
    if (x >= NRES * NH) return;
    int n = x / NH, h = x % NH;
    float R[9], t3[3];
#pragma unroll
    for (int r = 0; r < 9; ++r) R[r] = rot[n * 9 + r];
#pragma unroll
    for (int r = 0; r < 3; ++r) t3[r] = trans[n * 3 + r];
    const float* qp = proj + (size_t)n * PRJ + 576 + h * (PQ * 3);
    const float* kp = proj + (size_t)n * PRJ + 720 + h * (PQ * 3);
    const float* vp = proj + (size_t)n * PRJ + 864 + h * (PV * 3);
    const float* kk = proj + (size_t)n * PRJ + 192 + h * 16;

#pragma unroll
    for (int c = 0; c < 16; ++c) kT[(h * 16 + c) * NRES + n] = kk[c];

    float sq = 0.f, sk = 0.f;
#pragma unroll
    for (int p = 0; p < PQ; ++p) {
        const float* in = qp + p * 3;
        float* og = gq + (size_t)n * 144 + h * (PQ * 3) + p * 3;
#pragma unroll
        for (int a = 0; a < 3; ++a) {
            float g = R[a*3+0]*in[0] + R[a*3+1]*in[1] + R[a*3+2]*in[2] + t3[a];
            og[a] = g; sq += g * g;
        }
        const float* in2 = kp + p * 3;
#pragma unroll
        for (int a = 0; a < 3; ++a) {
            float g = R[a*3+0]*in2[0] + R[a*3+1]*in2[1] + R[a*3+2]*in2[2] + t3[a];
            gkT[(h * 12 + p * 3 + a) * NRES + n] = g;
            sk += g * g;
        }
    }
    sqq[n * NH + h] = sq;
    sqkT[h * NRES + n] = sk;
#pragma unroll
    for (int p = 0; p < PV; ++p) {
        const float* in = vp + p * 3;
        float* og = gv + (size_t)n * 288 + h * (PV * 3) + p * 3;
#pragma unroll
        for (int a = 0; a < 3; ++a)
            og[a] = R[a*3+0]*in[0] + R[a*3+1]*in[1] + R[a*3+2]*in[2] + t3[a];
    }
}

// ---------------------------------------------------------------------------
// Logits (R8 config): grid (i=512, jt=8), block 256 (4 waves), one 64-j tile.
// Bias via bf16 MFMA from swizzled LDS (cvt_pk packing, prepacked Wb frags);
// qk/cross/d2 f32 with coalesced j-major loads + LDS-staged qi/gqi.
// ---------------------------------------------------------------------------
__global__ void logits_mfma_kernel(const float* __restrict__ pair, const float* __restrict__ proj,
                                   const float* __restrict__ gq, const float* __restrict__ kT,
                                   const float* __restrict__ gkT, const float* __restrict__ sqq,
                                   const float* __restrict__ sqkT,
                                   const unsigned short* __restrict__ wbfrag,
                                   const float* __restrict__ gamma_raw, float* __restrict__ L)
{
    __shared__ unsigned short pl[64 * 128];   // bf16 swizzled (16 KB)
    __shared__ float bias_s[64 * 17];
    __shared__ float qi[192], gqi[144], sqi[12], gam[12];

    int i = blockIdx.x, jt = blockIdx.y, t = threadIdx.x;
    int lane = t & 63, w = t >> 6;

    // prepacked Wb B-fragments (4 coalesced dwordx4 loads)
    short8 bfrag[4];
#pragma unroll
    for (int ks = 0; ks < 4; ++ks)
        bfrag[ks] = *(const short8*)&wbfrag[ks * 512 + lane * 8];

    for (int x = t; x < 192; x += 256) qi[x] = proj[(size_t)i * PRJ + x];
    for (int x = t; x < 144; x += 256) gqi[x] = gq[(size_t)i * 144 + x];
    if (t < 12) { sqi[t] = sqq[i * 12 + t]; gam[t] = softplusf(gamma_raw[t]); }

    // stage pair tile -> bf16 swizzled LDS (cvt_pk packing)
    const float* prow = pair + ((size_t)i * NRES + jt * 64) * CZ;
#pragma unroll
    for (int m = 0; m < 8; ++m) {
        int idx = m * 1024 + t * 4;
        int row = idx >> 7, kk = idx & 127;
        float4 v = *(const float4*)&prow[idx];
        unsigned b01 = cvt_pk_bf16(v.x, v.y);
        unsigned b23 = cvt_pk_bf16(v.z, v.w);
        int byte = row * 256 + ((kk * 2) ^ ((row & 7) << 4));
        *(uint2*)((char*)pl + byte) = make_uint2(b01, b23);
    }
    __syncthreads();

    // MFMA bias
    {
        f32x4 acc = {0.f, 0.f, 0.f, 0.f};
        int arow = w * 16 + (lane & 15);
        int kb2 = (lane >> 4) * 16;
#pragma unroll
        for (int ks = 0; ks < 4; ++ks) {
            int byte = arow * 256 + (((ks * 64) + kb2) ^ ((arow & 7) << 4));
            short8 afrag = *(const short8*)((const char*)pl + byte);
            acc = __builtin_amdgcn_mfma_f32_16x16x32_bf16(afrag, bfrag[ks], acc, 0, 0, 0);
        }
        int crow = w * 16 + (lane >> 4) * 4;
        int ccol = lane & 15;
#pragma unroll
        for (int r = 0; r < 4; ++r) bias_s[(crow + r) * 17 + ccol] = acc[r];
    }
    __syncthreads();

    // f32 epilogue
    const float WLc = 0.57735026918962576f;
    const float WCc = 0.23570226039551584f;
    int j = jt * 64 + lane;
#pragma unroll
    for (int hh = 0; hh < 3; ++hh) {
        int h = w * 3 + hh;
        float qk = 0.f;
#pragma unroll
        for (int c = 0; c < 16; ++c)
            qk = fmaf(qi[h * 16 + c], kT[(h * 16 + c) * NRES + j], qk);
        float cross = 0.f;
#pragma unroll
        for (int x = 0; x < 12; ++x)
            cross = fmaf(gqi[h * 12 + x], gkT[(h * 12 + x) * NRES + j], cross);
        float d2 = sqi[h] + sqkT[h * NRES + j] - 2.f * cross;
        float logit = WLc * (qk * 0.25f + bias_s[lane * 17 + h] - 0.5f * WCc * gam[h] * d2);
        L[((size_t)i * NH + h) * NRES + j] = logit;
    }
}

// ---------------------------------------------------------------------------
// Softmax over j per (i,h) row, in place. grid = 6144, block = 256
// ---------------------------------------------------------------------------
__global__ void softmax_kernel(float* __restrict__ L)
{
    int row = blockIdx.x;
    float* p = L + (size_t)row * NRES;
    int t = threadIdx.x;
    __shared__ float red[256];
    float v0 = p[t], v1 = p[t + 256];
    red[t] = fmaxf(v0, v1);
    __syncthreads();
    for (int s = 128; s > 0; s >>= 1) { if (t < s) red[t] = fmaxf(red[t], red[t + s]); __syncthreads(); }
    float m = red[0];
    __syncthreads();
    float e0 = expf(v0 - m), e1 = expf(v1 - m);
    red[t] = e0 + e1;
    __syncthreads();
    for (int s = 128; s > 0; s >>= 1) { if (t < s) red[t] += red[t + s]; __syncthreads(); }
    float inv = 1.f / red[0];
    p[t] = e0 * inv;
    p[t + 256] = e1 * inv;
}

// ---------------------------------------------------------------------------
// o_pair: block per i, 768 threads = (32 z-quads x 12 heads x 2 j-halves)
// In-block LDS combine, direct stores (no global atomics).
// ---------------------------------------------------------------------------
__global__ __launch_bounds__(768) void opair_kernel(const float* __restrict__ pair,
                                                    const float* __restrict__ A,
                                                    float* __restrict__ concat)
{
    __shared__ float al[NH * NRES];     // 24 KB
    __shared__ float4 part[384];        // 6 KB
    int i = blockIdx.x, t = threadIdx.x;
    for (int x = t; x < NH * NRES / 4; x += 768)
        *(float4*)&al[x * 4] = *(const float4*)&A[(size_t)i * NH * NRES + x * 4];
    __syncthreads();
    int jh = (t >= 384) ? 1 : 0;
    int u = t - jh * 384;
    int zq = u & 31, h = u >> 5;
    float4 acc = {0.f, 0.f, 0.f, 0.f};
    const float* pr = pair + (size_t)i * NRES * CZ + (size_t)jh * 256 * CZ;
    const float* ah = al + h * NRES + jh * 256;
    for (int j = 0; j < 256; ++j) {
        float4 p4 = *(const float4*)&pr[(size_t)j * CZ + zq * 4];
        float a = ah[j];
        acc.x = fmaf(a, p4.x, acc.x);
        acc.y = fmaf(a, p4.y, acc.y);
        acc.z = fmaf(a, p4.z, acc.z);
        acc.w = fmaf(a, p4.w, acc.w);
    }
    if (t >= 384) part[u] = acc;
    __syncthreads();
    if (t < 384) {
        float4 o = part[t];
        o.x += acc.x; o.y += acc.y; o.z += acc.z; o.w += acc.w;
        *(float4*)&concat[(size_t)i * OUT_DIM + 576 + h * 128 + zq * 4] = o;
    }
}

// ---------------------------------------------------------------------------
// o_v, o_pt, local, norms -> concat[i, 0..575]. block per i, 1024 threads:
// unit = (elem 0..479, j-half); elem<192: o_v, else o_pt.
// ---------------------------------------------------------------------------
__global__ __launch_bounds__(1024) void ov_opt_kernel(const float* __restrict__ A,
                                                      const float* __restrict__ proj,
                                                      const float* __restrict__ gv,
                                                      const float* __restrict__ rot,
                                                      const float* __restrict__ trans,
                                                      float* __restrict__ concat)
{
    __shared__ float al[NH * NRES];    // 24 KB
    __shared__ float part[960];
    __shared__ float opt[NH * PV * 3];
    int i = blockIdx.x, t = threadIdx.x;
    for (int x = t; x < NH * NRES / 4; x += 1024)
        *(float4*)&al[x * 4] = *(const float4*)&A[(size_t)i * NH * NRES + x * 4];
    __syncthreads();

    if (t < 960) {
        int jh = (t >= 480) ? 1 : 0;
        int elem = t - jh * 480;
        float acc = 0.f;
        if (elem < 192) {
            int h = elem >> 4;
            const float* ah = al + h * NRES + jh * 256;
            const float* pv = proj + (size_t)(jh * 256) * PRJ + 384 + elem;
            for (int j = 0; j < 256; ++j) { acc = fmaf(ah[j], *pv, acc); pv += PRJ; }
        } else {
            int e = elem - 192;
            int h = e / 24;
            const float* ah = al + h * NRES + jh * 256;
            const float* pv = gv + (size_t)(jh * 256) * 288 + e;
            for (int j = 0; j < 256; ++j) { acc = fmaf(ah[j], *pv, acc); pv += 288; }
        }
        part[t] = acc;
    }
    __syncthreads();
    if (t < 480) {
        float v = part[t] + part[t + 480];
        if (t < 192) concat[(size_t)i * OUT_DIM + t] = v;
        else opt[t - 192] = v;
    }
    __syncthreads();
    if (t < 96) {
        int h = t >> 3, p = t & 7;
        float b0 = opt[h * 24 + p * 3 + 0] - trans[i * 3 + 0];
        float b1 = opt[h * 24 + p * 3 + 1] - trans[i * 3 + 1];
        float b2 = opt[h * 24 + p * 3 + 2] - trans[i * 3 + 2];
        const float* Ri = rot + i * 9;
        float l0 = Ri[0] * b0 + Ri[3] * b1 + Ri[6] * b2;
        float l1 = Ri[1] * b0 + Ri[4] * b1 + Ri[7] * b2;
        float l2 = Ri[2] * b0 + Ri[5] * b1 + Ri[8] * b2;
        float* c = concat + (size_t)i * OUT_DIM;
        c[192 + h * 24 + p * 3 + 0] = l0;
        c[192 + h * 24 + p * 3 + 1] = l1;
        c[192 + h * 24 + p * 3 + 2] = l2;
        c[480 + h * 8 + p] = sqrtf(l0 * l0 + l1 * l1 + l2 * l2 + 1e-8f);
    }
}

// ---------------------------------------------------------------------------
// LayerNorm over 384
// ---------------------------------------------------------------------------
__global__ void ln_kernel(const float* __restrict__ x, const float* __restrict__ g,
                          const float* __restrict__ b, float* __restrict__ y)
{
    int i = blockIdx.x, t = threadIdx.x;
    const float* xr = x + (size_t)i * CS;
    float a0 = xr[t], a1 = xr[t + 128], a2 = xr[t + 256];
    __shared__ float red[128];
    red[t] = a0 + a1 + a2;
    __syncthreads();
    for (int s = 64; s > 0; s >>= 1) { if (t < s) red[t] += red[t + s]; __syncthreads(); }
    float mean = red[0] * (1.f / CS);
    __syncthreads();
    float d0 = a0 - mean, d1 = a1 - mean, d2 = a2 - mean;
    red[t] = d0 * d0 + d1 * d1 + d2 * d2;
    __syncthreads();
    for (int s = 64; s > 0; s >>= 1) { if (t < s) red[t] += red[t + s]; __syncthreads(); }
    float rstd = rsqrtf(red[0] * (1.f / CS) + 1e-5f);
    float* yr = y + (size_t)i * CS;
    yr[t]       = d0 * rstd * g[t]       + b[t];
    yr[t + 128] = d1 * rstd * g[t + 128] + b[t + 128];
    yr[t + 256] = d2 * rstd * g[t + 256] + b[t + 256];
}

// ---------------------------------------------------------------------------
// Backbone (+ zero loss for the following loss kernel)
// ---------------------------------------------------------------------------
__global__ void backbone_kernel(const float* __restrict__ sfin, const float* __restrict__ Wbu,
                                const float* __restrict__ bbu, const float* __restrict__ rot,
                                const float* __restrict__ trans, float* __restrict__ rot_out,
                                float* __restrict__ trans_out, float* __restrict__ loss)
{
    int i = blockIdx.x, t = threadIdx.x;
    if (i == 0 && t == 0) *loss = 0.f;
    float part[6] = {0.f, 0.f, 0.f, 0.f, 0.f, 0.f};
    for (int k = t; k < CS; k += 128) {
        float s = sfin[(size_t)i * CS + k];
        const float* wr = Wbu + k * 6;
#pragma unroll
        for (int c = 0; c < 6; ++c) part[c] = fmaf(s, wr[c], part[c]);
    }
    __shared__ float red[6][128];
#pragma unroll
    for (int c = 0; c < 6; ++c) red[c][t] = part[c];
    __syncthreads();
    for (int s = 64; s > 0; s >>= 1) {
        if (t < s) {
#pragma unroll
            for (int c = 0; c < 6; ++c) red[c][t] += red[c][t + s];
        }
        __syncthreads();
    }
    if (t == 0) {
        float u[6];
#pragma unroll
        for (int c = 0; c < 6; ++c) u[c] = red[c][0] + bbu[c];
        float a = 1.f, b = u[0], c2 = u[1], d = u[2];
        float inv = rsqrtf(a * a + b * b + c2 * c2 + d * d);
        a *= inv; b *= inv; c2 *= inv; d *= inv;
        float R[9] = { a*a + b*b - c2*c2 - d*d, 2.f*(b*c2 - a*d),        2.f*(b*d + a*c2),
                       2.f*(b*c2 + a*d),        a*a - b*b + c2*c2 - d*d, 2.f*(c2*d - a*b),
                       2.f*(b*d - a*c2),        2.f*(c2*d + a*b),        a*a - b*b - c2*c2 + d*d };
        const float* Ri = rot + i * 9;
        float Rn[9];
#pragma unroll
        for (int r = 0; r < 3; ++r)
#pragma unroll
            for (int cc = 0; cc < 3; ++cc) {
                float s2 = 0.f;
#pragma unroll
                for (int kk = 0; kk < 3; ++kk) s2 += Ri[r * 3 + kk] * R[kk * 3 + cc];
                Rn[r * 3 + cc] = s2;
            }
#pragma unroll
        for (int r = 0; r < 9; ++r) rot_out[i * 9 + r] = Rn[r];
        float t0 = u[3], t1 = u[4], t2 = u[5];
#pragma unroll
        for (int r = 0; r < 3; ++r)
            trans_out[i * 3 + r] = Ri[r * 3 + 0] * t0 + Ri[r * 3 + 1] * t1 + Ri[r * 3 + 2] * t2 + trans[i * 3 + r];
    }
}

// ---------------------------------------------------------------------------
// Loss
// ---------------------------------------------------------------------------
__global__ void loss_kernel(const float* __restrict__ rot_new, const float* __restrict__ trans_new,
                            const float* __restrict__ rot_truth, const float* __restrict__ trans_truth,
                            float* __restrict__ loss)
{
    int i = blockIdx.x;
    int t = threadIdx.x;
    __shared__ float red[256];
    float Rn[9], Rt[9];
#pragma unroll
    for (int r = 0; r < 9; ++r) { Rn[r] = rot_new[i * 9 + r]; Rt[r] = rot_truth[i * 9 + r]; }
    float ti0 = trans_new[i * 3 + 0], ti1 = trans_new[i * 3 + 1], ti2 = trans_new[i * 3 + 2];
    float tt0 = trans_truth[i * 3 + 0], tt1 = trans_truth[i * 3 + 1], tt2 = trans_truth[i * 3 + 2];
    float s = 0.f;
    for (int j = t; j < NRES; j += 256) {
        float db0 = trans_new[j * 3 + 0] - ti0;
        float db1 = trans_new[j * 3 + 1] - ti1;
        float db2 = trans_new[j * 3 + 2] - ti2;
        float dp0 = Rn[0] * db0 + Rn[3] * db1 + Rn[6] * db2;
        float dp1 = Rn[1] * db0 + Rn[4] * db1 + Rn[7] * db2;
        float dp2 = Rn[2] * db0 + Rn[5] * db1 + Rn[8] * db2;
        float eb0 = trans_truth[j * 3 + 0] - tt0;
        float eb1 = trans_truth[j * 3 + 1] - tt1;
        float eb2 = trans_truth[j * 3 + 2] - tt2;
        float dt0 = Rt[0] * eb0 + Rt[3] * eb1 + Rt[6] * eb2;
        float dt1 = Rt[1] * eb0 + Rt[4] * eb1 + Rt[7] * eb2;
        float dt2 = Rt[2] * eb0 + Rt[5] * eb1 + Rt[8] * eb2;
        float dx = dp0 - dt0, dy = dp1 - dt1, dz = dp2 - dt2;
        float dd = sqrtf(dx * dx + dy * dy + dz * dz + 1e-12f);
        s += fminf(dd, 10.f);
    }
    red[t] = s;
    __syncthreads();
    for (int k = 128; k > 0; k >>= 1) { if (t < k) red[t] += red[t + k]; __syncthreads(); }
    if (t == 0) atomicAdd(loss, red[0] * (1.f / (512.f * 512.f * 10.f)));
}

// ---------------------------------------------------------------------------
extern "C" void kernel_launch(void* const* d_in, const int* in_sizes, int n_in,
                              void* d_out, int out_size, void* d_ws, size_t ws_size,
                              hipStream_t stream)
{
    const float* single      = (const float*)d_in[0];
    const float* pair        = (const float*)d_in[1];
    const float* rot         = (const float*)d_in[2];
    const float* trans       = (const float*)d_in[3];
    const float* rot_truth   = (const float*)d_in[4];
    const float* trans_truth = (const float*)d_in[5];
    const float* Wq  = (const float*)d_in[6];
    const float* Wk  = (const float*)d_in[7];
    const float* Wv  = (const float*)d_in[8];
    const float* Wqp = (const float*)d_in[9];
    const float* Wkp = (const float*)d_in[10];
    const float* Wvp = (const float*)d_in[11];
    const float* Wb  = (const float*)d_in[12];
    const float* Wo  = (const float*)d_in[13];
    const float* bo  = (const float*)d_in[14];
    const float* gamma_raw = (const float*)d_in[15];
    const float* ln1_g = (const float*)d_in[16];
    const float* ln1_b = (const float*)d_in[17];
    const float* ln2_g = (const float*)d_in[18];
    const float* ln2_b = (const float*)d_in[19];
    const float* W1 = (const float*)d_in[20];
    const float* b1 = (const float*)d_in[21];
    const float* W2 = (const float*)d_in[22];
    const float* b2 = (const float*)d_in[23];
    const float* W3 = (const float*)d_in[24];
    const float* b3 = (const float*)d_in[25];
    const float* Wbu = (const float*)d_in[26];
    const float* bbu = (const float*)d_in[27];

    float* out = (float*)d_out;
    float* single_out = out;                   // 512*384
    float* rot_out    = out + 196608;          // 512*9
    float* trans_out  = out + 201216;          // 512*3
    float* loss_out   = out + 202752;          // 1

    float* ws = (float*)d_ws;
    float* proj   = ws;                         // 589824
    float* gq     = proj   + 589824;            // 73728
    float* gv     = gq     + 73728;             // 147456
    float* sqq    = gv     + 147456;            // 6144
    float* kT     = sqq    + 6144;              // 98304
    float* gkT    = kT     + 98304;             // 73728
    float* sqkT   = gkT    + 73728;             // 6144
    float* wbfragf= sqkT   + 6144;              // 1024 (2048 ushorts)
    float* Amat   = wbfragf+ 1024;              // 3145728
    float* Bp     = Amat;                       // alias: dead after proj GEMM
    float* concat = Amat   + 3145728;           // 1081344
    float* out1   = concat + 1081344;           // 196608
    float* sln    = out1   + 196608;            // 196608
    float* h1     = sln    + 196608;            // 196608
    float* h2     = h1     + 196608;            // 196608
    unsigned short* wbfrag = (unsigned short*)wbfragf;

    dim3 b256(256);

    // 1. pack weights (+ Wb frags + zero proj); projection GEMM (k-split 2)
    int pack_total = CS * PRJ + 2048 + NRES * PRJ;
    pack_proj_kernel<<<dim3((pack_total + 255) / 256), b256, 0, stream>>>(
        Wq, Wk, Wv, Wqp, Wkp, Wvp, Wb, Bp, wbfrag, proj);
    gemm_tiled<<<dim3(8, PRJ / 64, 2), b256, 0, stream>>>(single, Bp, nullptr, nullptr, proj,
                                                          NRES, CS, PRJ, 0, 192, 0);

    // 2. frames
    frames_kernel<<<dim3((NRES * NH + 255) / 256), b256, 0, stream>>>(proj, rot, trans,
                                                                      gq, gv, sqq, kT, gkT, sqkT);

    // 3. logits (R8 config: grid 512x8, 256 thr) + softmax
    logits_mfma_kernel<<<dim3(NRES, 8), b256, 0, stream>>>(pair, proj, gq, kT, gkT, sqq, sqkT,
                                                           wbfrag, gamma_raw, Amat);
    softmax_kernel<<<dim3(NRES * NH), b256, 0, stream>>>(Amat);

    // 4. attention outputs (in-block j-splits, no global atomics)
    opair_kernel<<<dim3(NRES), dim3(768), 0, stream>>>(pair, Amat, concat);
    ov_opt_kernel<<<dim3(NRES), dim3(1024), 0, stream>>>(Amat, proj, gv, rot, trans, concat);

    // 5. ipa_out = concat @ Wo + bo + single  (k-split 4, atomic into pre-init)
    init_bias_kernel<<<dim3((NRES * CS + 255) / 256), b256, 0, stream>>>(bo, single, out1,
                                                                         NRES * CS, CS);
    gemm_tiled<<<dim3(8, CS / 64, 4), b256, 0, stream>>>(concat, Wo, nullptr, nullptr, out1,
                                                         NRES, OUT_DIM, CS, 0, 528, 0);

    // 6. LN1 + FF (k-split 4, relu folded into consumer A-load) + LN2
    ln_kernel<<<dim3(NRES), dim3(128), 0, stream>>>(out1, ln1_g, ln1_b, sln);
    init_bias_kernel<<<dim3((NRES * CS + 255) / 256), b256, 0, stream>>>(b1, nullptr, h1,
                                                                         NRES * CS, CS);
    init_bias_kernel<<<dim3((NRES * CS + 255) / 256), b256, 0, stream>>>(b2, nullptr, h2,
                                                                         NRES * CS, CS);
    gemm_tiled<<<dim3(8, CS / 64, 4), b256, 0, stream>>>(sln, W1, nullptr, nullptr, h1,
                                                         NRES, CS, CS, 0, 96, 0);
    gemm_tiled<<<dim3(8, CS / 64, 4), b256, 0, stream>>>(h1, W2, nullptr, nullptr, h2,
                                                         NRES, CS, CS, 0, 96, 1);
    init_bias_kernel<<<dim3((NRES * CS + 255) / 256), b256, 0, stream>>>(b3, sln, out1,
                                                                         NRES * CS, CS);
    gemm_tiled<<<dim3(8, CS / 64, 4), b256, 0, stream>>>(h2, W3, nullptr, nullptr, out1,
                                                         NRES, CS, CS, 0, 96, 1);
    ln_kernel<<<dim3(NRES), dim3(128), 0, stream>>>(out1, ln2_g, ln2_b, single_out);

    // 7. backbone (zeroes loss) + loss
    backbone_kernel<<<dim3(NRES), dim3(128), 0, stream>>>(single_out, Wbu, bbu, rot, trans,
                                                          rot_out, trans_out, loss_out);
    loss_kernel<<<dim3(NRES), b256, 0, stream>>>(rot_out, trans_out, rot_truth, trans_truth,
                                                 loss_out);
}

// Round 14
// 277.391 us; speedup vs baseline: 1.1396x; 1.0023x over previous
//
#include <hip/hip_runtime.h>
#include <hip/hip_bf16.h>
#include <math.h>

#define NRES 512
#define CS 384
#define CZ 128
#define NH 12
#define PQ 4
#define PV 8
#define OUT_DIM 2112   // H*(C + 3*PV + PV + CZ)
#define PRJ 1152       // packed projection width: q192|k192|v192|qp144|kp144|vp288

typedef __attribute__((ext_vector_type(8))) short short8;
typedef __attribute__((ext_vector_type(4))) float f32x4;

__device__ __forceinline__ float softplusf(float x) { return log1pf(expf(x)); }

__device__ __forceinline__ unsigned short f2bf(float f) {
    union { float f; unsigned u; } v; v.f = f;
    unsigned r = v.u + 0x7FFF + ((v.u >> 16) & 1);
    return (unsigned short)(r >> 16);
}

__device__ __forceinline__ unsigned cvt_pk_bf16(float lo, float hi) {
    unsigned r;
    asm volatile("v_cvt_pk_bf16_f32 %0, %1, %2" : "=v"(r) : "v"(lo), "v"(hi));
    return r;
}

// ---------------------------------------------------------------------------
// Pack 6 projection weights into Bp[384][1152] + Wb MFMA B-fragments
// + zero proj (avoids slow runtime fillBuffer in-graph).
// ---------------------------------------------------------------------------
__global__ void pack_proj_kernel(const float* __restrict__ Wq, const float* __restrict__ Wk,
                                 const float* __restrict__ Wv, const float* __restrict__ Wqp,
                                 const float* __restrict__ Wkp, const float* __restrict__ Wvp,
                                 const float* __restrict__ Wb,
                                 float* __restrict__ Bp, unsigned short* __restrict__ wbfrag,
                                 float* __restrict__ proj)
{
    int x = blockIdx.x * blockDim.x + threadIdx.x;
    if (x < CS * PRJ) {
        int k = x / PRJ, c = x % PRJ;
        float v;
        if      (c < 192)  v = Wq [k * 192 + c];
        else if (c < 384)  v = Wk [k * 192 + (c - 192)];
        else if (c < 576)  v = Wv [k * 192 + (c - 384)];
        else if (c < 720)  v = Wqp[k * 144 + (c - 576)];
        else if (c < 864)  v = Wkp[k * 144 + (c - 720)];
        else               v = Wvp[k * 288 + (c - 864)];
        Bp[x] = v;
    } else if (x < CS * PRJ + 2048) {
        int idx = x - CS * PRJ;               // ks*512 + lane*8 + e
        int ks = idx >> 9, r = idx & 511;
        int lane = r >> 3, e = r & 7;
        int col = lane & 15, kb = (lane >> 4) * 8;
        int row = ks * 32 + kb + e;
        float v = (col < NH) ? Wb[row * NH + col] : 0.f;
        wbfrag[idx] = f2bf(v);
    } else {
        int idx = x - (CS * PRJ + 2048);
        if (idx < NRES * PRJ) proj[idx] = 0.f;
    }
}

// ---------------------------------------------------------------------------
// Tiled f32 GEMM: BM=64, BN=64, BK=16, 256 threads, 4x4 micro-tile.
// reluA: relu A on load. gridDim.z>1: k-split partial, atomicAdd into pre-init C.
// ---------------------------------------------------------------------------
__global__ void gemm_tiled(const float* __restrict__ A, const float* __restrict__ B,
                           const float* __restrict__ bias, const float* __restrict__ res,
                           float* __restrict__ C, int M, int K, int Nc, int relu, int KS,
                           int reluA)
{
    __shared__ float As[16][68];
    __shared__ float Bs[16][64];
    int m0 = blockIdx.x * 64, n0 = blockIdx.y * 64;
    int kbeg = blockIdx.z * KS;
    int t = threadIdx.x;
    int tm = t >> 4, tn = t & 15;
    int lr = t >> 2, lc4 = t & 3;
    int br = t >> 4, bc4 = t & 15;
    float acc[4][4] = {{0.f}};

    for (int kt = kbeg; kt < kbeg + KS; kt += 16) {
        float4 a4 = *(const float4*)&A[(size_t)(m0 + lr) * K + kt + lc4 * 4];
        float4 b4 = *(const float4*)&B[(size_t)(kt + br) * Nc + n0 + bc4 * 4];
        if (reluA) {
            a4.x = fmaxf(a4.x, 0.f); a4.y = fmaxf(a4.y, 0.f);
            a4.z = fmaxf(a4.z, 0.f); a4.w = fmaxf(a4.w, 0.f);
        }
        As[lc4 * 4 + 0][lr] = a4.x;
        As[lc4 * 4 + 1][lr] = a4.y;
        As[lc4 * 4 + 2][lr] = a4.z;
        As[lc4 * 4 + 3][lr] = a4.w;
        *(float4*)&Bs[br][bc4 * 4] = b4;
        __syncthreads();
#pragma unroll
        for (int k = 0; k < 16; ++k) {
            float4 av = *(const float4*)&As[k][tm * 4];
            float4 bv = *(const float4*)&Bs[k][tn * 4];
            acc[0][0] = fmaf(av.x, bv.x, acc[0][0]); acc[0][1] = fmaf(av.x, bv.y, acc[0][1]);
            acc[0][2] = fmaf(av.x, bv.z, acc[0][2]); acc[0][3] = fmaf(av.x, bv.w, acc[0][3]);
            acc[1][0] = fmaf(av.y, bv.x, acc[1][0]); acc[1][1] = fmaf(av.y, bv.y, acc[1][1]);
            acc[1][2] = fmaf(av.y, bv.z, acc[1][2]); acc[1][3] = fmaf(av.y, bv.w, acc[1][3]);
            acc[2][0] = fmaf(av.z, bv.x, acc[2][0]); acc[2][1] = fmaf(av.z, bv.y, acc[2][1]);
            acc[2][2] = fmaf(av.z, bv.z, acc[2][2]); acc[2][3] = fmaf(av.z, bv.w, acc[2][3]);
            acc[3][0] = fmaf(av.w, bv.x, acc[3][0]); acc[3][1] = fmaf(av.w, bv.y, acc[3][1]);
            acc[3][2] = fmaf(av.w, bv.z, acc[3][2]); acc[3][3] = fmaf(av.w, bv.w, acc[3][3]);
        }
        __syncthreads();
    }

    if (gridDim.z > 1) {
#pragma unroll
        for (int r = 0; r < 4; ++r)
#pragma unroll
            for (int c = 0; c < 4; ++c)
                atomicAdd(&C[(size_t)(m0 + tm * 4 + r) * Nc + n0 + tn * 4 + c], acc[r][c]);
    } else {
#pragma unroll
        for (int r = 0; r < 4; ++r) {
            int row = m0 + tm * 4 + r;
            float4 v;
            float* vp = (float*)&v;
#pragma unroll
            for (int c = 0; c < 4; ++c) {
                int col = n0 + tn * 4 + c;
                float x = acc[r][c];
                if (bias) x += bias[col];
                if (res)  x += res[(size_t)row * Nc + col];
                if (relu) x = fmaxf(x, 0.f);
                vp[c] = x;
            }
            *(float4*)&C[(size_t)row * Nc + n0 + tn * 4] = v;
        }
    }
}

// ---------------------------------------------------------------------------
// init: out[x] = bias[x % Nc] (+ res[x])
// ---------------------------------------------------------------------------
__global__ void init_bias_kernel(const float* __restrict__ bias, const float* __restrict__ res,
                                 float* __restrict__ out, int total, int Nc)
{
    int x = blockIdx.x * blockDim.x + threadIdx.x;
    if (x >= total) return;
    float v = bias[x % Nc];
    if (res) v += res[x];
    out[x] = v;
}

// ---------------------------------------------------------------------------
// Frames: one thread per (n, h).
// ---------------------------------------------------------------------------
__global__ void frames_kernel(const float* __restrict__ proj, const float* __restrict__ rot,
                              const float* __restrict__ trans,
                              float* __restrict__ gq, float* __restrict__ gv,
                              float* __restrict__ sqq,
                              float* __restrict__ kT, float* __restrict__ gkT,
                              float* __restrict__ sqkT)
{
    int x = blockIdx.x * blockDim.x + threadIdx.x;
    if (x >= NRES * NH) return;
    int n = x / NH, h = x % NH;
    float R[9], t3[3];
#pragma unroll
    for (int r = 0; r < 9; ++r) R[r] = rot[n * 9 + r];
#pragma unroll
    for (int r = 0; r < 3; ++r) t3[r] = trans[n * 3 + r];
    const float* qp = proj + (size_t)n * PRJ + 576 + h * (PQ * 3);
    const float* kp = proj + (size_t)n * PRJ + 720 + h * (PQ * 3);
    const float* vp = proj + (size_t)n * PRJ + 864 + h * (PV * 3);
    const float* kk = proj + (size_t)n * PRJ + 192 + h * 16;

#pragma unroll
    for (int c = 0; c < 16; ++c) kT[(h * 16 + c) * NRES + n] = kk[c];

    float sq = 0.f, sk = 0.f;
#pragma unroll
    for (int p = 0; p < PQ; ++p) {
        const float* in = qp + p * 3;
        float* og = gq + (size_t)n * 144 + h * (PQ * 3) + p * 3;
#pragma unroll
        for (int a = 0; a < 3; ++a) {
            float g = R[a*3+0]*in[0] + R[a*3+1]*in[1] + R[a*3+2]*in[2] + t3[a];
            og[a] = g; sq += g * g;
        }
        const float* in2 = kp + p * 3;
#pragma unroll
        for (int a = 0; a < 3; ++a) {
            float g = R[a*3+0]*in2[0] + R[a*3+1]*in2[1] + R[a*3+2]*in2[2] + t3[a];
            gkT[(h * 12 + p * 3 + a) * NRES + n] = g;
            sk += g * g;
        }
    }
    sqq[n * NH + h] = sq;
    sqkT[h * NRES + n] = sk;
#pragma unroll
    for (int p = 0; p < PV; ++p) {
        const float* in = vp + p * 3;
        float* og = gv + (size_t)n * 288 + h * (PV * 3) + p * 3;
#pragma unroll
        for (int a = 0; a < 3; ++a)
            og[a] = R[a*3+0]*in[0] + R[a*3+1]*in[1] + R[a*3+2]*in[2] + t3[a];
    }
}

// ---------------------------------------------------------------------------
// Logits v8: grid (i=512, jt=8), block 256 (4 waves), one 64-j tile.
// MFMA A-fragments loaded DIRECTLY from global pair (no staging LDS,
// one barrier): lane l of wave w reads rows w*16+(l&15), z = ks*32+(l>>4)*8.
// Only LDS is the 4.25 KB bias redistribution buffer + small per-i arrays.
// ---------------------------------------------------------------------------
__global__ void logits_mfma_kernel(const float* __restrict__ pair, const float* __restrict__ proj,
                                   const float* __restrict__ gq, const float* __restrict__ kT,
                                   const float* __restrict__ gkT, const float* __restrict__ sqq,
                                   const float* __restrict__ sqkT,
                                   const unsigned short* __restrict__ wbfrag,
                                   const float* __restrict__ gamma_raw, float* __restrict__ L)
{
    __shared__ float bias_s[64 * 17];         // 4.25 KB
    __shared__ float qi[192], gqi[144], sqi[12], gam[12];

    int i = blockIdx.x, jt = blockIdx.y, t = threadIdx.x;
    int lane = t & 63, w = t >> 6;

    // issue MFMA A-operand loads straight from global pair (8 float4s)
    int arow = w * 16 + (lane & 15);                  // j within 64-tile
    int zofs = (lane >> 4) * 8;                       // z base within 32-chunk
    const float* arow_p = pair + ((size_t)i * NRES + jt * 64 + arow) * CZ + zofs;
    float4 a0 = *(const float4*)(arow_p + 0);
    float4 a1 = *(const float4*)(arow_p + 4);
    float4 b0 = *(const float4*)(arow_p + 32);
    float4 b1 = *(const float4*)(arow_p + 36);
    float4 c0 = *(const float4*)(arow_p + 64);
    float4 c1 = *(const float4*)(arow_p + 68);
    float4 d0 = *(const float4*)(arow_p + 96);
    float4 d1 = *(const float4*)(arow_p + 100);

    // prepacked Wb B-fragments (4 coalesced dwordx4 loads, L2-hot)
    short8 bfrag[4];
#pragma unroll
    for (int ks = 0; ks < 4; ++ks)
        bfrag[ks] = *(const short8*)&wbfrag[ks * 512 + lane * 8];

    // per-i small staging (runs while pair loads are in flight)
    for (int x = t; x < 192; x += 256) qi[x] = proj[(size_t)i * PRJ + x];
    for (int x = t; x < 144; x += 256) gqi[x] = gq[(size_t)i * 144 + x];
    if (t < 12) { sqi[t] = sqq[i * 12 + t]; gam[t] = softplusf(gamma_raw[t]); }

    // convert + MFMA (no staging LDS, no barrier before this)
    {
        f32x4 acc = {0.f, 0.f, 0.f, 0.f};
        short8 f;
        unsigned* fu = (unsigned*)&f;
        fu[0] = cvt_pk_bf16(a0.x, a0.y); fu[1] = cvt_pk_bf16(a0.z, a0.w);
        fu[2] = cvt_pk_bf16(a1.x, a1.y); fu[3] = cvt_pk_bf16(a1.z, a1.w);
        acc = __builtin_amdgcn_mfma_f32_16x16x32_bf16(f, bfrag[0], acc, 0, 0, 0);
        fu[0] = cvt_pk_bf16(b0.x, b0.y); fu[1] = cvt_pk_bf16(b0.z, b0.w);
        fu[2] = cvt_pk_bf16(b1.x, b1.y); fu[3] = cvt_pk_bf16(b1.z, b1.w);
        acc = __builtin_amdgcn_mfma_f32_16x16x32_bf16(f, bfrag[1], acc, 0, 0, 0);
        fu[0] = cvt_pk_bf16(c0.x, c0.y); fu[1] = cvt_pk_bf16(c0.z, c0.w);
        fu[2] = cvt_pk_bf16(c1.x, c1.y); fu[3] = cvt_pk_bf16(c1.z, c1.w);
        acc = __builtin_amdgcn_mfma_f32_16x16x32_bf16(f, bfrag[2], acc, 0, 0, 0);
        fu[0] = cvt_pk_bf16(d0.x, d0.y); fu[1] = cvt_pk_bf16(d0.z, d0.w);
        fu[2] = cvt_pk_bf16(d1.x, d1.y); fu[3] = cvt_pk_bf16(d1.z, d1.w);
        acc = __builtin_amdgcn_mfma_f32_16x16x32_bf16(f, bfrag[3], acc, 0, 0, 0);
        int crow = w * 16 + (lane >> 4) * 4;
        int ccol = lane & 15;
#pragma unroll
        for (int r = 0; r < 4; ++r) bias_s[(crow + r) * 17 + ccol] = acc[r];
    }
    __syncthreads();

    // f32 epilogue
    const float WLc = 0.57735026918962576f;
    const float WCc = 0.23570226039551584f;
    int j = jt * 64 + lane;
#pragma unroll
    for (int hh = 0; hh < 3; ++hh) {
        int h = w * 3 + hh;
        float qk = 0.f;
#pragma unroll
        for (int c = 0; c < 16; ++c)
            qk = fmaf(qi[h * 16 + c], kT[(h * 16 + c) * NRES + j], qk);
        float cross = 0.f;
#pragma unroll
        for (int x = 0; x < 12; ++x)
            cross = fmaf(gqi[h * 12 + x], gkT[(h * 12 + x) * NRES + j], cross);
        float d2 = sqi[h] + sqkT[h * NRES + j] - 2.f * cross;
        float logit = WLc * (qk * 0.25f + bias_s[lane * 17 + h] - 0.5f * WCc * gam[h] * d2);
        L[((size_t)i * NH + h) * NRES + j] = logit;
    }
}

// ---------------------------------------------------------------------------
// Softmax over j per (i,h) row, in place. grid = 6144, block = 256
// ---------------------------------------------------------------------------
__global__ void softmax_kernel(float* __restrict__ L)
{
    int row = blockIdx.x;
    float* p = L + (size_t)row * NRES;
    int t = threadIdx.x;
    __shared__ float red[256];
    float v0 = p[t], v1 = p[t + 256];
    red[t] = fmaxf(v0, v1);
    __syncthreads();
    for (int s = 128; s > 0; s >>= 1) { if (t < s) red[t] = fmaxf(red[t], red[t + s]); __syncthreads(); }
    float m = red[0];
    __syncthreads();
    float e0 = expf(v0 - m), e1 = expf(v1 - m);
    red[t] = e0 + e1;
    __syncthreads();
    for (int s = 128; s > 0; s >>= 1) { if (t < s) red[t] += red[t + s]; __syncthreads(); }
    float inv = 1.f / red[0];
    p[t] = e0 * inv;
    p[t + 256] = e1 * inv;
}

// ---------------------------------------------------------------------------
// o_pair: block per i, 768 threads = (32 z-quads x 12 heads x 2 j-halves)
// In-block LDS combine, direct stores (no global atomics).
// ---------------------------------------------------------------------------
__global__ __launch_bounds__(768) void opair_kernel(const float* __restrict__ pair,
                                                    const float* __restrict__ A,
                                                    float* __restrict__ concat)
{
    __shared__ float al[NH * NRES];     // 24 KB
    __shared__ float4 part[384];        // 6 KB
    int i = blockIdx.x, t = threadIdx.x;
    for (int x = t; x < NH * NRES / 4; x += 768)
        *(float4*)&al[x * 4] = *(const float4*)&A[(size_t)i * NH * NRES + x * 4];
    __syncthreads();
    int jh = (t >= 384) ? 1 : 0;
    int u = t - jh * 384;
    int zq = u & 31, h = u >> 5;
    float4 acc = {0.f, 0.f, 0.f, 0.f};
    const float* pr = pair + (size_t)i * NRES * CZ + (size_t)jh * 256 * CZ;
    const float* ah = al + h * NRES + jh * 256;
    for (int j = 0; j < 256; ++j) {
        float4 p4 = *(const float4*)&pr[(size_t)j * CZ + zq * 4];
        float a = ah[j];
        acc.x = fmaf(a, p4.x, acc.x);
        acc.y = fmaf(a, p4.y, acc.y);
        acc.z = fmaf(a, p4.z, acc.z);
        acc.w = fmaf(a, p4.w, acc.w);
    }
    if (t >= 384) part[u] = acc;
    __syncthreads();
    if (t < 384) {
        float4 o = part[t];
        o.x += acc.x; o.y += acc.y; o.z += acc.z; o.w += acc.w;
        *(float4*)&concat[(size_t)i * OUT_DIM + 576 + h * 128 + zq * 4] = o;
    }
}

// ---------------------------------------------------------------------------
// o_v, o_pt, local, norms -> concat[i, 0..575]. block per i, 1024 threads:
// unit = (elem 0..479, j-half); elem<192: o_v, else o_pt.
// ---------------------------------------------------------------------------
__global__ __launch_bounds__(1024) void ov_opt_kernel(const float* __restrict__ A,
                                                      const float* __restrict__ proj,
                                                      const float* __restrict__ gv,
                                                      const float* __restrict__ rot,
                                                      const float* __restrict__ trans,
                                                      float* __restrict__ concat)
{
    __shared__ float al[NH * NRES];    // 24 KB
    __shared__ float part[960];
    __shared__ float opt[NH * PV * 3];
    int i = blockIdx.x, t = threadIdx.x;
    for (int x = t; x < NH * NRES / 4; x += 1024)
        *(float4*)&al[x * 4] = *(const float4*)&A[(size_t)i * NH * NRES + x * 4];
    __syncthreads();

    if (t < 960) {
        int jh = (t >= 480) ? 1 : 0;
        int elem = t - jh * 480;
        float acc = 0.f;
        if (elem < 192) {
            int h = elem >> 4;
            const float* ah = al + h * NRES + jh * 256;
            const float* pv = proj + (size_t)(jh * 256) * PRJ + 384 + elem;
            for (int j = 0; j < 256; ++j) { acc = fmaf(ah[j], *pv, acc); pv += PRJ; }
        } else {
            int e = elem - 192;
            int h = e / 24;
            const float* ah = al + h * NRES + jh * 256;
            const float* pv = gv + (size_t)(jh * 256) * 288 + e;
            for (int j = 0; j < 256; ++j) { acc = fmaf(ah[j], *pv, acc); pv += 288; }
        }
        part[t] = acc;
    }
    __syncthreads();
    if (t < 480) {
        float v = part[t] + part[t + 480];
        if (t < 192) concat[(size_t)i * OUT_DIM + t] = v;
        else opt[t - 192] = v;
    }
    __syncthreads();
    if (t < 96) {
        int h = t >> 3, p = t & 7;
        float b0 = opt[h * 24 + p * 3 + 0] - trans[i * 3 + 0];
        float b1 = opt[h * 24 + p * 3 + 1] - trans[i * 3 + 1];
        float b2 = opt[h * 24 + p * 3 + 2] - trans[i * 3 + 2];
        const float* Ri = rot + i * 9;
        float l0 = Ri[0] * b0 + Ri[3] * b1 + Ri[6] * b2;
        float l1 = Ri[1] * b0 + Ri[4] * b1 + Ri[7] * b2;
        float l2 = Ri[2] * b0 + Ri[5] * b1 + Ri[8] * b2;
        float* c = concat + (size_t)i * OUT_DIM;
        c[192 + h * 24 + p * 3 + 0] = l0;
        c[192 + h * 24 + p * 3 + 1] = l1;
        c[192 + h * 24 + p * 3 + 2] = l2;
        c[480 + h * 8 + p] = sqrtf(l0 * l0 + l1 * l1 + l2 * l2 + 1e-8f);
    }
}

// ---------------------------------------------------------------------------
// LayerNorm over 384
// ---------------------------------------------------------------------------
__global__ void ln_kernel(const float* __restrict__ x, const float* __restrict__ g,
                          const float* __restrict__ b, float* __restrict__ y)
{
    int i = blockIdx.x, t = threadIdx.x;
    const float* xr = x + (size_t)i * CS;
    float a0 = xr[t], a1 = xr[t + 128], a2 = xr[t + 256];
    __shared__ float red[128];
    red[t] = a0 + a1 + a2;
    __syncthreads();
    for (int s = 64; s > 0; s >>= 1) { if (t < s) red[t] += red[t + s]; __syncthreads(); }
    float mean = red[0] * (1.f / CS);
    __syncthreads();
    float d0 = a0 - mean, d1 = a1 - mean, d2 = a2 - mean;
    red[t] = d0 * d0 + d1 * d1 + d2 * d2;
    __syncthreads();
    for (int s = 64; s > 0; s >>= 1) { if (t < s) red[t] += red[t + s]; __syncthreads(); }
    float rstd = rsqrtf(red[0] * (1.f / CS) + 1e-5f);
    float* yr = y + (size_t)i * CS;
    yr[t]       = d0 * rstd * g[t]       + b[t];
    yr[t + 128] = d1 * rstd * g[t + 128] + b[t + 128];
    yr[t + 256] = d2 * rstd * g[t + 256] + b[t + 256];
}

// ---------------------------------------------------------------------------
// Backbone (+ zero loss for the following loss kernel)
// ---------------------------------------------------------------------------
__global__ void backbone_kernel(const float* __restrict__ sfin, const float* __restrict__ Wbu,
                                const float* __restrict__ bbu, const float* __restrict__ rot,
                                const float* __restrict__ trans, float* __restrict__ rot_out,
                                float* __restrict__ trans_out, float* __restrict__ loss)
{
    int i = blockIdx.x, t = threadIdx.x;
    if (i == 0 && t == 0) *loss = 0.f;
    float part[6] = {0.f, 0.f, 0.f, 0.f, 0.f, 0.f};
    for (int k = t; k < CS; k += 128) {
        float s = sfin[(size_t)i * CS + k];
        const float* wr = Wbu + k * 6;
#pragma unroll
        for (int c = 0; c < 6; ++c) part[c] = fmaf(s, wr[c], part[c]);
    }
    __shared__ float red[6][128];
#pragma unroll
    for (int c = 0; c < 6; ++c) red[c][t] = part[c];
    __syncthreads();
    for (int s = 64; s > 0; s >>= 1) {
        if (t < s) {
#pragma unroll
            for (int c = 0; c < 6; ++c) red[c][t] += red[c][t + s];
        }
        __syncthreads();
    }
    if (t == 0) {
        float u[6];
#pragma unroll
        for (int c = 0; c < 6; ++c) u[c] = red[c][0] + bbu[c];
        float a = 1.f, b = u[0], c2 = u[1], d = u[2];
        float inv = rsqrtf(a * a + b * b + c2 * c2 + d * d);
        a *= inv; b *= inv; c2 *= inv; d *= inv;
        float R[9] = { a*a + b*b - c2*c2 - d*d, 2.f*(b*c2 - a*d),        2.f*(b*d + a*c2),
                       2.f*(b*c2 + a*d),        a*a - b*b + c2*c2 - d*d, 2.f*(c2*d - a*b),
                       2.f*(b*d - a*c2),        2.f*(c2*d + a*b),        a*a - b*b - c2*c2 + d*d };
        const float* Ri = rot + i * 9;
        float Rn[9];
#pragma unroll
        for (int r = 0; r < 3; ++r)
#pragma unroll
            for (int cc = 0; cc < 3; ++cc) {
                float s2 = 0.f;
#pragma unroll
                for (int kk = 0; kk < 3; ++kk) s2 += Ri[r * 3 + kk] * R[kk * 3 + cc];
                Rn[r * 3 + cc] = s2;
            }
#pragma unroll
        for (int r = 0; r < 9; ++r) rot_out[i * 9 + r] = Rn[r];
        float t0 = u[3], t1 = u[4], t2 = u[5];
#pragma unroll
        for (int r = 0; r < 3; ++r)
            trans_out[i * 3 + r] = Ri[r * 3 + 0] * t0 + Ri[r * 3 + 1] * t1 + Ri[r * 3 + 2] * t2 + trans[i * 3 + r];
    }
}

// ---------------------------------------------------------------------------
// Loss
// ---------------------------------------------------------------------------
__global__ void loss_kernel(const float* __restrict__ rot_new, const float* __restrict__ trans_new,
                            const float* __restrict__ rot_truth, const float* __restrict__ trans_truth,
                            float* __restrict__ loss)
{
    int i = blockIdx.x;
    int t = threadIdx.x;
    __shared__ float red[256];
    float Rn[9], Rt[9];
#pragma unroll
    for (int r = 0; r < 9; ++r) { Rn[r] = rot_new[i * 9 + r]; Rt[r] = rot_truth[i * 9 + r]; }
    float ti0 = trans_new[i * 3 + 0], ti1 = trans_new[i * 3 + 1], ti2 = trans_new[i * 3 + 2];
    float tt0 = trans_truth[i * 3 + 0], tt1 = trans_truth[i * 3 + 1], tt2 = trans_truth[i * 3 + 2];
    float s = 0.f;
    for (int j = t; j < NRES; j += 256) {
        float db0 = trans_new[j * 3 + 0] - ti0;
        float db1 = trans_new[j * 3 + 1] - ti1;
        float db2 = trans_new[j * 3 + 2] - ti2;
        float dp0 = Rn[0] * db0 + Rn[3] * db1 + Rn[6] * db2;
        float dp1 = Rn[1] * db0 + Rn[4] * db1 + Rn[7] * db2;
        float dp2 = Rn[2] * db0 + Rn[5] * db1 + Rn[8] * db2;
        float eb0 = trans_truth[j * 3 + 0] - tt0;
        float eb1 = trans_truth[j * 3 + 1] - tt1;
        float eb2 = trans_truth[j * 3 + 2] - tt2;
        float dt0 = Rt[0] * eb0 + Rt[3] * eb1 + Rt[6] * eb2;
        float dt1 = Rt[1] * eb0 + Rt[4] * eb1 + Rt[7] * eb2;
        float dt2 = Rt[2] * eb0 + Rt[5] * eb1 + Rt[8] * eb2;
        float dx = dp0 - dt0, dy = dp1 - dt1, dz = dp2 - dt2;
        float dd = sqrtf(dx * dx + dy * dy + dz * dz + 1e-12f);
        s += fminf(dd, 10.f);
    }
    red[t] = s;
    __syncthreads();
    for (int k = 128; k > 0; k >>= 1) { if (t < k) red[t] += red[t + k]; __syncthreads(); }
    if (t == 0) atomicAdd(loss, red[0] * (1.f / (512.f * 512.f * 10.f)));
}

// ---------------------------------------------------------------------------
extern "C" void kernel_launch(void* const* d_in, const int* in_sizes, int n_in,
                              void* d_out, int out_size, void* d_ws, size_t ws_size,
                              hipStream_t stream)
{
    const float* single      = (const float*)d_in[0];
    const float* pair        = (const float*)d_in[1];
    const float* rot         = (const float*)d_in[2];
    const float* trans       = (const float*)d_in[3];
    const float* rot_truth   = (const float*)d_in[4];
    const float* trans_truth = (const float*)d_in[5];
    const float* Wq  = (const float*)d_in[6];
    const float* Wk  = (const float*)d_in[7];
    const float* Wv  = (const float*)d_in[8];
    const float* Wqp = (const float*)d_in[9];
    const float* Wkp = (const float*)d_in[10];
    const float* Wvp = (const float*)d_in[11];
    const float* Wb  = (const float*)d_in[12];
    const float* Wo  = (const float*)d_in[13];
    const float* bo  = (const float*)d_in[14];
    const float* gamma_raw = (const float*)d_in[15];
    const float* ln1_g = (const float*)d_in[16];
    const float* ln1_b = (const float*)d_in[17];
    const float* ln2_g = (const float*)d_in[18];
    const float* ln2_b = (const float*)d_in[19];
    const float* W1 = (const float*)d_in[20];
    const float* b1 = (const float*)d_in[21];
    const float* W2 = (const float*)d_in[22];
    const float* b2 = (const float*)d_in[23];
    const float* W3 = (const float*)d_in[24];
    const float* b3 = (const float*)d_in[25];
    const float* Wbu = (const float*)d_in[26];
    const float* bbu = (const float*)d_in[27];

    float* out = (float*)d_out;
    float* single_out = out;                   // 512*384
    float* rot_out    = out + 196608;          // 512*9
    float* trans_out  = out + 201216;          // 512*3
    float* loss_out   = out + 202752;          // 1

    float* ws = (float*)d_ws;
    float* proj   = ws;                         // 589824
    float* gq     = proj   + 589824;            // 73728
    float* gv     = gq     + 73728;             // 147456
    float* sqq    = gv     + 147456;            // 6144
    float* kT     = sqq    + 6144;              // 98304
    float* gkT    = kT     + 98304;             // 73728
    float* sqkT   = gkT    + 73728;             // 6144
    float* wbfragf= sqkT   + 6144;              // 1024 (2048 ushorts)
    float* Amat   = wbfragf+ 1024;              // 3145728
    float* Bp     = Amat;                       // alias: dead after proj GEMM
    float* concat = Amat   + 3145728;           // 1081344
    float* out1   = concat + 1081344;           // 196608
    float* sln    = out1   + 196608;            // 196608
    float* h1     = sln    + 196608;            // 196608
    float* h2     = h1     + 196608;            // 196608
    unsigned short* wbfrag = (unsigned short*)wbfragf;

    dim3 b256(256);

    // 1. pack weights (+ Wb frags + zero proj); projection GEMM (k-split 2)
    int pack_total = CS * PRJ + 2048 + NRES * PRJ;
    pack_proj_kernel<<<dim3((pack_total + 255) / 256), b256, 0, stream>>>(
        Wq, Wk, Wv, Wqp, Wkp, Wvp, Wb, Bp, wbfrag, proj);
    gemm_tiled<<<dim3(8, PRJ / 64, 2), b256, 0, stream>>>(single, Bp, nullptr, nullptr, proj,
                                                          NRES, CS, PRJ, 0, 192, 0);

    // 2. frames
    frames_kernel<<<dim3((NRES * NH + 255) / 256), b256, 0, stream>>>(proj, rot, trans,
                                                                      gq, gv, sqq, kT, gkT, sqkT);

    // 3. logits (direct-global MFMA A-frags, 1 barrier) + softmax
    logits_mfma_kernel<<<dim3(NRES, 8), b256, 0, stream>>>(pair, proj, gq, kT, gkT, sqq, sqkT,
                                                           wbfrag, gamma_raw, Amat);
    softmax_kernel<<<dim3(NRES * NH), b256, 0, stream>>>(Amat);

    // 4. attention outputs (in-block j-splits, no global atomics)
    opair_kernel<<<dim3(NRES), dim3(768), 0, stream>>>(pair, Amat, concat);
    ov_opt_kernel<<<dim3(NRES), dim3(1024), 0, stream>>>(Amat, proj, gv, rot, trans, concat);

    // 5. ipa_out = concat @ Wo + bo + single  (k-split 4, atomic into pre-init)
    init_bias_kernel<<<dim3((NRES * CS + 255) / 256), b256, 0, stream>>>(bo, single, out1,
                                                                         NRES * CS, CS);
    gemm_tiled<<<dim3(8, CS / 64, 4), b256, 0, stream>>>(concat, Wo, nullptr, nullptr, out1,
                                                         NRES, OUT_DIM, CS, 0, 528, 0);

    // 6. LN1 + FF (k-split 4, relu folded into consumer A-load) + LN2
    ln_kernel<<<dim3(NRES), dim3(128), 0, stream>>>(out1, ln1_g, ln1_b, sln);
    init_bias_kernel<<<dim3((NRES * CS + 255) / 256), b256, 0, stream>>>(b1, nullptr, h1,
                                                                         NRES * CS, CS);
    init_bias_kernel<<<dim3((NRES * CS + 255) / 256), b256, 0, stream>>>(b2, nullptr, h2,
                                                                         NRES * CS, CS);
    gemm_tiled<<<dim3(8, CS / 64, 4), b256, 0, stream>>>(sln, W1, nullptr, nullptr, h1,
                                                         NRES, CS, CS, 0, 96, 0);
    gemm_tiled<<<dim3(8, CS / 64, 4), b256, 0, stream>>>(h1, W2, nullptr, nullptr, h2,
                                                         NRES, CS, CS, 0, 96, 1);
    init_bias_kernel<<<dim3((NRES * CS + 255) / 256), b256, 0, stream>>>(b3, sln, out1,
                                                                         NRES * CS, CS);
    gemm_tiled<<<dim3(8, CS / 64, 4), b256, 0, stream>>>(h2, W3, nullptr, nullptr, out1,
                                                         NRES, CS, CS, 0, 96, 1);
    ln_kernel<<<dim3(NRES), dim3(128), 0, stream>>>(out1, ln2_g, ln2_b, single_out);

    // 7. backbone (zeroes loss) + loss
    backbone_kernel<<<dim3(NRES), dim3(128), 0, stream>>>(single_out, Wbu, bbu, rot, trans,
                                                          rot_out, trans_out, loss_out);
    loss_kernel<<<dim3(NRES), b256, 0, stream>>>(rot_out, trans_out, rot_truth, trans_truth,
                                                 loss_out);
}

// Round 15
// 275.119 us; speedup vs baseline: 1.1490x; 1.0083x over previous
//
#include <hip/hip_runtime.h>
#include <hip/hip_bf16.h>
#include <math.h>

#define NRES 512
#define CS 384
#define CZ 128
#define NH 12
#define PQ 4
#define PV 8
#define OUT_DIM 2112   // H*(C + 3*PV + PV + CZ)
#define PRJ 1152       // packed projection width: q192|k192|v192|qp144|kp144|vp288

typedef __attribute__((ext_vector_type(8))) short short8;
typedef __attribute__((ext_vector_type(4))) float f32x4;

__device__ __forceinline__ float softplusf(float x) { return log1pf(expf(x)); }

__device__ __forceinline__ unsigned short f2bf(float f) {
    union { float f; unsigned u; } v; v.f = f;
    unsigned r = v.u + 0x7FFF + ((v.u >> 16) & 1);
    return (unsigned short)(r >> 16);
}

__device__ __forceinline__ unsigned cvt_pk_bf16(float lo, float hi) {
    unsigned r;
    asm volatile("v_cvt_pk_bf16_f32 %0, %1, %2" : "=v"(r) : "v"(lo), "v"(hi));
    return r;
}

// ---------------------------------------------------------------------------
// Pack 6 projection weights into Bp[384][1152] + Wb MFMA B-fragments
// + zero proj (avoids slow runtime fillBuffer in-graph).
// ---------------------------------------------------------------------------
__global__ void pack_proj_kernel(const float* __restrict__ Wq, const float* __restrict__ Wk,
                                 const float* __restrict__ Wv, const float* __restrict__ Wqp,
                                 const float* __restrict__ Wkp, const float* __restrict__ Wvp,
                                 const float* __restrict__ Wb,
                                 float* __restrict__ Bp, unsigned short* __restrict__ wbfrag,
                                 float* __restrict__ proj)
{
    int x = blockIdx.x * blockDim.x + threadIdx.x;
    if (x < CS * PRJ) {
        int k = x / PRJ, c = x % PRJ;
        float v;
        if      (c < 192)  v = Wq [k * 192 + c];
        else if (c < 384)  v = Wk [k * 192 + (c - 192)];
        else if (c < 576)  v = Wv [k * 192 + (c - 384)];
        else if (c < 720)  v = Wqp[k * 144 + (c - 576)];
        else if (c < 864)  v = Wkp[k * 144 + (c - 720)];
        else               v = Wvp[k * 288 + (c - 864)];
        Bp[x] = v;
    } else if (x < CS * PRJ + 2048) {
        int idx = x - CS * PRJ;               // ks*512 + lane*8 + e
        int ks = idx >> 9, r = idx & 511;
        int lane = r >> 3, e = r & 7;
        int col = lane & 15, kb = (lane >> 4) * 8;
        int row = ks * 32 + kb + e;
        float v = (col < NH) ? Wb[row * NH + col] : 0.f;
        wbfrag[idx] = f2bf(v);
    } else {
        int idx = x - (CS * PRJ + 2048);
        if (idx < NRES * PRJ) proj[idx] = 0.f;
    }
}

// ---------------------------------------------------------------------------
// Tiled f32 GEMM: BM=64, BN=64, BK=16, 256 threads, 4x4 micro-tile.
// reluA: relu A on load. gridDim.z>1: k-split partial, atomicAdd into pre-init C.
// ---------------------------------------------------------------------------
__global__ void gemm_tiled(const float* __restrict__ A, const float* __restrict__ B,
                           const float* __restrict__ bias, const float* __restrict__ res,
                           float* __restrict__ C, int M, int K, int Nc, int relu, int KS,
                           int reluA)
{
    __shared__ float As[16][68];
    __shared__ float Bs[16][64];
    int m0 = blockIdx.x * 64, n0 = blockIdx.y * 64;
    int kbeg = blockIdx.z * KS;
    int t = threadIdx.x;
    int tm = t >> 4, tn = t & 15;
    int lr = t >> 2, lc4 = t & 3;
    int br = t >> 4, bc4 = t & 15;
    float acc[4][4] = {{0.f}};

    for (int kt = kbeg; kt < kbeg + KS; kt += 16) {
        float4 a4 = *(const float4*)&A[(size_t)(m0 + lr) * K + kt + lc4 * 4];
        float4 b4 = *(const float4*)&B[(size_t)(kt + br) * Nc + n0 + bc4 * 4];
        if (reluA) {
            a4.x = fmaxf(a4.x, 0.f); a4.y = fmaxf(a4.y, 0.f);
            a4.z = fmaxf(a4.z, 0.f); a4.w = fmaxf(a4.w, 0.f);
        }
        As[lc4 * 4 + 0][lr] = a4.x;
        As[lc4 * 4 + 1][lr] = a4.y;
        As[lc4 * 4 + 2][lr] = a4.z;
        As[lc4 * 4 + 3][lr] = a4.w;
        *(float4*)&Bs[br][bc4 * 4] = b4;
        __syncthreads();
#pragma unroll
        for (int k = 0; k < 16; ++k) {
            float4 av = *(const float4*)&As[k][tm * 4];
            float4 bv = *(const float4*)&Bs[k][tn * 4];
            acc[0][0] = fmaf(av.x, bv.x, acc[0][0]); acc[0][1] = fmaf(av.x, bv.y, acc[0][1]);
            acc[0][2] = fmaf(av.x, bv.z, acc[0][2]); acc[0][3] = fmaf(av.x, bv.w, acc[0][3]);
            acc[1][0] = fmaf(av.y, bv.x, acc[1][0]); acc[1][1] = fmaf(av.y, bv.y, acc[1][1]);
            acc[1][2] = fmaf(av.y, bv.z, acc[1][2]); acc[1][3] = fmaf(av.y, bv.w, acc[1][3]);
            acc[2][0] = fmaf(av.z, bv.x, acc[2][0]); acc[2][1] = fmaf(av.z, bv.y, acc[2][1]);
            acc[2][2] = fmaf(av.z, bv.z, acc[2][2]); acc[2][3] = fmaf(av.z, bv.w, acc[2][3]);
            acc[3][0] = fmaf(av.w, bv.x, acc[3][0]); acc[3][1] = fmaf(av.w, bv.y, acc[3][1]);
            acc[3][2] = fmaf(av.w, bv.z, acc[3][2]); acc[3][3] = fmaf(av.w, bv.w, acc[3][3]);
        }
        __syncthreads();
    }

    if (gridDim.z > 1) {
#pragma unroll
        for (int r = 0; r < 4; ++r)
#pragma unroll
            for (int c = 0; c < 4; ++c)
                atomicAdd(&C[(size_t)(m0 + tm * 4 + r) * Nc + n0 + tn * 4 + c], acc[r][c]);
    } else {
#pragma unroll
        for (int r = 0; r < 4; ++r) {
            int row = m0 + tm * 4 + r;
            float4 v;
            float* vp = (float*)&v;
#pragma unroll
            for (int c = 0; c < 4; ++c) {
                int col = n0 + tn * 4 + c;
                float x = acc[r][c];
                if (bias) x += bias[col];
                if (res)  x += res[(size_t)row * Nc + col];
                if (relu) x = fmaxf(x, 0.f);
                vp[c] = x;
            }
            *(float4*)&C[(size_t)row * Nc + n0 + tn * 4] = v;
        }
    }
}

// ---------------------------------------------------------------------------
// init: out[x] = bias[x % Nc] (+ res[x])
// ---------------------------------------------------------------------------
__global__ void init_bias_kernel(const float* __restrict__ bias, const float* __restrict__ res,
                                 float* __restrict__ out, int total, int Nc)
{
    int x = blockIdx.x * blockDim.x + threadIdx.x;
    if (x >= total) return;
    float v = bias[x % Nc];
    if (res) v += res[x];
    out[x] = v;
}

// ---------------------------------------------------------------------------
// Frames: one thread per (n, h).
// ---------------------------------------------------------------------------
__global__ void frames_kernel(const float* __restrict__ proj, const float* __restrict__ rot,
                              const float* __restrict__ trans,
                              float* __restrict__ gq, float* __restrict__ gv,
                              float* __restrict__ sqq,
                              float* __restrict__ kT, float* __restrict__ gkT,
                              float* __restrict__ sqkT)
{
    int x = blockIdx.x * blockDim.x + threadIdx.x;
    if (x >= NRES * NH) return;
    int n = x / NH, h = x % NH;
    float R[9], t3[3];
#pragma unroll
    for (int r = 0; r < 9; ++r) R[r] = rot[n * 9 + r];
#pragma unroll
    for (int r = 0; r < 3; ++r) t3[r] = trans[n * 3 + r];
    const float* qp = proj + (size_t)n * PRJ + 576 + h * (PQ * 3);
    const float* kp = proj + (size_t)n * PRJ + 720 + h * (PQ * 3);
    const float* vp = proj + (size_t)n * PRJ + 864 + h * (PV * 3);
    const float* kk = proj + (size_t)n * PRJ + 192 + h * 16;

#pragma unroll
    for (int c = 0; c < 16; ++c) kT[(h * 16 + c) * NRES + n] = kk[c];

    float sq = 0.f, sk = 0.f;
#pragma unroll
    for (int p = 0; p < PQ; ++p) {
        const float* in = qp + p * 3;
        float* og = gq + (size_t)n * 144 + h * (PQ * 3) + p * 3;
#pragma unroll
        for (int a = 0; a < 3; ++a) {
            float g = R[a*3+0]*in[0] + R[a*3+1]*in[1] + R[a*3+2]*in[2] + t3[a];
            og[a] = g; sq += g * g;
        }
        const float* in2 = kp + p * 3;
#pragma unroll
        for (int a = 0; a < 3; ++a) {
            float g = R[a*3+0]*in2[0] + R[a*3+1]*in2[1] + R[a*3+2]*in2[2] + t3[a];
            gkT[(h * 12 + p * 3 + a) * NRES + n] = g;
            sk += g * g;
        }
    }
    sqq[n * NH + h] = sq;
    sqkT[h * NRES + n] = sk;
#pragma unroll
    for (int p = 0; p < PV; ++p) {
        const float* in = vp + p * 3;
        float* og = gv + (size_t)n * 288 + h * (PV * 3) + p * 3;
#pragma unroll
        for (int a = 0; a < 3; ++a)
            og[a] = R[a*3+0]*in[0] + R[a*3+1]*in[1] + R[a*3+2]*in[2] + t3[a];
    }
}

// ---------------------------------------------------------------------------
// Logits v8: grid (i=512, jt=8), block 256 (4 waves), one 64-j tile.
// MFMA A-fragments loaded directly from global pair (no staging LDS).
// ---------------------------------------------------------------------------
__global__ void logits_mfma_kernel(const float* __restrict__ pair, const float* __restrict__ proj,
                                   const float* __restrict__ gq, const float* __restrict__ kT,
                                   const float* __restrict__ gkT, const float* __restrict__ sqq,
                                   const float* __restrict__ sqkT,
                                   const unsigned short* __restrict__ wbfrag,
                                   const float* __restrict__ gamma_raw, float* __restrict__ L)
{
    __shared__ float bias_s[64 * 17];         // 4.25 KB
    __shared__ float qi[192], gqi[144], sqi[12], gam[12];

    int i = blockIdx.x, jt = blockIdx.y, t = threadIdx.x;
    int lane = t & 63, w = t >> 6;

    int arow = w * 16 + (lane & 15);
    int zofs = (lane >> 4) * 8;
    const float* arow_p = pair + ((size_t)i * NRES + jt * 64 + arow) * CZ + zofs;
    float4 a0 = *(const float4*)(arow_p + 0);
    float4 a1 = *(const float4*)(arow_p + 4);
    float4 b0 = *(const float4*)(arow_p + 32);
    float4 b1 = *(const float4*)(arow_p + 36);
    float4 c0 = *(const float4*)(arow_p + 64);
    float4 c1 = *(const float4*)(arow_p + 68);
    float4 d0 = *(const float4*)(arow_p + 96);
    float4 d1 = *(const float4*)(arow_p + 100);

    short8 bfrag[4];
#pragma unroll
    for (int ks = 0; ks < 4; ++ks)
        bfrag[ks] = *(const short8*)&wbfrag[ks * 512 + lane * 8];

    for (int x = t; x < 192; x += 256) qi[x] = proj[(size_t)i * PRJ + x];
    for (int x = t; x < 144; x += 256) gqi[x] = gq[(size_t)i * 144 + x];
    if (t < 12) { sqi[t] = sqq[i * 12 + t]; gam[t] = softplusf(gamma_raw[t]); }

    {
        f32x4 acc = {0.f, 0.f, 0.f, 0.f};
        short8 f;
        unsigned* fu = (unsigned*)&f;
        fu[0] = cvt_pk_bf16(a0.x, a0.y); fu[1] = cvt_pk_bf16(a0.z, a0.w);
        fu[2] = cvt_pk_bf16(a1.x, a1.y); fu[3] = cvt_pk_bf16(a1.z, a1.w);
        acc = __builtin_amdgcn_mfma_f32_16x16x32_bf16(f, bfrag[0], acc, 0, 0, 0);
        fu[0] = cvt_pk_bf16(b0.x, b0.y); fu[1] = cvt_pk_bf16(b0.z, b0.w);
        fu[2] = cvt_pk_bf16(b1.x, b1.y); fu[3] = cvt_pk_bf16(b1.z, b1.w);
        acc = __builtin_amdgcn_mfma_f32_16x16x32_bf16(f, bfrag[1], acc, 0, 0, 0);
        fu[0] = cvt_pk_bf16(c0.x, c0.y); fu[1] = cvt_pk_bf16(c0.z, c0.w);
        fu[2] = cvt_pk_bf16(c1.x, c1.y); fu[3] = cvt_pk_bf16(c1.z, c1.w);
        acc = __builtin_amdgcn_mfma_f32_16x16x32_bf16(f, bfrag[2], acc, 0, 0, 0);
        fu[0] = cvt_pk_bf16(d0.x, d0.y); fu[1] = cvt_pk_bf16(d0.z, d0.w);
        fu[2] = cvt_pk_bf16(d1.x, d1.y); fu[3] = cvt_pk_bf16(d1.z, d1.w);
        acc = __builtin_amdgcn_mfma_f32_16x16x32_bf16(f, bfrag[3], acc, 0, 0, 0);
        int crow = w * 16 + (lane >> 4) * 4;
        int ccol = lane & 15;
#pragma unroll
        for (int r = 0; r < 4; ++r) bias_s[(crow + r) * 17 + ccol] = acc[r];
    }
    __syncthreads();

    const float WLc = 0.57735026918962576f;
    const float WCc = 0.23570226039551584f;
    int j = jt * 64 + lane;
#pragma unroll
    for (int hh = 0; hh < 3; ++hh) {
        int h = w * 3 + hh;
        float qk = 0.f;
#pragma unroll
        for (int c = 0; c < 16; ++c)
            qk = fmaf(qi[h * 16 + c], kT[(h * 16 + c) * NRES + j], qk);
        float cross = 0.f;
#pragma unroll
        for (int x = 0; x < 12; ++x)
            cross = fmaf(gqi[h * 12 + x], gkT[(h * 12 + x) * NRES + j], cross);
        float d2 = sqi[h] + sqkT[h * NRES + j] - 2.f * cross;
        float logit = WLc * (qk * 0.25f + bias_s[lane * 17 + h] - 0.5f * WCc * gam[h] * d2);
        L[((size_t)i * NH + h) * NRES + j] = logit;
    }
}

// ---------------------------------------------------------------------------
// Softmax over j per (i,h) row, in place. grid = 6144, block = 256
// ---------------------------------------------------------------------------
__global__ void softmax_kernel(float* __restrict__ L)
{
    int row = blockIdx.x;
    float* p = L + (size_t)row * NRES;
    int t = threadIdx.x;
    __shared__ float red[256];
    float v0 = p[t], v1 = p[t + 256];
    red[t] = fmaxf(v0, v1);
    __syncthreads();
    for (int s = 128; s > 0; s >>= 1) { if (t < s) red[t] = fmaxf(red[t], red[t + s]); __syncthreads(); }
    float m = red[0];
    __syncthreads();
    float e0 = expf(v0 - m), e1 = expf(v1 - m);
    red[t] = e0 + e1;
    __syncthreads();
    for (int s = 128; s > 0; s >>= 1) { if (t < s) red[t] += red[t + s]; __syncthreads(); }
    float inv = 1.f / red[0];
    p[t] = e0 * inv;
    p[t + 256] = e1 * inv;
}

// ---------------------------------------------------------------------------
// Fused attention outputs: o_pair + o_v + o_pt + local/norms in one kernel.
// Block per i, 1024 threads. Stage al[12x512] ONCE (was staged twice before).
// 1728 work units (768 opair: h x zq x j-half; 960 ov/opt: elem x j-half),
// each a 256-j loop; strided unit loop; LDS partial combine; direct stores.
// ---------------------------------------------------------------------------
__global__ __launch_bounds__(1024) void attn_out_kernel(const float* __restrict__ pair,
                                                        const float* __restrict__ A,
                                                        const float* __restrict__ proj,
                                                        const float* __restrict__ gv,
                                                        const float* __restrict__ rot,
                                                        const float* __restrict__ trans,
                                                        float* __restrict__ concat)
{
    __shared__ float al[NH * NRES];     // 24 KB
    __shared__ float4 part4[768];       // 12 KB (opair partials)
    __shared__ float partv[960];        // 3.75 KB (ov/opt partials)
    __shared__ float opt[NH * PV * 3];  // 1.125 KB
    int i = blockIdx.x, t = threadIdx.x;
    for (int x = t; x < NH * NRES / 4; x += 1024)
        *(float4*)&al[x * 4] = *(const float4*)&A[(size_t)i * NH * NRES + x * 4];
    __syncthreads();

    for (int u = t; u < 1728; u += 1024) {
        if (u < 768) {
            // opair unit: jh = u/384, zq = (u%384)&31, h = (u%384)>>5
            int jh = u >> 9 >= 0 ? (u / 384) : 0;   // 0 or 1
            int sub = u - jh * 384;
            int zq = sub & 31, h = sub >> 5;
            float4 acc = {0.f, 0.f, 0.f, 0.f};
            const float* pr = pair + (size_t)i * NRES * CZ + (size_t)jh * 256 * CZ;
            const float* ah = al + h * NRES + jh * 256;
            for (int j = 0; j < 256; ++j) {
                float4 p4 = *(const float4*)&pr[(size_t)j * CZ + zq * 4];
                float a = ah[j];
                acc.x = fmaf(a, p4.x, acc.x);
                acc.y = fmaf(a, p4.y, acc.y);
                acc.z = fmaf(a, p4.z, acc.z);
                acc.w = fmaf(a, p4.w, acc.w);
            }
            part4[u] = acc;
        } else {
            // ov/opt unit: v = u-768; jh = v/480, elem = v%480
            int v = u - 768;
            int jh = v / 480;
            int elem = v - jh * 480;
            float acc = 0.f;
            if (elem < 192) {
                int h = elem >> 4;
                const float* ah = al + h * NRES + jh * 256;
                const float* pv = proj + (size_t)(jh * 256) * PRJ + 384 + elem;
                for (int j = 0; j < 256; ++j) { acc = fmaf(ah[j], *pv, acc); pv += PRJ; }
            } else {
                int e = elem - 192;
                int h = e / 24;
                const float* ah = al + h * NRES + jh * 256;
                const float* pv = gv + (size_t)(jh * 256) * 288 + e;
                for (int j = 0; j < 256; ++j) { acc = fmaf(ah[j], *pv, acc); pv += 288; }
            }
            partv[v] = acc;
        }
    }
    __syncthreads();

    if (t < 384) {   // opair combine + store
        int zq = t & 31, h = t >> 5;
        float4 a = part4[t], b = part4[t + 384];
        float4 o;
        o.x = a.x + b.x; o.y = a.y + b.y; o.z = a.z + b.z; o.w = a.w + b.w;
        *(float4*)&concat[(size_t)i * OUT_DIM + 576 + h * 128 + zq * 4] = o;
    } else if (t >= 512 && t < 992) {   // ov/opt combine (disjoint threads)
        int elem = t - 512;
        float v = partv[elem] + partv[elem + 480];
        if (elem < 192) concat[(size_t)i * OUT_DIM + elem] = v;
        else opt[elem - 192] = v;
    }
    __syncthreads();
    if (t < 96) {   // finalize local/norms
        int h = t >> 3, p = t & 7;
        float b0 = opt[h * 24 + p * 3 + 0] - trans[i * 3 + 0];
        float b1 = opt[h * 24 + p * 3 + 1] - trans[i * 3 + 1];
        float b2 = opt[h * 24 + p * 3 + 2] - trans[i * 3 + 2];
        const float* Ri = rot + i * 9;
        float l0 = Ri[0] * b0 + Ri[3] * b1 + Ri[6] * b2;
        float l1 = Ri[1] * b0 + Ri[4] * b1 + Ri[7] * b2;
        float l2 = Ri[2] * b0 + Ri[5] * b1 + Ri[8] * b2;
        float* c = concat + (size_t)i * OUT_DIM;
        c[192 + h * 24 + p * 3 + 0] = l0;
        c[192 + h * 24 + p * 3 + 1] = l1;
        c[192 + h * 24 + p * 3 + 2] = l2;
        c[480 + h * 8 + p] = sqrtf(l0 * l0 + l1 * l1 + l2 * l2 + 1e-8f);
    }
}

// ---------------------------------------------------------------------------
// LayerNorm over 384
// ---------------------------------------------------------------------------
__global__ void ln_kernel(const float* __restrict__ x, const float* __restrict__ g,
                          const float* __restrict__ b, float* __restrict__ y)
{
    int i = blockIdx.x, t = threadIdx.x;
    const float* xr = x + (size_t)i * CS;
    float a0 = xr[t], a1 = xr[t + 128], a2 = xr[t + 256];
    __shared__ float red[128];
    red[t] = a0 + a1 + a2;
    __syncthreads();
    for (int s = 64; s > 0; s >>= 1) { if (t < s) red[t] += red[t + s]; __syncthreads(); }
    float mean = red[0] * (1.f / CS);
    __syncthreads();
    float d0 = a0 - mean, d1 = a1 - mean, d2 = a2 - mean;
    red[t] = d0 * d0 + d1 * d1 + d2 * d2;
    __syncthreads();
    for (int s = 64; s > 0; s >>= 1) { if (t < s) red[t] += red[t + s]; __syncthreads(); }
    float rstd = rsqrtf(red[0] * (1.f / CS) + 1e-5f);
    float* yr = y + (size_t)i * CS;
    yr[t]       = d0 * rstd * g[t]       + b[t];
    yr[t + 128] = d1 * rstd * g[t + 128] + b[t + 128];
    yr[t + 256] = d2 * rstd * g[t + 256] + b[t + 256];
}

// ---------------------------------------------------------------------------
// Backbone (+ zero loss for the following loss kernel)
// ---------------------------------------------------------------------------
__global__ void backbone_kernel(const float* __restrict__ sfin, const float* __restrict__ Wbu,
                                const float* __restrict__ bbu, const float* __restrict__ rot,
                                const float* __restrict__ trans, float* __restrict__ rot_out,
                                float* __restrict__ trans_out, float* __restrict__ loss)
{
    int i = blockIdx.x, t = threadIdx.x;
    if (i == 0 && t == 0) *loss = 0.f;
    float part[6] = {0.f, 0.f, 0.f, 0.f, 0.f, 0.f};
    for (int k = t; k < CS; k += 128) {
        float s = sfin[(size_t)i * CS + k];
        const float* wr = Wbu + k * 6;
#pragma unroll
        for (int c = 0; c < 6; ++c) part[c] = fmaf(s, wr[c], part[c]);
    }
    __shared__ float red[6][128];
#pragma unroll
    for (int c = 0; c < 6; ++c) red[c][t] = part[c];
    __syncthreads();
    for (int s = 64; s > 0; s >>= 1) {
        if (t < s) {
#pragma unroll
            for (int c = 0; c < 6; ++c) red[c][t] += red[c][t + s];
        }
        __syncthreads();
    }
    if (t == 0) {
        float u[6];
#pragma unroll
        for (int c = 0; c < 6; ++c) u[c] = red[c][0] + bbu[c];
        float a = 1.f, b = u[0], c2 = u[1], d = u[2];
        float inv = rsqrtf(a * a + b * b + c2 * c2 + d * d);
        a *= inv; b *= inv; c2 *= inv; d *= inv;
        float R[9] = { a*a + b*b - c2*c2 - d*d, 2.f*(b*c2 - a*d),        2.f*(b*d + a*c2),
                       2.f*(b*c2 + a*d),        a*a - b*b + c2*c2 - d*d, 2.f*(c2*d - a*b),
                       2.f*(b*d - a*c2),        2.f*(c2*d + a*b),        a*a - b*b - c2*c2 + d*d };
        const float* Ri = rot + i * 9;
        float Rn[9];
#pragma unroll
        for (int r = 0; r < 3; ++r)
#pragma unroll
            for (int cc = 0; cc < 3; ++cc) {
                float s2 = 0.f;
#pragma unroll
                for (int kk = 0; kk < 3; ++kk) s2 += Ri[r * 3 + kk] * R[kk * 3 + cc];
                Rn[r * 3 + cc] = s2;
            }
#pragma unroll
        for (int r = 0; r < 9; ++r) rot_out[i * 9 + r] = Rn[r];
        float t0 = u[3], t1 = u[4], t2 = u[5];
#pragma unroll
        for (int r = 0; r < 3; ++r)
            trans_out[i * 3 + r] = Ri[r * 3 + 0] * t0 + Ri[r * 3 + 1] * t1 + Ri[r * 3 + 2] * t2 + trans[i * 3 + r];
    }
}

// ---------------------------------------------------------------------------
// Loss
// ---------------------------------------------------------------------------
__global__ void loss_kernel(const float* __restrict__ rot_new, const float* __restrict__ trans_new,
                            const float* __restrict__ rot_truth, const float* __restrict__ trans_truth,
                            float* __restrict__ loss)
{
    int i = blockIdx.x;
    int t = threadIdx.x;
    __shared__ float red[256];
    float Rn[9], Rt[9];
#pragma unroll
    for (int r = 0; r < 9; ++r) { Rn[r] = rot_new[i * 9 + r]; Rt[r] = rot_truth[i * 9 + r]; }
    float ti0 = trans_new[i * 3 + 0], ti1 = trans_new[i * 3 + 1], ti2 = trans_new[i * 3 + 2];
    float tt0 = trans_truth[i * 3 + 0], tt1 = trans_truth[i * 3 + 1], tt2 = trans_truth[i * 3 + 2];
    float s = 0.f;
    for (int j = t; j < NRES; j += 256) {
        float db0 = trans_new[j * 3 + 0] - ti0;
        float db1 = trans_new[j * 3 + 1] - ti1;
        float db2 = trans_new[j * 3 + 2] - ti2;
        float dp0 = Rn[0] * db0 + Rn[3] * db1 + Rn[6] * db2;
        float dp1 = Rn[1] * db0 + Rn[4] * db1 + Rn[7] * db2;
        float dp2 = Rn[2] * db0 + Rn[5] * db1 + Rn[8] * db2;
        float eb0 = trans_truth[j * 3 + 0] - tt0;
        float eb1 = trans_truth[j * 3 + 1] - tt1;
        float eb2 = trans_truth[j * 3 + 2] - tt2;
        float dt0 = Rt[0] * eb0 + Rt[3] * eb1 + Rt[6] * eb2;
        float dt1 = Rt[1] * eb0 + Rt[4] * eb1 + Rt[7] * eb2;
        float dt2 = Rt[2] * eb0 + Rt[5] * eb1 + Rt[8] * eb2;
        float dx = dp0 - dt0, dy = dp1 - dt1, dz = dp2 - dt2;
        float dd = sqrtf(dx * dx + dy * dy + dz * dz + 1e-12f);
        s += fminf(dd, 10.f);
    }
    red[t] = s;
    __syncthreads();
    for (int k = 128; k > 0; k >>= 1) { if (t < k) red[t] += red[t + k]; __syncthreads(); }
    if (t == 0) atomicAdd(loss, red[0] * (1.f / (512.f * 512.f * 10.f)));
}

// ---------------------------------------------------------------------------
extern "C" void kernel_launch(void* const* d_in, const int* in_sizes, int n_in,
                              void* d_out, int out_size, void* d_ws, size_t ws_size,
                              hipStream_t stream)
{
    const float* single      = (const float*)d_in[0];
    const float* pair        = (const float*)d_in[1];
    const float* rot         = (const float*)d_in[2];
    const float* trans       = (const float*)d_in[3];
    const float* rot_truth   = (const float*)d_in[4];
    const float* trans_truth = (const float*)d_in[5];
    const float* Wq  = (const float*)d_in[6];
    const float* Wk  = (const float*)d_in[7];
    const float* Wv  = (const float*)d_in[8];
    const float* Wqp = (const float*)d_in[9];
    const float* Wkp = (const float*)d_in[10];
    const float* Wvp = (const float*)d_in[11];
    const float* Wb  = (const float*)d_in[12];
    const float* Wo  = (const float*)d_in[13];
    const float* bo  = (const float*)d_in[14];
    const float* gamma_raw = (const float*)d_in[15];
    const float* ln1_g = (const float*)d_in[16];
    const float* ln1_b = (const float*)d_in[17];
    const float* ln2_g = (const float*)d_in[18];
    const float* ln2_b = (const float*)d_in[19];
    const float* W1 = (const float*)d_in[20];
    const float* b1 = (const float*)d_in[21];
    const float* W2 = (const float*)d_in[22];
    const float* b2 = (const float*)d_in[23];
    const float* W3 = (const float*)d_in[24];
    const float* b3 = (const float*)d_in[25];
    const float* Wbu = (const float*)d_in[26];
    const float* bbu = (const float*)d_in[27];

    float* out = (float*)d_out;
    float* single_out = out;                   // 512*384
    float* rot_out    = out + 196608;          // 512*9
    float* trans_out  = out + 201216;          // 512*3
    float* loss_out   = out + 202752;          // 1

    float* ws = (float*)d_ws;
    float* proj   = ws;                         // 589824
    float* gq     = proj   + 589824;            // 73728
    float* gv     = gq     + 73728;             // 147456
    float* sqq    = gv     + 147456;            // 6144
    float* kT     = sqq    + 6144;              // 98304
    float* gkT    = kT     + 98304;             // 73728
    float* sqkT   = gkT    + 73728;             // 6144
    float* wbfragf= sqkT   + 6144;              // 1024 (2048 ushorts)
    float* Amat   = wbfragf+ 1024;              // 3145728
    float* Bp     = Amat;                       // alias: dead after proj GEMM
    float* concat = Amat   + 3145728;           // 1081344
    float* out1   = concat + 1081344;           // 196608
    float* sln    = out1   + 196608;            // 196608
    float* h1     = sln    + 196608;            // 196608
    float* h2     = h1     + 196608;            // 196608
    unsigned short* wbfrag = (unsigned short*)wbfragf;

    dim3 b256(256);

    // 1. pack weights (+ Wb frags + zero proj); projection GEMM (k-split 2)
    int pack_total = CS * PRJ + 2048 + NRES * PRJ;
    pack_proj_kernel<<<dim3((pack_total + 255) / 256), b256, 0, stream>>>(
        Wq, Wk, Wv, Wqp, Wkp, Wvp, Wb, Bp, wbfrag, proj);
    gemm_tiled<<<dim3(8, PRJ / 64, 2), b256, 0, stream>>>(single, Bp, nullptr, nullptr, proj,
                                                          NRES, CS, PRJ, 0, 192, 0);

    // 2. frames
    frames_kernel<<<dim3((NRES * NH + 255) / 256), b256, 0, stream>>>(proj, rot, trans,
                                                                      gq, gv, sqq, kT, gkT, sqkT);

    // 3. logits (direct-global MFMA A-frags) + softmax
    logits_mfma_kernel<<<dim3(NRES, 8), b256, 0, stream>>>(pair, proj, gq, kT, gkT, sqq, sqkT,
                                                           wbfrag, gamma_raw, Amat);
    softmax_kernel<<<dim3(NRES * NH), b256, 0, stream>>>(Amat);

    // 4. fused attention outputs (single al stage, o_pair+o_v+o_pt+finalize)
    attn_out_kernel<<<dim3(NRES), dim3(1024), 0, stream>>>(pair, Amat, proj, gv, rot, trans,
                                                           concat);

    // 5. ipa_out = concat @ Wo + bo + single  (k-split 4, atomic into pre-init)
    init_bias_kernel<<<dim3((NRES * CS + 255) / 256), b256, 0, stream>>>(bo, single, out1,
                                                                         NRES * CS, CS);
    gemm_tiled<<<dim3(8, CS / 64, 4), b256, 0, stream>>>(concat, Wo, nullptr, nullptr, out1,
                                                         NRES, OUT_DIM, CS, 0, 528, 0);

    // 6. LN1 + FF (k-split 4, relu folded into consumer A-load) + LN2
    ln_kernel<<<dim3(NRES), dim3(128), 0, stream>>>(out1, ln1_g, ln1_b, sln);
    init_bias_kernel<<<dim3((NRES * CS + 255) / 256), b256, 0, stream>>>(b1, nullptr, h1,
                                                                         NRES * CS, CS);
    init_bias_kernel<<<dim3((NRES * CS + 255) / 256), b256, 0, stream>>>(b2, nullptr, h2,
                                                                         NRES * CS, CS);
    gemm_tiled<<<dim3(8, CS / 64, 4), b256, 0, stream>>>(sln, W1, nullptr, nullptr, h1,
                                                         NRES, CS, CS, 0, 96, 0);
    gemm_tiled<<<dim3(8, CS / 64, 4), b256, 0, stream>>>(h1, W2, nullptr, nullptr, h2,
                                                         NRES, CS, CS, 0, 96, 1);
    init_bias_kernel<<<dim3((NRES * CS + 255) / 256), b256, 0, stream>>>(b3, sln, out1,
                                                                         NRES * CS, CS);
    gemm_tiled<<<dim3(8, CS / 64, 4), b256, 0, stream>>>(h2, W3, nullptr, nullptr, out1,
                                                         NRES, CS, CS, 0, 96, 1);
    ln_kernel<<<dim3(NRES), dim3(128), 0, stream>>>(out1, ln2_g, ln2_b, single_out);

    // 7. backbone (zeroes loss) + loss
    backbone_kernel<<<dim3(NRES), dim3(128), 0, stream>>>(single_out, Wbu, bbu, rot, trans,
                                                          rot_out, trans_out, loss_out);
    loss_kernel<<<dim3(NRES), b256, 0, stream>>>(rot_out, trans_out, rot_truth, trans_truth,
                                                 loss_out);
}

// Round 16
// 266.998 us; speedup vs baseline: 1.1840x; 1.0304x over previous
//
#include <hip/hip_runtime.h>
#include <hip/hip_bf16.h>
#include <math.h>

#define NRES 512
#define CS 384
#define CZ 128
#define NH 12
#define PQ 4
#define PV 8
#define OUT_DIM 2112   // H*(C + 3*PV + PV + CZ)
#define PRJ 1152       // packed projection width: q192|k192|v192|qp144|kp144|vp288

typedef __attribute__((ext_vector_type(8))) short short8;
typedef __attribute__((ext_vector_type(4))) float f32x4;

__device__ __forceinline__ float softplusf(float x) { return log1pf(expf(x)); }

__device__ __forceinline__ unsigned short f2bf(float f) {
    union { float f; unsigned u; } v; v.f = f;
    unsigned r = v.u + 0x7FFF + ((v.u >> 16) & 1);
    return (unsigned short)(r >> 16);
}

__device__ __forceinline__ unsigned cvt_pk_bf16(float lo, float hi) {
    unsigned r;
    asm volatile("v_cvt_pk_bf16_f32 %0, %1, %2" : "=v"(r) : "v"(lo), "v"(hi));
    return r;
}

// ---------------------------------------------------------------------------
// Pack 6 projection weights into Bp[384][1152] + Wb MFMA B-fragments
// + zero proj (avoids slow runtime fillBuffer in-graph).
// ---------------------------------------------------------------------------
__global__ void pack_proj_kernel(const float* __restrict__ Wq, const float* __restrict__ Wk,
                                 const float* __restrict__ Wv, const float* __restrict__ Wqp,
                                 const float* __restrict__ Wkp, const float* __restrict__ Wvp,
                                 const float* __restrict__ Wb,
                                 float* __restrict__ Bp, unsigned short* __restrict__ wbfrag,
                                 float* __restrict__ proj)
{
    int x = blockIdx.x * blockDim.x + threadIdx.x;
    if (x < CS * PRJ) {
        int k = x / PRJ, c = x % PRJ;
        float v;
        if      (c < 192)  v = Wq [k * 192 + c];
        else if (c < 384)  v = Wk [k * 192 + (c - 192)];
        else if (c < 576)  v = Wv [k * 192 + (c - 384)];
        else if (c < 720)  v = Wqp[k * 144 + (c - 576)];
        else if (c < 864)  v = Wkp[k * 144 + (c - 720)];
        else               v = Wvp[k * 288 + (c - 864)];
        Bp[x] = v;
    } else if (x < CS * PRJ + 2048) {
        int idx = x - CS * PRJ;               // ks*512 + lane*8 + e
        int ks = idx >> 9, r = idx & 511;
        int lane = r >> 3, e = r & 7;
        int col = lane & 15, kb = (lane >> 4) * 8;
        int row = ks * 32 + kb + e;
        float v = (col < NH) ? Wb[row * NH + col] : 0.f;
        wbfrag[idx] = f2bf(v);
    } else {
        int idx = x - (CS * PRJ + 2048);
        if (idx < NRES * PRJ) proj[idx] = 0.f;
    }
}

// ---------------------------------------------------------------------------
// Tiled f32 GEMM: BM=64, BN=64, BK=16, 256 threads, 4x4 micro-tile.
// reluA: relu A on load. gridDim.z>1: k-split partial, atomicAdd into pre-init C.
// ---------------------------------------------------------------------------
__global__ void gemm_tiled(const float* __restrict__ A, const float* __restrict__ B,
                           const float* __restrict__ bias, const float* __restrict__ res,
                           float* __restrict__ C, int M, int K, int Nc, int relu, int KS,
                           int reluA)
{
    __shared__ float As[16][68];
    __shared__ float Bs[16][64];
    int m0 = blockIdx.x * 64, n0 = blockIdx.y * 64;
    int kbeg = blockIdx.z * KS;
    int t = threadIdx.x;
    int tm = t >> 4, tn = t & 15;
    int lr = t >> 2, lc4 = t & 3;
    int br = t >> 4, bc4 = t & 15;
    float acc[4][4] = {{0.f}};

    for (int kt = kbeg; kt < kbeg + KS; kt += 16) {
        float4 a4 = *(const float4*)&A[(size_t)(m0 + lr) * K + kt + lc4 * 4];
        float4 b4 = *(const float4*)&B[(size_t)(kt + br) * Nc + n0 + bc4 * 4];
        if (reluA) {
            a4.x = fmaxf(a4.x, 0.f); a4.y = fmaxf(a4.y, 0.f);
            a4.z = fmaxf(a4.z, 0.f); a4.w = fmaxf(a4.w, 0.f);
        }
        As[lc4 * 4 + 0][lr] = a4.x;
        As[lc4 * 4 + 1][lr] = a4.y;
        As[lc4 * 4 + 2][lr] = a4.z;
        As[lc4 * 4 + 3][lr] = a4.w;
        *(float4*)&Bs[br][bc4 * 4] = b4;
        __syncthreads();
#pragma unroll
        for (int k = 0; k < 16; ++k) {
            float4 av = *(const float4*)&As[k][tm * 4];
            float4 bv = *(const float4*)&Bs[k][tn * 4];
            acc[0][0] = fmaf(av.x, bv.x, acc[0][0]); acc[0][1] = fmaf(av.x, bv.y, acc[0][1]);
            acc[0][2] = fmaf(av.x, bv.z, acc[0][2]); acc[0][3] = fmaf(av.x, bv.w, acc[0][3]);
            acc[1][0] = fmaf(av.y, bv.x, acc[1][0]); acc[1][1] = fmaf(av.y, bv.y, acc[1][1]);
            acc[1][2] = fmaf(av.y, bv.z, acc[1][2]); acc[1][3] = fmaf(av.y, bv.w, acc[1][3]);
            acc[2][0] = fmaf(av.z, bv.x, acc[2][0]); acc[2][1] = fmaf(av.z, bv.y, acc[2][1]);
            acc[2][2] = fmaf(av.z, bv.z, acc[2][2]); acc[2][3] = fmaf(av.z, bv.w, acc[2][3]);
            acc[3][0] = fmaf(av.w, bv.x, acc[3][0]); acc[3][1] = fmaf(av.w, bv.y, acc[3][1]);
            acc[3][2] = fmaf(av.w, bv.z, acc[3][2]); acc[3][3] = fmaf(av.w, bv.w, acc[3][3]);
        }
        __syncthreads();
    }

    if (gridDim.z > 1) {
#pragma unroll
        for (int r = 0; r < 4; ++r)
#pragma unroll
            for (int c = 0; c < 4; ++c)
                atomicAdd(&C[(size_t)(m0 + tm * 4 + r) * Nc + n0 + tn * 4 + c], acc[r][c]);
    } else {
#pragma unroll
        for (int r = 0; r < 4; ++r) {
            int row = m0 + tm * 4 + r;
            float4 v;
            float* vp = (float*)&v;
#pragma unroll
            for (int c = 0; c < 4; ++c) {
                int col = n0 + tn * 4 + c;
                float x = acc[r][c];
                if (bias) x += bias[col];
                if (res)  x += res[(size_t)row * Nc + col];
                if (relu) x = fmaxf(x, 0.f);
                vp[c] = x;
            }
            *(float4*)&C[(size_t)row * Nc + n0 + tn * 4] = v;
        }
    }
}

// ---------------------------------------------------------------------------
// init: out[x] = bias[x % Nc] (+ res[x])
// ---------------------------------------------------------------------------
__global__ void init_bias_kernel(const float* __restrict__ bias, const float* __restrict__ res,
                                 float* __restrict__ out, int total, int Nc)
{
    int x = blockIdx.x * blockDim.x + threadIdx.x;
    if (x >= total) return;
    float v = bias[x % Nc];
    if (res) v += res[x];
    out[x] = v;
}

// ---------------------------------------------------------------------------
// Frames: one thread per (n, h).
// ---------------------------------------------------------------------------
__global__ void frames_kernel(const float* __restrict__ proj, const float* __restrict__ rot,
                              const float* __restrict__ trans,
                              float* __restrict__ gq, float* __restrict__ gv,
                              float* __restrict__ sqq,
                              float* __restrict__ kT, float* __restrict__ gkT,
                              float* __restrict__ sqkT)
{
    int x = blockIdx.x * blockDim.x + threadIdx.x;
    if (x >= NRES * NH) return;
    int n = x / NH, h = x % NH;
    float R[9], t3[3];
#pragma unroll
    for (int r = 0; r < 9; ++r) R[r] = rot[n * 9 + r];
#pragma unroll
    for (int r = 0; r < 3; ++r) t3[r] = trans[n * 3 + r];
    const float* qp = proj + (size_t)n * PRJ + 576 + h * (PQ * 3);
    const float* kp = proj + (size_t)n * PRJ + 720 + h * (PQ * 3);
    const float* vp = proj + (size_t)n * PRJ + 864 + h * (PV * 3);
    const float* kk = proj + (size_t)n * PRJ + 192 + h * 16;

#pragma unroll
    for (int c = 0; c < 16; ++c) kT[(h * 16 + c) * NRES + n] = kk[c];

    float sq = 0.f, sk = 0.f;
#pragma unroll
    for (int p = 0; p < PQ; ++p) {
        const float* in = qp + p * 3;
        float* og = gq + (size_t)n * 144 + h * (PQ * 3) + p * 3;
#pragma unroll
        for (int a = 0; a < 3; ++a) {
            float g = R[a*3+0]*in[0] + R[a*3+1]*in[1] + R[a*3+2]*in[2] + t3[a];
            og[a] = g; sq += g * g;
        }
        const float* in2 = kp + p * 3;
#pragma unroll
        for (int a = 0; a < 3; ++a) {
            float g = R[a*3+0]*in2[0] + R[a*3+1]*in2[1] + R[a*3+2]*in2[2] + t3[a];
            gkT[(h * 12 + p * 3 + a) * NRES + n] = g;
            sk += g * g;
        }
    }
    sqq[n * NH + h] = sq;
    sqkT[h * NRES + n] = sk;
#pragma unroll
    for (int p = 0; p < PV; ++p) {
        const float* in = vp + p * 3;
        float* og = gv + (size_t)n * 288 + h * (PV * 3) + p * 3;
#pragma unroll
        for (int a = 0; a < 3; ++a)
            og[a] = R[a*3+0]*in[0] + R[a*3+1]*in[1] + R[a*3+2]*in[2] + t3[a];
    }
}

// ---------------------------------------------------------------------------
// Logits v8: grid (i=512, jt=8), block 256 (4 waves), one 64-j tile.
// MFMA A-fragments loaded directly from global pair (no staging LDS).
// Writes PRE-SOFTMAX logits to L (softmax fused into attn_out).
// ---------------------------------------------------------------------------
__global__ void logits_mfma_kernel(const float* __restrict__ pair, const float* __restrict__ proj,
                                   const float* __restrict__ gq, const float* __restrict__ kT,
                                   const float* __restrict__ gkT, const float* __restrict__ sqq,
                                   const float* __restrict__ sqkT,
                                   const unsigned short* __restrict__ wbfrag,
                                   const float* __restrict__ gamma_raw, float* __restrict__ L)
{
    __shared__ float bias_s[64 * 17];         // 4.25 KB
    __shared__ float qi[192], gqi[144], sqi[12], gam[12];

    int i = blockIdx.x, jt = blockIdx.y, t = threadIdx.x;
    int lane = t & 63, w = t >> 6;

    int arow = w * 16 + (lane & 15);
    int zofs = (lane >> 4) * 8;
    const float* arow_p = pair + ((size_t)i * NRES + jt * 64 + arow) * CZ + zofs;
    float4 a0 = *(const float4*)(arow_p + 0);
    float4 a1 = *(const float4*)(arow_p + 4);
    float4 b0 = *(const float4*)(arow_p + 32);
    float4 b1 = *(const float4*)(arow_p + 36);
    float4 c0 = *(const float4*)(arow_p + 64);
    float4 c1 = *(const float4*)(arow_p + 68);
    float4 d0 = *(const float4*)(arow_p + 96);
    float4 d1 = *(const float4*)(arow_p + 100);

    short8 bfrag[4];
#pragma unroll
    for (int ks = 0; ks < 4; ++ks)
        bfrag[ks] = *(const short8*)&wbfrag[ks * 512 + lane * 8];

    for (int x = t; x < 192; x += 256) qi[x] = proj[(size_t)i * PRJ + x];
    for (int x = t; x < 144; x += 256) gqi[x] = gq[(size_t)i * 144 + x];
    if (t < 12) { sqi[t] = sqq[i * 12 + t]; gam[t] = softplusf(gamma_raw[t]); }

    {
        f32x4 acc = {0.f, 0.f, 0.f, 0.f};
        short8 f;
        unsigned* fu = (unsigned*)&f;
        fu[0] = cvt_pk_bf16(a0.x, a0.y); fu[1] = cvt_pk_bf16(a0.z, a0.w);
        fu[2] = cvt_pk_bf16(a1.x, a1.y); fu[3] = cvt_pk_bf16(a1.z, a1.w);
        acc = __builtin_amdgcn_mfma_f32_16x16x32_bf16(f, bfrag[0], acc, 0, 0, 0);
        fu[0] = cvt_pk_bf16(b0.x, b0.y); fu[1] = cvt_pk_bf16(b0.z, b0.w);
        fu[2] = cvt_pk_bf16(b1.x, b1.y); fu[3] = cvt_pk_bf16(b1.z, b1.w);
        acc = __builtin_amdgcn_mfma_f32_16x16x32_bf16(f, bfrag[1], acc, 0, 0, 0);
        fu[0] = cvt_pk_bf16(c0.x, c0.y); fu[1] = cvt_pk_bf16(c0.z, c0.w);
        fu[2] = cvt_pk_bf16(c1.x, c1.y); fu[3] = cvt_pk_bf16(c1.z, c1.w);
        acc = __builtin_amdgcn_mfma_f32_16x16x32_bf16(f, bfrag[2], acc, 0, 0, 0);
        fu[0] = cvt_pk_bf16(d0.x, d0.y); fu[1] = cvt_pk_bf16(d0.z, d0.w);
        fu[2] = cvt_pk_bf16(d1.x, d1.y); fu[3] = cvt_pk_bf16(d1.z, d1.w);
        acc = __builtin_amdgcn_mfma_f32_16x16x32_bf16(f, bfrag[3], acc, 0, 0, 0);
        int crow = w * 16 + (lane >> 4) * 4;
        int ccol = lane & 15;
#pragma unroll
        for (int r = 0; r < 4; ++r) bias_s[(crow + r) * 17 + ccol] = acc[r];
    }
    __syncthreads();

    const float WLc = 0.57735026918962576f;
    const float WCc = 0.23570226039551584f;
    int j = jt * 64 + lane;
#pragma unroll
    for (int hh = 0; hh < 3; ++hh) {
        int h = w * 3 + hh;
        float qk = 0.f;
#pragma unroll
        for (int c = 0; c < 16; ++c)
            qk = fmaf(qi[h * 16 + c], kT[(h * 16 + c) * NRES + j], qk);
        float cross = 0.f;
#pragma unroll
        for (int x = 0; x < 12; ++x)
            cross = fmaf(gqi[h * 12 + x], gkT[(h * 12 + x) * NRES + j], cross);
        float d2 = sqi[h] + sqkT[h * NRES + j] - 2.f * cross;
        float logit = WLc * (qk * 0.25f + bias_s[lane * 17 + h] - 0.5f * WCc * gam[h] * d2);
        L[((size_t)i * NH + h) * NRES + j] = logit;
    }
}

// ---------------------------------------------------------------------------
// Fused attention outputs + softmax: stage RAW logits, softmax in LDS
// (exp written in place, 1/sum folded into the combine stores), then
// o_pair + o_v + o_pt + local/norms. Block per i, 1024 threads.
// ---------------------------------------------------------------------------
__global__ __launch_bounds__(1024) void attn_out_kernel(const float* __restrict__ pair,
                                                        const float* __restrict__ A,
                                                        const float* __restrict__ proj,
                                                        const float* __restrict__ gv,
                                                        const float* __restrict__ rot,
                                                        const float* __restrict__ trans,
                                                        float* __restrict__ concat)
{
    __shared__ float al[NH * NRES];     // 24 KB
    __shared__ float4 part4[768];       // 12 KB (opair partials)
    __shared__ float partv[960];        // 3.75 KB (ov/opt partials)
    __shared__ float opt[NH * PV * 3];  // 1.125 KB
    __shared__ float sred[NH][32];      // softmax partials
    __shared__ float mh[NH], invh[NH];
    int i = blockIdx.x, t = threadIdx.x;
    for (int x = t; x < NH * NRES / 4; x += 1024)
        *(float4*)&al[x * 4] = *(const float4*)&A[(size_t)i * NH * NRES + x * 4];
    __syncthreads();

    // --- softmax over j per h-row (in LDS; conflict-free stride-32 scans) ---
    if (t < NH * 32) {
        int h = t >> 5, l = t & 31;
        float m = -1e30f;
#pragma unroll
        for (int e = 0; e < 16; ++e) m = fmaxf(m, al[h * NRES + l + e * 32]);
        sred[h][l] = m;
    }
    __syncthreads();
    if (t < NH) {
        float m = -1e30f;
#pragma unroll
        for (int l = 0; l < 32; ++l) m = fmaxf(m, sred[t][l]);
        mh[t] = m;
    }
    __syncthreads();
    if (t < NH * 32) {
        int h = t >> 5, l = t & 31;
        float m = mh[h], s = 0.f;
#pragma unroll
        for (int e = 0; e < 16; ++e) {
            int idx = h * NRES + l + e * 32;
            float ex = expf(al[idx] - m);
            al[idx] = ex;
            s += ex;
        }
        sred[h][l] = s;
    }
    __syncthreads();
    if (t < NH) {
        float s = 0.f;
#pragma unroll
        for (int l = 0; l < 32; ++l) s += sred[t][l];
        invh[t] = 1.f / s;
    }
    __syncthreads();

    // --- accumulate 1728 units (unnormalized; 1/sum folded at stores) ---
    for (int u = t; u < 1728; u += 1024) {
        if (u < 768) {
            int jh = u / 384;
            int sub = u - jh * 384;
            int zq = sub & 31, h = sub >> 5;
            float4 acc = {0.f, 0.f, 0.f, 0.f};
            const float* pr = pair + (size_t)i * NRES * CZ + (size_t)jh * 256 * CZ;
            const float* ah = al + h * NRES + jh * 256;
            for (int j = 0; j < 256; ++j) {
                float4 p4 = *(const float4*)&pr[(size_t)j * CZ + zq * 4];
                float a = ah[j];
                acc.x = fmaf(a, p4.x, acc.x);
                acc.y = fmaf(a, p4.y, acc.y);
                acc.z = fmaf(a, p4.z, acc.z);
                acc.w = fmaf(a, p4.w, acc.w);
            }
            part4[u] = acc;
        } else {
            int v = u - 768;
            int jh = v / 480;
            int elem = v - jh * 480;
            float acc = 0.f;
            if (elem < 192) {
                int h = elem >> 4;
                const float* ah = al + h * NRES + jh * 256;
                const float* pv = proj + (size_t)(jh * 256) * PRJ + 384 + elem;
                for (int j = 0; j < 256; ++j) { acc = fmaf(ah[j], *pv, acc); pv += PRJ; }
            } else {
                int e = elem - 192;
                int h = e / 24;
                const float* ah = al + h * NRES + jh * 256;
                const float* pv = gv + (size_t)(jh * 256) * 288 + e;
                for (int j = 0; j < 256; ++j) { acc = fmaf(ah[j], *pv, acc); pv += 288; }
            }
            partv[v] = acc;
        }
    }
    __syncthreads();

    if (t < 384) {   // opair combine + normalize + store
        int zq = t & 31, h = t >> 5;
        float inv = invh[h];
        float4 a = part4[t], b = part4[t + 384];
        float4 o;
        o.x = (a.x + b.x) * inv; o.y = (a.y + b.y) * inv;
        o.z = (a.z + b.z) * inv; o.w = (a.w + b.w) * inv;
        *(float4*)&concat[(size_t)i * OUT_DIM + 576 + h * 128 + zq * 4] = o;
    } else if (t >= 512 && t < 992) {   // ov/opt combine + normalize
        int elem = t - 512;
        float v = partv[elem] + partv[elem + 480];
        if (elem < 192) {
            int h = elem >> 4;
            concat[(size_t)i * OUT_DIM + elem] = v * invh[h];
        } else {
            int e = elem - 192;
            int h = e / 24;
            opt[e] = v * invh[h];
        }
    }
    __syncthreads();
    if (t < 96) {   // finalize local/norms
        int h = t >> 3, p = t & 7;
        float b0 = opt[h * 24 + p * 3 + 0] - trans[i * 3 + 0];
        float b1 = opt[h * 24 + p * 3 + 1] - trans[i * 3 + 1];
        float b2 = opt[h * 24 + p * 3 + 2] - trans[i * 3 + 2];
        const float* Ri = rot + i * 9;
        float l0 = Ri[0] * b0 + Ri[3] * b1 + Ri[6] * b2;
        float l1 = Ri[1] * b0 + Ri[4] * b1 + Ri[7] * b2;
        float l2 = Ri[2] * b0 + Ri[5] * b1 + Ri[8] * b2;
        float* c = concat + (size_t)i * OUT_DIM;
        c[192 + h * 24 + p * 3 + 0] = l0;
        c[192 + h * 24 + p * 3 + 1] = l1;
        c[192 + h * 24 + p * 3 + 2] = l2;
        c[480 + h * 8 + p] = sqrtf(l0 * l0 + l1 * l1 + l2 * l2 + 1e-8f);
    }
}

// ---------------------------------------------------------------------------
// LayerNorm over 384
// ---------------------------------------------------------------------------
__global__ void ln_kernel(const float* __restrict__ x, const float* __restrict__ g,
                          const float* __restrict__ b, float* __restrict__ y)
{
    int i = blockIdx.x, t = threadIdx.x;
    const float* xr = x + (size_t)i * CS;
    float a0 = xr[t], a1 = xr[t + 128], a2 = xr[t + 256];
    __shared__ float red[128];
    red[t] = a0 + a1 + a2;
    __syncthreads();
    for (int s = 64; s > 0; s >>= 1) { if (t < s) red[t] += red[t + s]; __syncthreads(); }
    float mean = red[0] * (1.f / CS);
    __syncthreads();
    float d0 = a0 - mean, d1 = a1 - mean, d2 = a2 - mean;
    red[t] = d0 * d0 + d1 * d1 + d2 * d2;
    __syncthreads();
    for (int s = 64; s > 0; s >>= 1) { if (t < s) red[t] += red[t + s]; __syncthreads(); }
    float rstd = rsqrtf(red[0] * (1.f / CS) + 1e-5f);
    float* yr = y + (size_t)i * CS;
    yr[t]       = d0 * rstd * g[t]       + b[t];
    yr[t + 128] = d1 * rstd * g[t + 128] + b[t + 128];
    yr[t + 256] = d2 * rstd * g[t + 256] + b[t + 256];
}

// ---------------------------------------------------------------------------
// Backbone (+ zero loss for the following loss kernel)
// ---------------------------------------------------------------------------
__global__ void backbone_kernel(const float* __restrict__ sfin, const float* __restrict__ Wbu,
                                const float* __restrict__ bbu, const float* __restrict__ rot,
                                const float* __restrict__ trans, float* __restrict__ rot_out,
                                float* __restrict__ trans_out, float* __restrict__ loss)
{
    int i = blockIdx.x, t = threadIdx.x;
    if (i == 0 && t == 0) *loss = 0.f;
    float part[6] = {0.f, 0.f, 0.f, 0.f, 0.f, 0.f};
    for (int k = t; k < CS; k += 128) {
        float s = sfin[(size_t)i * CS + k];
        const float* wr = Wbu + k * 6;
#pragma unroll
        for (int c = 0; c < 6; ++c) part[c] = fmaf(s, wr[c], part[c]);
    }
    __shared__ float red[6][128];
#pragma unroll
    for (int c = 0; c < 6; ++c) red[c][t] = part[c];
    __syncthreads();
    for (int s = 64; s > 0; s >>= 1) {
        if (t < s) {
#pragma unroll
            for (int c = 0; c < 6; ++c) red[c][t] += red[c][t + s];
        }
        __syncthreads();
    }
    if (t == 0) {
        float u[6];
#pragma unroll
        for (int c = 0; c < 6; ++c) u[c] = red[c][0] + bbu[c];
        float a = 1.f, b = u[0], c2 = u[1], d = u[2];
        float inv = rsqrtf(a * a + b * b + c2 * c2 + d * d);
        a *= inv; b *= inv; c2 *= inv; d *= inv;
        float R[9] = { a*a + b*b - c2*c2 - d*d, 2.f*(b*c2 - a*d),        2.f*(b*d + a*c2),
                       2.f*(b*c2 + a*d),        a*a - b*b + c2*c2 - d*d, 2.f*(c2*d - a*b),
                       2.f*(b*d - a*c2),        2.f*(c2*d + a*b),        a*a - b*b - c2*c2 + d*d };
        const float* Ri = rot + i * 9;
        float Rn[9];
#pragma unroll
        for (int r = 0; r < 3; ++r)
#pragma unroll
            for (int cc = 0; cc < 3; ++cc) {
                float s2 = 0.f;
#pragma unroll
                for (int kk = 0; kk < 3; ++kk) s2 += Ri[r * 3 + kk] * R[kk * 3 + cc];
                Rn[r * 3 + cc] = s2;
            }
#pragma unroll
        for (int r = 0; r < 9; ++r) rot_out[i * 9 + r] = Rn[r];
        float t0 = u[3], t1 = u[4], t2 = u[5];
#pragma unroll
        for (int r = 0; r < 3; ++r)
            trans_out[i * 3 + r] = Ri[r * 3 + 0] * t0 + Ri[r * 3 + 1] * t1 + Ri[r * 3 + 2] * t2 + trans[i * 3 + r];
    }
}

// ---------------------------------------------------------------------------
// Loss
// ---------------------------------------------------------------------------
__global__ void loss_kernel(const float* __restrict__ rot_new, const float* __restrict__ trans_new,
                            const float* __restrict__ rot_truth, const float* __restrict__ trans_truth,
                            float* __restrict__ loss)
{
    int i = blockIdx.x;
    int t = threadIdx.x;
    __shared__ float red[256];
    float Rn[9], Rt[9];
#pragma unroll
    for (int r = 0; r < 9; ++r) { Rn[r] = rot_new[i * 9 + r]; Rt[r] = rot_truth[i * 9 + r]; }
    float ti0 = trans_new[i * 3 + 0], ti1 = trans_new[i * 3 + 1], ti2 = trans_new[i * 3 + 2];
    float tt0 = trans_truth[i * 3 + 0], tt1 = trans_truth[i * 3 + 1], tt2 = trans_truth[i * 3 + 2];
    float s = 0.f;
    for (int j = t; j < NRES; j += 256) {
        float db0 = trans_new[j * 3 + 0] - ti0;
        float db1 = trans_new[j * 3 + 1] - ti1;
        float db2 = trans_new[j * 3 + 2] - ti2;
        float dp0 = Rn[0] * db0 + Rn[3] * db1 + Rn[6] * db2;
        float dp1 = Rn[1] * db0 + Rn[4] * db1 + Rn[7] * db2;
        float dp2 = Rn[2] * db0 + Rn[5] * db1 + Rn[8] * db2;
        float eb0 = trans_truth[j * 3 + 0] - tt0;
        float eb1 = trans_truth[j * 3 + 1] - tt1;
        float eb2 = trans_truth[j * 3 + 2] - tt2;
        float dt0 = Rt[0] * eb0 + Rt[3] * eb1 + Rt[6] * eb2;
        float dt1 = Rt[1] * eb0 + Rt[4] * eb1 + Rt[7] * eb2;
        float dt2 = Rt[2] * eb0 + Rt[5] * eb1 + Rt[8] * eb2;
        float dx = dp0 - dt0, dy = dp1 - dt1, dz = dp2 - dt2;
        float dd = sqrtf(dx * dx + dy * dy + dz * dz + 1e-12f);
        s += fminf(dd, 10.f);
    }
    red[t] = s;
    __syncthreads();
    for (int k = 128; k > 0; k >>= 1) { if (t < k) red[t] += red[t + k]; __syncthreads(); }
    if (t == 0) atomicAdd(loss, red[0] * (1.f / (512.f * 512.f * 10.f)));
}

// ---------------------------------------------------------------------------
extern "C" void kernel_launch(void* const* d_in, const int* in_sizes, int n_in,
                              void* d_out, int out_size, void* d_ws, size_t ws_size,
                              hipStream_t stream)
{
    const float* single      = (const float*)d_in[0];
    const float* pair        = (const float*)d_in[1];
    const float* rot         = (const float*)d_in[2];
    const float* trans       = (const float*)d_in[3];
    const float* rot_truth   = (const float*)d_in[4];
    const float* trans_truth = (const float*)d_in[5];
    const float* Wq  = (const float*)d_in[6];
    const float* Wk  = (const float*)d_in[7];
    const float* Wv  = (const float*)d_in[8];
    const float* Wqp = (const float*)d_in[9];
    const float* Wkp = (const float*)d_in[10];
    const float* Wvp = (const float*)d_in[11];
    const float* Wb  = (const float*)d_in[12];
    const float* Wo  = (const float*)d_in[13];
    const float* bo  = (const float*)d_in[14];
    const float* gamma_raw = (const float*)d_in[15];
    const float* ln1_g = (const float*)d_in[16];
    const float* ln1_b = (const float*)d_in[17];
    const float* ln2_g = (const float*)d_in[18];
    const float* ln2_b = (const float*)d_in[19];
    const float* W1 = (const float*)d_in[20];
    const float* b1 = (const float*)d_in[21];
    const float* W2 = (const float*)d_in[22];
    const float* b2 = (const float*)d_in[23];
    const float* W3 = (const float*)d_in[24];
    const float* b3 = (const float*)d_in[25];
    const float* Wbu = (const float*)d_in[26];
    const float* bbu = (const float*)d_in[27];

    float* out = (float*)d_out;
    float* single_out = out;                   // 512*384
    float* rot_out    = out + 196608;          // 512*9
    float* trans_out  = out + 201216;          // 512*3
    float* loss_out   = out + 202752;          // 1

    float* ws = (float*)d_ws;
    float* proj   = ws;                         // 589824
    float* gq     = proj   + 589824;            // 73728
    float* gv     = gq     + 73728;             // 147456
    float* sqq    = gv     + 147456;            // 6144
    float* kT     = sqq    + 6144;              // 98304
    float* gkT    = kT     + 98304;             // 73728
    float* sqkT   = gkT    + 73728;             // 6144
    float* wbfragf= sqkT   + 6144;              // 1024 (2048 ushorts)
    float* Amat   = wbfragf+ 1024;              // 3145728
    float* Bp     = Amat;                       // alias: dead after proj GEMM
    float* concat = Amat   + 3145728;           // 1081344
    float* out1   = concat + 1081344;           // 196608
    float* sln    = out1   + 196608;            // 196608
    float* h1     = sln    + 196608;            // 196608
    float* h2     = h1     + 196608;            // 196608
    unsigned short* wbfrag = (unsigned short*)wbfragf;

    dim3 b256(256);

    // 1. pack weights (+ Wb frags + zero proj); projection GEMM (k-split 2)
    int pack_total = CS * PRJ + 2048 + NRES * PRJ;
    pack_proj_kernel<<<dim3((pack_total + 255) / 256), b256, 0, stream>>>(
        Wq, Wk, Wv, Wqp, Wkp, Wvp, Wb, Bp, wbfrag, proj);
    gemm_tiled<<<dim3(8, PRJ / 64, 2), b256, 0, stream>>>(single, Bp, nullptr, nullptr, proj,
                                                          NRES, CS, PRJ, 0, 192, 0);

    // 2. frames
    frames_kernel<<<dim3((NRES * NH + 255) / 256), b256, 0, stream>>>(proj, rot, trans,
                                                                      gq, gv, sqq, kT, gkT, sqkT);

    // 3. logits (pre-softmax)
    logits_mfma_kernel<<<dim3(NRES, 8), b256, 0, stream>>>(pair, proj, gq, kT, gkT, sqq, sqkT,
                                                           wbfrag, gamma_raw, Amat);

    // 4. fused softmax + attention outputs
    attn_out_kernel<<<dim3(NRES), dim3(1024), 0, stream>>>(pair, Amat, proj, gv, rot, trans,
                                                           concat);

    // 5. ipa_out = concat @ Wo + bo + single  (k-split 4, atomic into pre-init)
    init_bias_kernel<<<dim3((NRES * CS + 255) / 256), b256, 0, stream>>>(bo, single, out1,
                                                                         NRES * CS, CS);
    gemm_tiled<<<dim3(8, CS / 64, 4), b256, 0, stream>>>(concat, Wo, nullptr, nullptr, out1,
                                                         NRES, OUT_DIM, CS, 0, 528, 0);

    // 6. LN1 + FF (k-split 4, relu folded into consumer A-load) + LN2
    ln_kernel<<<dim3(NRES), dim3(128), 0, stream>>>(out1, ln1_g, ln1_b, sln);
    init_bias_kernel<<<dim3((NRES * CS + 255) / 256), b256, 0, stream>>>(b1, nullptr, h1,
                                                                         NRES * CS, CS);
    init_bias_kernel<<<dim3((NRES * CS + 255) / 256), b256, 0, stream>>>(b2, nullptr, h2,
                                                                         NRES * CS, CS);
    gemm_tiled<<<dim3(8, CS / 64, 4), b256, 0, stream>>>(sln, W1, nullptr, nullptr, h1,
                                                         NRES, CS, CS, 0, 96, 0);
    gemm_tiled<<<dim3(8, CS / 64, 4), b256, 0, stream>>>(h1, W2, nullptr, nullptr, h2,
                                                         NRES, CS, CS, 0, 96, 1);
    init_bias_kernel<<<dim3((NRES * CS + 255) / 256), b256, 0, stream>>>(b3, sln, out1,
                                                                         NRES * CS, CS);
    gemm_tiled<<<dim3(8, CS / 64, 4), b256, 0, stream>>>(h2, W3, nullptr, nullptr, out1,
                                                         NRES, CS, CS, 0, 96, 1);
    ln_kernel<<<dim3(NRES), dim3(128), 0, stream>>>(out1, ln2_g, ln2_b, single_out);

    // 7. backbone (zeroes loss) + loss
    backbone_kernel<<<dim3(NRES), dim3(128), 0, stream>>>(single_out, Wbu, bbu, rot, trans,
                                                          rot_out, trans_out, loss_out);
    loss_kernel<<<dim3(NRES), b256, 0, stream>>>(rot_out, trans_out, rot_truth, trans_truth,
                                                 loss_out);
}

// Round 17
// 261.976 us; speedup vs baseline: 1.2067x; 1.0192x over previous
//
#include <hip/hip_runtime.h>
#include <hip/hip_bf16.h>
#include <math.h>

#define NRES 512
#define CS 384
#define CZ 128
#define NH 12
#define PQ 4
#define PV 8
#define OUT_DIM 2112   // H*(C + 3*PV + PV + CZ)
#define PRJ 1152       // packed projection width: q192|k192|v192|qp144|kp144|vp288

typedef __attribute__((ext_vector_type(8))) short short8;
typedef __attribute__((ext_vector_type(4))) float f32x4;

__device__ __forceinline__ float softplusf(float x) { return log1pf(expf(x)); }

__device__ __forceinline__ unsigned short f2bf(float f) {
    union { float f; unsigned u; } v; v.f = f;
    unsigned r = v.u + 0x7FFF + ((v.u >> 16) & 1);
    return (unsigned short)(r >> 16);
}

__device__ __forceinline__ unsigned cvt_pk_bf16(float lo, float hi) {
    unsigned r;
    asm volatile("v_cvt_pk_bf16_f32 %0, %1, %2" : "=v"(r) : "v"(lo), "v"(hi));
    return r;
}

// ---------------------------------------------------------------------------
// Pack 6 projection weights into Bp[384][1152] + Wb MFMA B-fragments
// + zero proj (avoids slow runtime fillBuffer in-graph).
// ---------------------------------------------------------------------------
__global__ void pack_proj_kernel(const float* __restrict__ Wq, const float* __restrict__ Wk,
                                 const float* __restrict__ Wv, const float* __restrict__ Wqp,
                                 const float* __restrict__ Wkp, const float* __restrict__ Wvp,
                                 const float* __restrict__ Wb,
                                 float* __restrict__ Bp, unsigned short* __restrict__ wbfrag,
                                 float* __restrict__ proj)
{
    int x = blockIdx.x * blockDim.x + threadIdx.x;
    if (x < CS * PRJ) {
        int k = x / PRJ, c = x % PRJ;
        float v;
        if      (c < 192)  v = Wq [k * 192 + c];
        else if (c < 384)  v = Wk [k * 192 + (c - 192)];
        else if (c < 576)  v = Wv [k * 192 + (c - 384)];
        else if (c < 720)  v = Wqp[k * 144 + (c - 576)];
        else if (c < 864)  v = Wkp[k * 144 + (c - 720)];
        else               v = Wvp[k * 288 + (c - 864)];
        Bp[x] = v;
    } else if (x < CS * PRJ + 2048) {
        int idx = x - CS * PRJ;               // ks*512 + lane*8 + e
        int ks = idx >> 9, r = idx & 511;
        int lane = r >> 3, e = r & 7;
        int col = lane & 15, kb = (lane >> 4) * 8;
        int row = ks * 32 + kb + e;
        float v = (col < NH) ? Wb[row * NH + col] : 0.f;
        wbfrag[idx] = f2bf(v);
    } else {
        int idx = x - (CS * PRJ + 2048);
        if (idx < NRES * PRJ) proj[idx] = 0.f;
    }
}

// ---------------------------------------------------------------------------
// Tiled f32 GEMM: BM=64, BN=64, BK=16, 256 threads, 4x4 micro-tile.
// reluA: relu A on load. gridDim.z>1: k-split partial, atomicAdd into pre-init C.
// ---------------------------------------------------------------------------
__global__ void gemm_tiled(const float* __restrict__ A, const float* __restrict__ B,
                           const float* __restrict__ bias, const float* __restrict__ res,
                           float* __restrict__ C, int M, int K, int Nc, int relu, int KS,
                           int reluA)
{
    __shared__ float As[16][68];
    __shared__ float Bs[16][64];
    int m0 = blockIdx.x * 64, n0 = blockIdx.y * 64;
    int kbeg = blockIdx.z * KS;
    int t = threadIdx.x;
    int tm = t >> 4, tn = t & 15;
    int lr = t >> 2, lc4 = t & 3;
    int br = t >> 4, bc4 = t & 15;
    float acc[4][4] = {{0.f}};

    for (int kt = kbeg; kt < kbeg + KS; kt += 16) {
        float4 a4 = *(const float4*)&A[(size_t)(m0 + lr) * K + kt + lc4 * 4];
        float4 b4 = *(const float4*)&B[(size_t)(kt + br) * Nc + n0 + bc4 * 4];
        if (reluA) {
            a4.x = fmaxf(a4.x, 0.f); a4.y = fmaxf(a4.y, 0.f);
            a4.z = fmaxf(a4.z, 0.f); a4.w = fmaxf(a4.w, 0.f);
        }
        As[lc4 * 4 + 0][lr] = a4.x;
        As[lc4 * 4 + 1][lr] = a4.y;
        As[lc4 * 4 + 2][lr] = a4.z;
        As[lc4 * 4 + 3][lr] = a4.w;
        *(float4*)&Bs[br][bc4 * 4] = b4;
        __syncthreads();
#pragma unroll
        for (int k = 0; k < 16; ++k) {
            float4 av = *(const float4*)&As[k][tm * 4];
            float4 bv = *(const float4*)&Bs[k][tn * 4];
            acc[0][0] = fmaf(av.x, bv.x, acc[0][0]); acc[0][1] = fmaf(av.x, bv.y, acc[0][1]);
            acc[0][2] = fmaf(av.x, bv.z, acc[0][2]); acc[0][3] = fmaf(av.x, bv.w, acc[0][3]);
            acc[1][0] = fmaf(av.y, bv.x, acc[1][0]); acc[1][1] = fmaf(av.y, bv.y, acc[1][1]);
            acc[1][2] = fmaf(av.y, bv.z, acc[1][2]); acc[1][3] = fmaf(av.y, bv.w, acc[1][3]);
            acc[2][0] = fmaf(av.z, bv.x, acc[2][0]); acc[2][1] = fmaf(av.z, bv.y, acc[2][1]);
            acc[2][2] = fmaf(av.z, bv.z, acc[2][2]); acc[2][3] = fmaf(av.z, bv.w, acc[2][3]);
            acc[3][0] = fmaf(av.w, bv.x, acc[3][0]); acc[3][1] = fmaf(av.w, bv.y, acc[3][1]);
            acc[3][2] = fmaf(av.w, bv.z, acc[3][2]); acc[3][3] = fmaf(av.w, bv.w, acc[3][3]);
        }
        __syncthreads();
    }

    if (gridDim.z > 1) {
#pragma unroll
        for (int r = 0; r < 4; ++r)
#pragma unroll
            for (int c = 0; c < 4; ++c)
                atomicAdd(&C[(size_t)(m0 + tm * 4 + r) * Nc + n0 + tn * 4 + c], acc[r][c]);
    } else {
#pragma unroll
        for (int r = 0; r < 4; ++r) {
            int row = m0 + tm * 4 + r;
            float4 v;
            float* vp = (float*)&v;
#pragma unroll
            for (int c = 0; c < 4; ++c) {
                int col = n0 + tn * 4 + c;
                float x = acc[r][c];
                if (bias) x += bias[col];
                if (res)  x += res[(size_t)row * Nc + col];
                if (relu) x = fmaxf(x, 0.f);
                vp[c] = x;
            }
            *(float4*)&C[(size_t)row * Nc + n0 + tn * 4] = v;
        }
    }
}

// ---------------------------------------------------------------------------
// Fused init: out1 = bo + single ; h1 = b1 ; h2 = b2  (one launch)
// ---------------------------------------------------------------------------
__global__ void init3_kernel(const float* __restrict__ bo, const float* __restrict__ single,
                             const float* __restrict__ b1, const float* __restrict__ b2,
                             float* __restrict__ out1, float* __restrict__ h1,
                             float* __restrict__ h2)
{
    int x = blockIdx.x * blockDim.x + threadIdx.x;
    if (x >= NRES * CS) return;
    int c = x % CS;
    out1[x] = bo[c] + single[x];
    h1[x] = b1[c];
    h2[x] = b2[c];
}

// ---------------------------------------------------------------------------
// Frames: one thread per (n, h).
// ---------------------------------------------------------------------------
__global__ void frames_kernel(const float* __restrict__ proj, const float* __restrict__ rot,
                              const float* __restrict__ trans,
                              float* __restrict__ gq, float* __restrict__ gv,
                              float* __restrict__ sqq,
                              float* __restrict__ kT, float* __restrict__ gkT,
                              float* __restrict__ sqkT)
{
    int x = blockIdx.x * blockDim.x + threadIdx.x;
    if (x >= NRES * NH) return;
    int n = x / NH, h = x % NH;
    float R[9], t3[3];
#pragma unroll
    for (int r = 0; r < 9; ++r) R[r] = rot[n * 9 + r];
#pragma unroll
    for (int r = 0; r < 3; ++r) t3[r] = trans[n * 3 + r];
    const float* qp = proj + (size_t)n * PRJ + 576 + h * (PQ * 3);
    const float* kp = proj + (size_t)n * PRJ + 720 + h * (PQ * 3);
    const float* vp = proj + (size_t)n * PRJ + 864 + h * (PV * 3);
    const float* kk = proj + (size_t)n * PRJ + 192 + h * 16;

#pragma unroll
    for (int c = 0; c < 16; ++c) kT[(h * 16 + c) * NRES + n] = kk[c];

    float sq = 0.f, sk = 0.f;
#pragma unroll
    for (int p = 0; p < PQ; ++p) {
        const float* in = qp + p * 3;
        float* og = gq + (size_t)n * 144 + h * (PQ * 3) + p * 3;
#pragma unroll
        for (int a = 0; a < 3; ++a) {
            float g = R[a*3+0]*in[0] + R[a*3+1]*in[1] + R[a*3+2]*in[2] + t3[a];
            og[a] = g; sq += g * g;
        }
        const float* in2 = kp + p * 3;
#pragma unroll
        for (int a = 0; a < 3; ++a) {
            float g = R[a*3+0]*in2[0] + R[a*3+1]*in2[1] + R[a*3+2]*in2[2] + t3[a];
            gkT[(h * 12 + p * 3 + a) * NRES + n] = g;
            sk += g * g;
        }
    }
    sqq[n * NH + h] = sq;
    sqkT[h * NRES + n] = sk;
#pragma unroll
    for (int p = 0; p < PV; ++p) {
        const float* in = vp + p * 3;
        float* og = gv + (size_t)n * 288 + h * (PV * 3) + p * 3;
#pragma unroll
        for (int a = 0; a < 3; ++a)
            og[a] = R[a*3+0]*in[0] + R[a*3+1]*in[1] + R[a*3+2]*in[2] + t3[a];
    }
}

// ---------------------------------------------------------------------------
// Logits: grid (i=512, jt=8), block 256 (4 waves), one 64-j tile.
// MFMA A-fragments loaded directly from global pair; pre-softmax output.
// ---------------------------------------------------------------------------
__global__ void logits_mfma_kernel(const float* __restrict__ pair, const float* __restrict__ proj,
                                   const float* __restrict__ gq, const float* __restrict__ kT,
                                   const float* __restrict__ gkT, const float* __restrict__ sqq,
                                   const float* __restrict__ sqkT,
                                   const unsigned short* __restrict__ wbfrag,
                                   const float* __restrict__ gamma_raw, float* __restrict__ L)
{
    __shared__ float bias_s[64 * 17];         // 4.25 KB
    __shared__ float qi[192], gqi[144], sqi[12], gam[12];

    int i = blockIdx.x, jt = blockIdx.y, t = threadIdx.x;
    int lane = t & 63, w = t >> 6;

    int arow = w * 16 + (lane & 15);
    int zofs = (lane >> 4) * 8;
    const float* arow_p = pair + ((size_t)i * NRES + jt * 64 + arow) * CZ + zofs;
    float4 a0 = *(const float4*)(arow_p + 0);
    float4 a1 = *(const float4*)(arow_p + 4);
    float4 b0 = *(const float4*)(arow_p + 32);
    float4 b1 = *(const float4*)(arow_p + 36);
    float4 c0 = *(const float4*)(arow_p + 64);
    float4 c1 = *(const float4*)(arow_p + 68);
    float4 d0 = *(const float4*)(arow_p + 96);
    float4 d1 = *(const float4*)(arow_p + 100);

    short8 bfrag[4];
#pragma unroll
    for (int ks = 0; ks < 4; ++ks)
        bfrag[ks] = *(const short8*)&wbfrag[ks * 512 + lane * 8];

    for (int x = t; x < 192; x += 256) qi[x] = proj[(size_t)i * PRJ + x];
    for (int x = t; x < 144; x += 256) gqi[x] = gq[(size_t)i * 144 + x];
    if (t < 12) { sqi[t] = sqq[i * 12 + t]; gam[t] = softplusf(gamma_raw[t]); }

    {
        f32x4 acc = {0.f, 0.f, 0.f, 0.f};
        short8 f;
        unsigned* fu = (unsigned*)&f;
        fu[0] = cvt_pk_bf16(a0.x, a0.y); fu[1] = cvt_pk_bf16(a0.z, a0.w);
        fu[2] = cvt_pk_bf16(a1.x, a1.y); fu[3] = cvt_pk_bf16(a1.z, a1.w);
        acc = __builtin_amdgcn_mfma_f32_16x16x32_bf16(f, bfrag[0], acc, 0, 0, 0);
        fu[0] = cvt_pk_bf16(b0.x, b0.y); fu[1] = cvt_pk_bf16(b0.z, b0.w);
        fu[2] = cvt_pk_bf16(b1.x, b1.y); fu[3] = cvt_pk_bf16(b1.z, b1.w);
        acc = __builtin_amdgcn_mfma_f32_16x16x32_bf16(f, bfrag[1], acc, 0, 0, 0);
        fu[0] = cvt_pk_bf16(c0.x, c0.y); fu[1] = cvt_pk_bf16(c0.z, c0.w);
        fu[2] = cvt_pk_bf16(c1.x, c1.y); fu[3] = cvt_pk_bf16(c1.z, c1.w);
        acc = __builtin_amdgcn_mfma_f32_16x16x32_bf16(f, bfrag[2], acc, 0, 0, 0);
        fu[0] = cvt_pk_bf16(d0.x, d0.y); fu[1] = cvt_pk_bf16(d0.z, d0.w);
        fu[2] = cvt_pk_bf16(d1.x, d1.y); fu[3] = cvt_pk_bf16(d1.z, d1.w);
        acc = __builtin_amdgcn_mfma_f32_16x16x32_bf16(f, bfrag[3], acc, 0, 0, 0);
        int crow = w * 16 + (lane >> 4) * 4;
        int ccol = lane & 15;
#pragma unroll
        for (int r = 0; r < 4; ++r) bias_s[(crow + r) * 17 + ccol] = acc[r];
    }
    __syncthreads();

    const float WLc = 0.57735026918962576f;
    const float WCc = 0.23570226039551584f;
    int j = jt * 64 + lane;
#pragma unroll
    for (int hh = 0; hh < 3; ++hh) {
        int h = w * 3 + hh;
        float qk = 0.f;
#pragma unroll
        for (int c = 0; c < 16; ++c)
            qk = fmaf(qi[h * 16 + c], kT[(h * 16 + c) * NRES + j], qk);
        float cross = 0.f;
#pragma unroll
        for (int x = 0; x < 12; ++x)
            cross = fmaf(gqi[h * 12 + x], gkT[(h * 12 + x) * NRES + j], cross);
        float d2 = sqi[h] + sqkT[h * NRES + j] - 2.f * cross;
        float logit = WLc * (qk * 0.25f + bias_s[lane * 17 + h] - 0.5f * WCc * gam[h] * d2);
        L[((size_t)i * NH + h) * NRES + j] = logit;
    }
}

// ---------------------------------------------------------------------------
// Fused attention outputs + softmax (R16 config, unchanged).
// ---------------------------------------------------------------------------
__global__ __launch_bounds__(1024) void attn_out_kernel(const float* __restrict__ pair,
                                                        const float* __restrict__ A,
                                                        const float* __restrict__ proj,
                                                        const float* __restrict__ gv,
                                                        const float* __restrict__ rot,
                                                        const float* __restrict__ trans,
                                                        float* __restrict__ concat)
{
    __shared__ float al[NH * NRES];     // 24 KB
    __shared__ float4 part4[768];       // 12 KB
    __shared__ float partv[960];        // 3.75 KB
    __shared__ float opt[NH * PV * 3];  // 1.125 KB
    __shared__ float sred[NH][32];
    __shared__ float mh[NH], invh[NH];
    int i = blockIdx.x, t = threadIdx.x;
    for (int x = t; x < NH * NRES / 4; x += 1024)
        *(float4*)&al[x * 4] = *(const float4*)&A[(size_t)i * NH * NRES + x * 4];
    __syncthreads();

    // softmax over j per h-row (stride-32 scans)
    if (t < NH * 32) {
        int h = t >> 5, l = t & 31;
        float m = -1e30f;
#pragma unroll
        for (int e = 0; e < 16; ++e) m = fmaxf(m, al[h * NRES + l + e * 32]);
        sred[h][l] = m;
    }
    __syncthreads();
    if (t < NH) {
        float m = -1e30f;
#pragma unroll
        for (int l = 0; l < 32; ++l) m = fmaxf(m, sred[t][l]);
        mh[t] = m;
    }
    __syncthreads();
    if (t < NH * 32) {
        int h = t >> 5, l = t & 31;
        float m = mh[h], s = 0.f;
#pragma unroll
        for (int e = 0; e < 16; ++e) {
            int idx = h * NRES + l + e * 32;
            float ex = expf(al[idx] - m);
            al[idx] = ex;
            s += ex;
        }
        sred[h][l] = s;
    }
    __syncthreads();
    if (t < NH) {
        float s = 0.f;
#pragma unroll
        for (int l = 0; l < 32; ++l) s += sred[t][l];
        invh[t] = 1.f / s;
    }
    __syncthreads();

    // accumulate 1728 units (unnormalized)
    for (int u = t; u < 1728; u += 1024) {
        if (u < 768) {
            int jh = u / 384;
            int sub = u - jh * 384;
            int zq = sub & 31, h = sub >> 5;
            float4 acc = {0.f, 0.f, 0.f, 0.f};
            const float* pr = pair + (size_t)i * NRES * CZ + (size_t)jh * 256 * CZ;
            const float* ah = al + h * NRES + jh * 256;
            for (int j = 0; j < 256; ++j) {
                float4 p4 = *(const float4*)&pr[(size_t)j * CZ + zq * 4];
                float a = ah[j];
                acc.x = fmaf(a, p4.x, acc.x);
                acc.y = fmaf(a, p4.y, acc.y);
                acc.z = fmaf(a, p4.z, acc.z);
                acc.w = fmaf(a, p4.w, acc.w);
            }
            part4[u] = acc;
        } else {
            int v = u - 768;
            int jh = v / 480;
            int elem = v - jh * 480;
            float acc = 0.f;
            if (elem < 192) {
                int h = elem >> 4;
                const float* ah = al + h * NRES + jh * 256;
                const float* pv = proj + (size_t)(jh * 256) * PRJ + 384 + elem;
                for (int j = 0; j < 256; ++j) { acc = fmaf(ah[j], *pv, acc); pv += PRJ; }
            } else {
                int e = elem - 192;
                int h = e / 24;
                const float* ah = al + h * NRES + jh * 256;
                const float* pv = gv + (size_t)(jh * 256) * 288 + e;
                for (int j = 0; j < 256; ++j) { acc = fmaf(ah[j], *pv, acc); pv += 288; }
            }
            partv[v] = acc;
        }
    }
    __syncthreads();

    if (t < 384) {
        int zq = t & 31, h = t >> 5;
        float inv = invh[h];
        float4 a = part4[t], b = part4[t + 384];
        float4 o;
        o.x = (a.x + b.x) * inv; o.y = (a.y + b.y) * inv;
        o.z = (a.z + b.z) * inv; o.w = (a.w + b.w) * inv;
        *(float4*)&concat[(size_t)i * OUT_DIM + 576 + h * 128 + zq * 4] = o;
    } else if (t >= 512 && t < 992) {
        int elem = t - 512;
        float v = partv[elem] + partv[elem + 480];
        if (elem < 192) {
            int h = elem >> 4;
            concat[(size_t)i * OUT_DIM + elem] = v * invh[h];
        } else {
            int e = elem - 192;
            int h = e / 24;
            opt[e] = v * invh[h];
        }
    }
    __syncthreads();
    if (t < 96) {
        int h = t >> 3, p = t & 7;
        float b0 = opt[h * 24 + p * 3 + 0] - trans[i * 3 + 0];
        float b1 = opt[h * 24 + p * 3 + 1] - trans[i * 3 + 1];
        float b2 = opt[h * 24 + p * 3 + 2] - trans[i * 3 + 2];
        const float* Ri = rot + i * 9;
        float l0 = Ri[0] * b0 + Ri[3] * b1 + Ri[6] * b2;
        float l1 = Ri[1] * b0 + Ri[4] * b1 + Ri[7] * b2;
        float l2 = Ri[2] * b0 + Ri[5] * b1 + Ri[8] * b2;
        float* c = concat + (size_t)i * OUT_DIM;
        c[192 + h * 24 + p * 3 + 0] = l0;
        c[192 + h * 24 + p * 3 + 1] = l1;
        c[192 + h * 24 + p * 3 + 2] = l2;
        c[480 + h * 8 + p] = sqrtf(l0 * l0 + l1 * l1 + l2 * l2 + 1e-8f);
    }
}

// ---------------------------------------------------------------------------
// LayerNorm over 384 (+ optional extra output: extraOut = extraB + y)
// ---------------------------------------------------------------------------
__global__ void ln_kernel(const float* __restrict__ x, const float* __restrict__ g,
                          const float* __restrict__ b, float* __restrict__ y,
                          const float* __restrict__ extraB, float* __restrict__ extraOut)
{
    int i = blockIdx.x, t = threadIdx.x;
    const float* xr = x + (size_t)i * CS;
    float a0 = xr[t], a1 = xr[t + 128], a2 = xr[t + 256];
    __shared__ float red[128];
    red[t] = a0 + a1 + a2;
    __syncthreads();
    for (int s = 64; s > 0; s >>= 1) { if (t < s) red[t] += red[t + s]; __syncthreads(); }
    float mean = red[0] * (1.f / CS);
    __syncthreads();
    float d0 = a0 - mean, d1 = a1 - mean, d2 = a2 - mean;
    red[t] = d0 * d0 + d1 * d1 + d2 * d2;
    __syncthreads();
    for (int s = 64; s > 0; s >>= 1) { if (t < s) red[t] += red[t + s]; __syncthreads(); }
    float rstd = rsqrtf(red[0] * (1.f / CS) + 1e-5f);
    float* yr = y + (size_t)i * CS;
    float y0 = d0 * rstd * g[t]       + b[t];
    float y1 = d1 * rstd * g[t + 128] + b[t + 128];
    float y2 = d2 * rstd * g[t + 256] + b[t + 256];
    yr[t] = y0; yr[t + 128] = y1; yr[t + 256] = y2;
    if (extraOut) {
        float* er = extraOut + (size_t)i * CS;
        er[t]       = extraB[t]       + y0;
        er[t + 128] = extraB[t + 128] + y1;
        er[t + 256] = extraB[t + 256] + y2;
    }
}

// ---------------------------------------------------------------------------
// Backbone (+ zero loss for the following loss kernel)
// ---------------------------------------------------------------------------
__global__ void backbone_kernel(const float* __restrict__ sfin, const float* __restrict__ Wbu,
                                const float* __restrict__ bbu, const float* __restrict__ rot,
                                const float* __restrict__ trans, float* __restrict__ rot_out,
                                float* __restrict__ trans_out, float* __restrict__ loss)
{
    int i = blockIdx.x, t = threadIdx.x;
    if (i == 0 && t == 0) *loss = 0.f;
    float part[6] = {0.f, 0.f, 0.f, 0.f, 0.f, 0.f};
    for (int k = t; k < CS; k += 128) {
        float s = sfin[(size_t)i * CS + k];
        const float* wr = Wbu + k * 6;
#pragma unroll
        for (int c = 0; c < 6; ++c) part[c] = fmaf(s, wr[c], part[c]);
    }
    __shared__ float red[6][128];
#pragma unroll
    for (int c = 0; c < 6; ++c) red[c][t] = part[c];
    __syncthreads();
    for (int s = 64; s > 0; s >>= 1) {
        if (t < s) {
#pragma unroll
            for (int c = 0; c < 6; ++c) red[c][t] += red[c][t + s];
        }
        __syncthreads();
    }
    if (t == 0) {
        float u[6];
#pragma unroll
        for (int c = 0; c < 6; ++c) u[c] = red[c][0] + bbu[c];
        float a = 1.f, b = u[0], c2 = u[1], d = u[2];
        float inv = rsqrtf(a * a + b * b + c2 * c2 + d * d);
        a *= inv; b *= inv; c2 *= inv; d *= inv;
        float R[9] = { a*a + b*b - c2*c2 - d*d, 2.f*(b*c2 - a*d),        2.f*(b*d + a*c2),
                       2.f*(b*c2 + a*d),        a*a - b*b + c2*c2 - d*d, 2.f*(c2*d - a*b),
                       2.f*(b*d - a*c2),        2.f*(c2*d + a*b),        a*a - b*b - c2*c2 + d*d };
        const float* Ri = rot + i * 9;
        float Rn[9];
#pragma unroll
        for (int r = 0; r < 3; ++r)
#pragma unroll
            for (int cc = 0; cc < 3; ++cc) {
                float s2 = 0.f;
#pragma unroll
                for (int kk = 0; kk < 3; ++kk) s2 += Ri[r * 3 + kk] * R[kk * 3 + cc];
                Rn[r * 3 + cc] = s2;
            }
#pragma unroll
        for (int r = 0; r < 9; ++r) rot_out[i * 9 + r] = Rn[r];
        float t0 = u[3], t1 = u[4], t2 = u[5];
#pragma unroll
        for (int r = 0; r < 3; ++r)
            trans_out[i * 3 + r] = Ri[r * 3 + 0] * t0 + Ri[r * 3 + 1] * t1 + Ri[r * 3 + 2] * t2 + trans[i * 3 + r];
    }
}

// ---------------------------------------------------------------------------
// Loss
// ---------------------------------------------------------------------------
__global__ void loss_kernel(const float* __restrict__ rot_new, const float* __restrict__ trans_new,
                            const float* __restrict__ rot_truth, const float* __restrict__ trans_truth,
                            float* __restrict__ loss)
{
    int i = blockIdx.x;
    int t = threadIdx.x;
    __shared__ float red[256];
    float Rn[9], Rt[9];
#pragma unroll
    for (int r = 0; r < 9; ++r) { Rn[r] = rot_new[i * 9 + r]; Rt[r] = rot_truth[i * 9 + r]; }
    float ti0 = trans_new[i * 3 + 0], ti1 = trans_new[i * 3 + 1], ti2 = trans_new[i * 3 + 2];
    float tt0 = trans_truth[i * 3 + 0], tt1 = trans_truth[i * 3 + 1], tt2 = trans_truth[i * 3 + 2];
    float s = 0.f;
    for (int j = t; j < NRES; j += 256) {
        float db0 = trans_new[j * 3 + 0] - ti0;
        float db1 = trans_new[j * 3 + 1] - ti1;
        float db2 = trans_new[j * 3 + 2] - ti2;
        float dp0 = Rn[0] * db0 + Rn[3] * db1 + Rn[6] * db2;
        float dp1 = Rn[1] * db0 + Rn[4] * db1 + Rn[7] * db2;
        float dp2 = Rn[2] * db0 + Rn[5] * db1 + Rn[8] * db2;
        float eb0 = trans_truth[j * 3 + 0] - tt0;
        float eb1 = trans_truth[j * 3 + 1] - tt1;
        float eb2 = trans_truth[j * 3 + 2] - tt2;
        float dt0 = Rt[0] * eb0 + Rt[3] * eb1 + Rt[6] * eb2;
        float dt1 = Rt[1] * eb0 + Rt[4] * eb1 + Rt[7] * eb2;
        float dt2 = Rt[2] * eb0 + Rt[5] * eb1 + Rt[8] * eb2;
        float dx = dp0 - dt0, dy = dp1 - dt1, dz = dp2 - dt2;
        float dd = sqrtf(dx * dx + dy * dy + dz * dz + 1e-12f);
        s += fminf(dd, 10.f);
    }
    red[t] = s;
    __syncthreads();
    for (int k = 128; k > 0; k >>= 1) { if (t < k) red[t] += red[t + k]; __syncthreads(); }
    if (t == 0) atomicAdd(loss, red[0] * (1.f / (512.f * 512.f * 10.f)));
}

// ---------------------------------------------------------------------------
extern "C" void kernel_launch(void* const* d_in, const int* in_sizes, int n_in,
                              void* d_out, int out_size, void* d_ws, size_t ws_size,
                              hipStream_t stream)
{
    const float* single      = (const float*)d_in[0];
    const float* pair        = (const float*)d_in[1];
    const float* rot         = (const float*)d_in[2];
    const float* trans       = (const float*)d_in[3];
    const float* rot_truth   = (const float*)d_in[4];
    const float* trans_truth = (const float*)d_in[5];
    const float* Wq  = (const float*)d_in[6];
    const float* Wk  = (const float*)d_in[7];
    const float* Wv  = (const float*)d_in[8];
    const float* Wqp = (const float*)d_in[9];
    const float* Wkp = (const float*)d_in[10];
    const float* Wvp = (const float*)d_in[11];
    const float* Wb  = (const float*)d_in[12];
    const float* Wo  = (const float*)d_in[13];
    const float* bo  = (const float*)d_in[14];
    const float* gamma_raw = (const float*)d_in[15];
    const float* ln1_g = (const float*)d_in[16];
    const float* ln1_b = (const float*)d_in[17];
    const float* ln2_g = (const float*)d_in[18];
    const float* ln2_b = (const float*)d_in[19];
    const float* W1 = (const float*)d_in[20];
    const float* b1 = (const float*)d_in[21];
    const float* W2 = (const float*)d_in[22];
    const float* b2 = (const float*)d_in[23];
    const float* W3 = (const float*)d_in[24];
    const float* b3 = (const float*)d_in[25];
    const float* Wbu = (const float*)d_in[26];
    const float* bbu = (const float*)d_in[27];

    float* out = (float*)d_out;
    float* single_out = out;                   // 512*384
    float* rot_out    = out + 196608;          // 512*9
    float* trans_out  = out + 201216;          // 512*3
    float* loss_out   = out + 202752;          // 1

    float* ws = (float*)d_ws;
    float* proj   = ws;                         // 589824
    float* gq     = proj   + 589824;            // 73728
    float* gv     = gq     + 73728;             // 147456
    float* sqq    = gv     + 147456;            // 6144
    float* kT     = sqq    + 6144;              // 98304
    float* gkT    = kT     + 98304;             // 73728
    float* sqkT   = gkT    + 73728;             // 6144
    float* wbfragf= sqkT   + 6144;              // 1024 (2048 ushorts)
    float* Amat   = wbfragf+ 1024;              // 3145728
    float* Bp     = Amat;                       // alias: dead after proj GEMM
    float* out2   = Amat;                       // alias: Amat dead after attn_out
    float* concat = Amat   + 3145728;           // 1081344
    float* out1   = concat + 1081344;           // 196608
    float* sln    = out1   + 196608;            // 196608
    float* h1     = sln    + 196608;            // 196608
    float* h2     = h1     + 196608;            // 196608
    unsigned short* wbfrag = (unsigned short*)wbfragf;

    dim3 b256(256);

    // 1. pack weights (+ Wb frags + zero proj); projection GEMM (k-split 2)
    int pack_total = CS * PRJ + 2048 + NRES * PRJ;
    pack_proj_kernel<<<dim3((pack_total + 255) / 256), b256, 0, stream>>>(
        Wq, Wk, Wv, Wqp, Wkp, Wvp, Wb, Bp, wbfrag, proj);
    gemm_tiled<<<dim3(8, PRJ / 64, 2), b256, 0, stream>>>(single, Bp, nullptr, nullptr, proj,
                                                          NRES, CS, PRJ, 0, 192, 0);

    // 2. frames
    frames_kernel<<<dim3((NRES * NH + 255) / 256), b256, 0, stream>>>(proj, rot, trans,
                                                                      gq, gv, sqq, kT, gkT, sqkT);

    // 3. logits (pre-softmax)
    logits_mfma_kernel<<<dim3(NRES, 8), b256, 0, stream>>>(pair, proj, gq, kT, gkT, sqq, sqkT,
                                                           wbfrag, gamma_raw, Amat);

    // 4. fused softmax + attention outputs
    attn_out_kernel<<<dim3(NRES), dim3(1024), 0, stream>>>(pair, Amat, proj, gv, rot, trans,
                                                           concat);

    // 5. fused init (out1/h1/h2) + Wo GEMM (k-split 4, atomic)
    init3_kernel<<<dim3((NRES * CS + 255) / 256), b256, 0, stream>>>(bo, single, b1, b2,
                                                                     out1, h1, h2);
    gemm_tiled<<<dim3(8, CS / 64, 4), b256, 0, stream>>>(concat, Wo, nullptr, nullptr, out1,
                                                         NRES, OUT_DIM, CS, 0, 528, 0);

    // 6. LN1 (also writes out2 = b3 + sln, aliasing dead Amat) + FF + LN2
    ln_kernel<<<dim3(NRES), dim3(128), 0, stream>>>(out1, ln1_g, ln1_b, sln, b3, out2);
    gemm_tiled<<<dim3(8, CS / 64, 4), b256, 0, stream>>>(sln, W1, nullptr, nullptr, h1,
                                                         NRES, CS, CS, 0, 96, 0);
    gemm_tiled<<<dim3(8, CS / 64, 4), b256, 0, stream>>>(h1, W2, nullptr, nullptr, h2,
                                                         NRES, CS, CS, 0, 96, 1);
    gemm_tiled<<<dim3(8, CS / 64, 4), b256, 0, stream>>>(h2, W3, nullptr, nullptr, out2,
                                                         NRES, CS, CS, 0, 96, 1);
    ln_kernel<<<dim3(NRES), dim3(128), 0, stream>>>(out2, ln2_g, ln2_b, single_out,
                                                    nullptr, nullptr);

    // 7. backbone (zeroes loss) + loss
    backbone_kernel<<<dim3(NRES), dim3(128), 0, stream>>>(single_out, Wbu, bbu, rot, trans,
                                                          rot_out, trans_out, loss_out);
    loss_kernel<<<dim3(NRES), b256, 0, stream>>>(rot_out, trans_out, rot_truth, trans_truth,
                                                 loss_out);
}